// Round 4
// baseline (501.910 us; speedup 1.0000x reference)
//
#include <hip/hip_runtime.h>
#include <hip/hip_bf16.h>
#include <cmath>
#include <stdint.h>

typedef __hip_bfloat16 bf16;
typedef __attribute__((ext_vector_type(8))) __bf16 bf16x8;
typedef __attribute__((ext_vector_type(8))) unsigned short u16x8;
typedef __attribute__((ext_vector_type(4))) float f32x4;

// Async global->LDS DMA, 16B per lane. LDS dest must be wave-uniform base;
// HW adds lane*16.
__device__ __forceinline__ void gld16(const void* g, const void* l)
{
    __builtin_amdgcn_global_load_lds(
        (const __attribute__((address_space(1))) unsigned int*)(unsigned long long)g,
        (__attribute__((address_space(3))) unsigned int*)(unsigned int)(unsigned long long)l,
        16, 0, 0);
}

// ---------------------------------------------------------------------------
// Fused fp32 -> bf16 conversion of all 12 tensors in one launch.
// ---------------------------------------------------------------------------
struct CvtSrcs { const float* p[24]; };

__global__ __launch_bounds__(256) void cvt_all(CvtSrcs s, bf16* __restrict__ dst)
{
    const int i = (blockIdx.x * 256 + threadIdx.x) * 8;
    const int seg = i >> 20;
    const float* sp = s.p[seg] + (i & 1048575);
    const float4 a = *(const float4*)(sp);
    const float4 b = *(const float4*)(sp + 4);
    const float v[8] = {a.x, a.y, a.z, a.w, b.x, b.y, b.z, b.w};
    bf16 tmp[8];
#pragma unroll
    for (int j = 0; j < 8; ++j) tmp[j] = __float2bfloat16(v[j]);
    *(uint4*)(dst + i) = *(const uint4*)tmp;
}

enum {
    EPI_QSCALE = 0,          // out_bf16 = (C + bias) * 0.125
    EPI_KV = 1,              // N=2048 fused: K plain / Vt transposed
    EPI_RELU = 2,            // out_bf16 = relu(C + bias)
    EPI_RES_F32_F32OUT = 3,  // out_f32  = res_f32 + C + bias
    EPI_PART = 4             // split-K=4 partial: out_bf16 = C (no bias)
};

// ---------------------------------------------------------------------------
// gemm256: C[4096,N] = A[4096,K] @ W[N,K]^T (+bias). 256x256 tile, BK=64,
// 512 thr = 8 waves (2M x 4N), per-wave 128x64 out. LDS 128KB: 2 slots x
// (A 256x64 + B 256x64), each as 2 halves of 128 rows.
// R4: counted-vmcnt 4-phase pipeline (T3+T4). Tile tt+1 staged in quarters
// spread over tile tt's phases (order b0,b1,b2,b3,a0,a2,a1,a3); waits are
// vmcnt(2) at P0 (certifies b0..b3,a0,a2 of current tile; invariant: exactly
// 8 outstanding) and vmcnt(2) at P1 (certifies a1,a3). Raw s_barrier (no
// compiler drain) only at P0/P1. Loads get >=2 phases of latency cover and
// are NEVER drained to 0 in the main loop (m218: +38% vs drain0).
// WAR safety: last ds_read of a slot (P3) is certified by the wave's own
// lgkmcnt before its MFMAs; >=2 barriers separate it from the first gld16
// write into that slot next tile.
// LDS XOR-swizzle (T2): phys 16B-slot = logical_kslot ^ (row&7); linear LDS
// dest + pre-swizzled global source, same XOR on reads. 0 conflicts (R2).
// ---------------------------------------------------------------------------
template <int EPI>
__global__ __launch_bounds__(512, 2) void gemm256(
    const bf16* __restrict__ A, const bf16* __restrict__ W,
    const float* __restrict__ bias, void* __restrict__ out,
    int N, int Kiter, int Kstride)
{
    __shared__ __align__(16) unsigned short sA[2][2][128 * 64];  // [slot][half]
    __shared__ __align__(16) unsigned short sB[2][2][128 * 64];

    const int t  = threadIdx.x;          // 0..511
    const int l  = t & 63;
    const int w  = t >> 6;               // 0..7
    const int wv = w * 64;
    const int wr = w >> 2;               // 0..1 : M-half of block
    const int wc = w & 3;                // 0..3 : N-quarter of block
    const int lm = l & 15;
    const int kq = l >> 4;
    const int rx = lm & 7;               // read-side swizzle row bits

    int bx = blockIdx.x;
    if (EPI == EPI_PART) {
        const int chunk = bx >> 6;       // 4 chunks x 64 blocks
        bx &= 63;
        A += (size_t)chunk * 1024;       // K-offset within rows
        W += (size_t)chunk * 1024;
        out = (void*)((bf16*)out + (size_t)chunk * 4096 * 1024);
    }
    // XCD-aware: xcd owns 2 contiguous bm-bands; bm fastest within xcd.
    const int xcd = bx & 7;
    const int ib  = bx >> 3;
    const int bm  = xcd * 2 + (ib & 1);
    const int bn  = ib >> 1;

    // Staging source: thread t covers 16B = (row t>>3, phys slot t&7);
    // logical kslot = (t&7) ^ ((t>>3)&7)  (inverse-swizzled source).
    const bf16* gA = A + (size_t)(bm * 256 + (t >> 3)) * Kstride
                       + ((t & 7) ^ ((t >> 3) & 7)) * 8;
    const bf16* gB = W + (size_t)(bn * 256 + (t >> 3)) * Kstride
                       + ((t & 7) ^ ((t >> 3) & 7)) * 8;

    // stage one 64-row quarter j (0..3) of tile kt into slot
#define SQA(slot, kt, j)                                        \
    gld16(gA + (size_t)((j) * 64) * Kstride + (kt) * 64,        \
          &sA[slot][(j) >> 1][(((j) & 1) * 512 + wv) * 8])
#define SQB(slot, kt, j)                                        \
    gld16(gB + (size_t)((j) * 64) * Kstride + (kt) * 64,        \
          &sB[slot][(j) >> 1][(((j) & 1) * 512 + wv) * 8])

    bf16x8 af[4][2], bg[2][2];

#define READ_AF(s_, mh)                                                     \
    do {                                                                    \
        _Pragma("unroll")                                                   \
        for (int mi = 0; mi < 4; ++mi)                                      \
            _Pragma("unroll")                                               \
            for (int kk = 0; kk < 2; ++kk) {                                \
                const int lr = (mh) * 64 + mi * 16 + lm;                    \
                const int sl = ((kk << 2) | kq) ^ rx;                       \
                af[mi][kk] = __builtin_bit_cast(bf16x8,                     \
                    *(const u16x8*)(&sA[s_][wr][lr * 64 + sl * 8]));        \
            }                                                               \
    } while (0)
#define READ_BG(s_, nh)                                                     \
    do {                                                                    \
        _Pragma("unroll")                                                   \
        for (int ni = 0; ni < 2; ++ni)                                      \
            _Pragma("unroll")                                               \
            for (int kk = 0; kk < 2; ++kk) {                                \
                const int lr = (wc & 1) * 64 + (nh) * 32 + ni * 16 + lm;    \
                const int sl = ((kk << 2) | kq) ^ rx;                       \
                bg[ni][kk] = __builtin_bit_cast(bf16x8,                     \
                    *(const u16x8*)(&sB[s_][wc >> 1][lr * 64 + sl * 8]));   \
            }                                                               \
    } while (0)
#define MFMA_QUAD(mh, nh)                                                   \
    do {                                                                    \
        __builtin_amdgcn_s_setprio(1);                                      \
        _Pragma("unroll")                                                   \
        for (int mi = 0; mi < 4; ++mi)                                      \
            _Pragma("unroll")                                               \
            for (int ni = 0; ni < 2; ++ni)                                  \
                _Pragma("unroll")                                           \
                for (int kk = 0; kk < 2; ++kk)                              \
                    acc[(mh) * 4 + mi][(nh) * 2 + ni] =                     \
                        __builtin_amdgcn_mfma_f32_16x16x32_bf16(            \
                            af[mi][kk], bg[ni][kk],                         \
                            acc[(mh) * 4 + mi][(nh) * 2 + ni], 0, 0, 0);    \
        __builtin_amdgcn_s_setprio(0);                                      \
    } while (0)
#define BARRIER() do { __builtin_amdgcn_s_barrier();                        \
                       __builtin_amdgcn_sched_barrier(0); } while (0)
#define WAITV2() asm volatile("s_waitcnt vmcnt(2)" ::: "memory")
#define WAITV0() asm volatile("s_waitcnt vmcnt(0)" ::: "memory")

    f32x4 acc[8][4] = {};
    const int NT = Kiter >> 6;

    // prologue: tile 0 -> slot 0; issue order b0 b1 b2 b3 a0 a2 a1 a3
    SQB(0, 0, 0); SQB(0, 0, 1); SQB(0, 0, 2); SQB(0, 0, 3);
    SQA(0, 0, 0); SQA(0, 0, 2); SQA(0, 0, 1); SQA(0, 0, 3);

    for (int tt = 0; tt < NT - 1; ++tt) {
        const int s = tt & 1, d = s ^ 1, kn = tt + 1;
        // P0 (mh0,nh0): certify b0..b3,a0,a2 of tile tt
        WAITV2(); BARRIER();
        SQB(d, kn, 0); SQB(d, kn, 1);
        READ_AF(s, 0); READ_BG(s, 0);
        MFMA_QUAD(0, 0);
        // P1 (mh1,nh0): certify a1,a3 of tile tt
        WAITV2(); BARRIER();
        SQB(d, kn, 2); SQB(d, kn, 3);
        READ_AF(s, 1);
        MFMA_QUAD(1, 0);
        // P2 (mh1,nh1): af alive; bg nh1 certified since P0
        SQA(d, kn, 0); SQA(d, kn, 2);
        READ_BG(s, 1);
        MFMA_QUAD(1, 1);
        // P3 (mh0,nh1): re-read af mh0; bg alive
        SQA(d, kn, 1); SQA(d, kn, 3);
        READ_AF(s, 0);
        MFMA_QUAD(0, 1);
    }
    {   // final tile: no staging; P1 drains to 0 (vmcnt(2) would under-wait)
        const int s = (NT - 1) & 1;
        WAITV2(); BARRIER();
        READ_AF(s, 0); READ_BG(s, 0);
        MFMA_QUAD(0, 0);
        WAITV0(); BARRIER();
        READ_AF(s, 1);
        MFMA_QUAD(1, 0);
        READ_BG(s, 1);
        MFMA_QUAD(1, 1);
        READ_AF(s, 0);
        MFMA_QUAD(0, 1);
    }
#undef SQA
#undef SQB
#undef READ_AF
#undef READ_BG
#undef MFMA_QUAD
#undef BARRIER
#undef WAITV2
#undef WAITV0

    // Epilogue. C/D: col = lane&15 (+16*NI), row = kq*4 + r (+16*MI).
#pragma unroll
    for (int NI = 0; NI < 4; ++NI) {
        const int col = bn * 256 + wc * 64 + NI * 16 + lm;
        const float bv = (EPI == EPI_PART) ? 0.f : bias[col];
#pragma unroll
        for (int MI = 0; MI < 8; ++MI) {
            const int row = bm * 256 + wr * 128 + MI * 16 + kq * 4;
#pragma unroll
            for (int r = 0; r < 4; ++r) {
                float v = acc[MI][NI][r] + bv;
                if (EPI == EPI_RELU) v = fmaxf(v, 0.f);
                ((bf16*)out)[(size_t)(row + r) * N + col] = __float2bfloat16(v);
            }
        }
    }
}

// ---------------------------------------------------------------------------
// GEMM (128-class): C[M,N] = A[M,K] @ W[N,K]^T (+ bias). BM x 128 tile,
// BK=32, async global_load_lds dbuf, 1 barrier/iter. Used for QKV/out-proj.
// ---------------------------------------------------------------------------
template <int EPI, int BM>
__global__ __launch_bounds__(BM * 2, 2) void gemm_bt(
    const bf16* __restrict__ A, const bf16* __restrict__ W,
    const float* __restrict__ bias, const float* __restrict__ bias2,
    const float* __restrict__ res, void* __restrict__ out,
    int M, int N, int Kiter, int Kstride)
{
    constexpr int T    = BM * 2;
    constexpr int ISSA = (BM * 4) / T;
    constexpr int ISSB = 512 / T;
    constexpr int ROWS = T / 4;
    constexpr int MBK  = 4096 / BM;
    constexpr int MBX  = MBK / 8;
    constexpr int MBS  = (BM == 64) ? 3 : 2;

    __shared__ __align__(16) unsigned short sA[2][BM * 32];
    __shared__ __align__(16) unsigned short sB[2][128 * 32];

    const int t  = threadIdx.x;
    const int l  = t & 63;
    const int w  = t >> 6;
    const int wv = w * 64;
    const int wm = (w >> 1) * 64;
    const int wn = (w & 1) * 64;
    const int lm = l & 15;
    const int kq = l >> 4;

    int bx = blockIdx.x;
    const int xcd = bx & 7;
    const int ib  = bx >> 3;
    const int bm  = xcd * MBX + (ib & (MBX - 1));
    const int bn  = ib >> MBS;

    const bf16* gA = A + (size_t)(bm * BM + (t >> 2)) * Kstride + (t & 3) * 8;
    const bf16* gB = W + (size_t)(bn * 128 + (t >> 2)) * Kstride + (t & 3) * 8;

    int aoffs[4], boffs[4];
#pragma unroll
    for (int i = 0; i < 4; ++i) {
        aoffs[i] = (wm + i * 16 + lm) * 32 + kq * 8;
        boffs[i] = (wn + i * 16 + lm) * 32 + kq * 8;
    }

#define STAGE(buf, kk)                                                       \
    do {                                                                     \
        _Pragma("unroll")                                                    \
        for (int j = 0; j < ISSA; ++j)                                       \
            gld16(gA + (size_t)j * ROWS * Kstride + (kk),                    \
                  &sA[buf][(j * T + wv) * 8]);                               \
        _Pragma("unroll")                                                    \
        for (int j = 0; j < ISSB; ++j)                                       \
            gld16(gB + (size_t)j * ROWS * Kstride + (kk),                    \
                  &sB[buf][(j * T + wv) * 8]);                               \
    } while (0)

    STAGE(0, 0);
    __syncthreads();

    f32x4 acc[4][4] = {};

    for (int k0 = 0; k0 < Kiter; k0 += 32) {
        const int cur = (k0 >> 5) & 1;

        if (k0 + 32 < Kiter) STAGE(cur ^ 1, k0 + 32);

        bf16x8 af[4], bg[4];
#pragma unroll
        for (int i = 0; i < 4; ++i)
            af[i] = __builtin_bit_cast(bf16x8, *(const u16x8*)(&sA[cur][aoffs[i]]));
#pragma unroll
        for (int i = 0; i < 4; ++i)
            bg[i] = __builtin_bit_cast(bf16x8, *(const u16x8*)(&sB[cur][boffs[i]]));
#pragma unroll
        for (int mi = 0; mi < 4; ++mi)
#pragma unroll
            for (int ni = 0; ni < 4; ++ni)
                acc[mi][ni] = __builtin_amdgcn_mfma_f32_16x16x32_bf16(
                    af[mi], bg[ni], acc[mi][ni], 0, 0, 0);

        __syncthreads();
    }
#undef STAGE

#pragma unroll
    for (int ni = 0; ni < 4; ++ni) {
        const int col = bn * 128 + wn + ni * 16 + lm;
        float bv = 0.f;
        if (EPI == EPI_KV) bv = (col < 1024) ? bias[col] : bias2[col - 1024];
        else bv = bias[col];
#pragma unroll
        for (int mi = 0; mi < 4; ++mi) {
#pragma unroll
            for (int r = 0; r < 4; ++r) {
                const int row = bm * BM + wm + mi * 16 + kq * 4 + r;
                float v = acc[mi][ni][r] + bv;
                if (EPI == EPI_QSCALE) v *= 0.125f;
                if (EPI == EPI_KV) {
                    if (col < 1024) {
                        ((bf16*)out)[(size_t)row * 1024 + col] = __float2bfloat16(v);
                    } else {
                        const int ch = col - 1024;  // h*64 + d
                        const size_t idx = (size_t)4 * 1048576 +
                            ((size_t)((row >> 10) * 16 + (ch >> 6)) * 64 + (ch & 63)) * 1024
                            + (row & 1023);
                        ((bf16*)out)[idx] = __float2bfloat16(v);
                    }
                } else if (EPI == EPI_RES_F32_F32OUT) {
                    const size_t idx = (size_t)row * N + col;
                    ((float*)out)[idx] = v + res[idx];
                } else {
                    ((bf16*)out)[(size_t)row * N + col] = __float2bfloat16(v);
                }
            }
        }
    }
}

// ---------------------------------------------------------------------------
// FFN2 split-K reduce: out_f32 = x2 + b2 + sum_{c<4} (float)P[c].
// ---------------------------------------------------------------------------
__global__ __launch_bounds__(256) void ffn2_reduce(
    const bf16* __restrict__ P, const float* __restrict__ x2,
    const float* __restrict__ b2, float* __restrict__ out)
{
    const int i = (blockIdx.x * 256 + threadIdx.x) * 8;
    float v[8];
    {
        const float4 a = *(const float4*)(x2 + i);
        const float4 b = *(const float4*)(x2 + i + 4);
        v[0]=a.x; v[1]=a.y; v[2]=a.z; v[3]=a.w; v[4]=b.x; v[5]=b.y; v[6]=b.z; v[7]=b.w;
    }
    const int cb = i & 1023;
#pragma unroll
    for (int j = 0; j < 8; ++j) v[j] += b2[cb + j];
#pragma unroll
    for (int c = 0; c < 4; ++c) {
        const u16x8 u = *(const u16x8*)(P + (size_t)c * 4194304 + i);
        const bf16x8 pb = __builtin_bit_cast(bf16x8, u);
#pragma unroll
        for (int j = 0; j < 8; ++j) v[j] += (float)pb[j];
    }
    float4 o0 = {v[0], v[1], v[2], v[3]}, o1 = {v[4], v[5], v[6], v[7]};
    *(float4*)(out + i) = o0;
    *(float4*)(out + i + 4) = o1;
}

// ---------------------------------------------------------------------------
// Flash attention (MFMA). One block = (b,h) x 128 q-rows; 4 waves x 32 q-rows.
// Q,K,O: [B,T,H*64] bf16 (0.125 pre-folded into Q). Vt: [B,H,64(d),S] bf16.
// K/V staged via async global_load_lds; double-buffered LDS, 1 barrier/tile.
// ---------------------------------------------------------------------------
template <bool CAUSAL, bool SBIAS>
__global__ __launch_bounds__(256, 2) void flash_attn(
    const bf16* __restrict__ Q, const bf16* __restrict__ K,
    const bf16* __restrict__ Vt, bf16* __restrict__ O,
    const float* __restrict__ sbias, const float* __restrict__ scale_ptr)
{
    __shared__ __align__(16) unsigned short sK[2][64 * 64];
    __shared__ __align__(16) unsigned short sV[2][64 * 64];
    __shared__ __align__(16) unsigned short sP[4 * 32 * 72];

    const int t  = threadIdx.x;
    const int l  = t & 63;
    const int w  = t >> 6;
    const int wv = w * 64;
    const int lm = l & 15;
    const int kq = l >> 4;

    const int qb = blockIdx.x & 7;
    const int bh = blockIdx.x >> 3;
    const int h  = bh & 15;
    const int b  = bh >> 4;

    const int tb = qb * 128 + w * 32;
    const size_t qrow0 = (size_t)(b * 1024 + tb) * 1024 + h * 64;

    bf16x8 qf[2][2];
#pragma unroll
    for (int mi = 0; mi < 2; ++mi)
#pragma unroll
        for (int kk = 0; kk < 2; ++kk)
            qf[mi][kk] = __builtin_bit_cast(bf16x8,
                *(const u16x8*)(Q + qrow0 + (size_t)(mi * 16 + lm) * 1024 + kk * 32 + kq * 8));

    float cs = 0.f; const float* sb = nullptr;
    if (SBIAS) { cs = scale_ptr[0]; sb = sbias + b * 1024; }

    const bf16* gK = K  + (size_t)(b * 1024 + (t >> 2)) * 1024 + h * 64 + (t & 3) * 8;
    const bf16* gV = Vt + (size_t)((b * 16 + h) * 64 + (t >> 2)) * 1024 + (t & 3) * 8;
    __bf16* sPw = (__bf16*)sP + w * 32 * 72;

#define STAGE_KV(buf, s0r)                                              \
    do {                                                                \
        gld16(gK + (size_t)(s0r) * 1024,      &sK[buf][wv * 8]);        \
        gld16(gK + (size_t)(s0r) * 1024 + 32, &sK[buf][wv * 8 + 2048]); \
        gld16(gV + (s0r),                     &sV[buf][wv * 8]);        \
        gld16(gV + (s0r) + 32,                &sV[buf][wv * 8 + 2048]); \
    } while (0)

    const int niter = CAUSAL ? (2 * qb + 2) : 16;

    STAGE_KV(0, 0);
    __syncthreads();

    f32x4 acc_o[2][4] = {};
    f32x4 l_run[2] = {};

    for (int it = 0; it < niter; ++it) {
        const int s0 = it * 64;
        const int cur = it & 1;

        if (it + 1 < niter) STAGE_KV(cur ^ 1, s0 + 64);

        f32x4 accs[2][4] = {};
#pragma unroll
        for (int ni = 0; ni < 4; ++ni)
#pragma unroll
            for (int kk = 0; kk < 2; ++kk) {
                const bf16x8 kf = __builtin_bit_cast(bf16x8,
                    *(const u16x8*)(&sK[cur][kk * 2048 + (ni * 16 + lm) * 32 + kq * 8]));
#pragma unroll
                for (int mi = 0; mi < 2; ++mi)
                    accs[mi][ni] = __builtin_amdgcn_mfma_f32_16x16x32_bf16(
                        qf[mi][kk], kf, accs[mi][ni], 0, 0, 0);
            }

        if (SBIAS) {
#pragma unroll
            for (int ni = 0; ni < 4; ++ni) {
                const float sv = cs * sb[s0 + ni * 16 + lm];
#pragma unroll
                for (int mi = 0; mi < 2; ++mi)
#pragma unroll
                    for (int r = 0; r < 4; ++r) accs[mi][ni][r] += sv;
            }
        }
        if (CAUSAL && (s0 + 63 > tb)) {
#pragma unroll
            for (int ni = 0; ni < 4; ++ni) {
                const int s = s0 + ni * 16 + lm;
#pragma unroll
                for (int mi = 0; mi < 2; ++mi)
#pragma unroll
                    for (int r = 0; r < 4; ++r)
                        if (s > tb + mi * 16 + kq * 4 + r) accs[mi][ni][r] = -1e30f;
            }
        }

#pragma unroll
        for (int mi = 0; mi < 2; ++mi)
#pragma unroll
            for (int ni = 0; ni < 4; ++ni)
#pragma unroll
                for (int r = 0; r < 4; ++r) {
                    const float e = __expf(accs[mi][ni][r]);
                    l_run[mi][r] += e;
                    sPw[(mi * 16 + kq * 4 + r) * 72 + ni * 16 + lm] = (__bf16)e;
                }

#pragma unroll
        for (int kk = 0; kk < 2; ++kk) {
            bf16x8 pf[2];
#pragma unroll
            for (int mi = 0; mi < 2; ++mi)
                pf[mi] = __builtin_bit_cast(bf16x8,
                    *(const u16x8*)(sPw + (mi * 16 + lm) * 72 + kk * 32 + kq * 8));
#pragma unroll
            for (int di = 0; di < 4; ++di) {
                const bf16x8 vf = __builtin_bit_cast(bf16x8,
                    *(const u16x8*)(&sV[cur][kk * 2048 + (di * 16 + lm) * 32 + kq * 8]));
#pragma unroll
                for (int mi = 0; mi < 2; ++mi)
                    acc_o[mi][di] = __builtin_amdgcn_mfma_f32_16x16x32_bf16(
                        pf[mi], vf, acc_o[mi][di], 0, 0, 0);
            }
        }

        __syncthreads();
    }
#undef STAGE_KV

#pragma unroll
    for (int mi = 0; mi < 2; ++mi) {
        f32x4 lt = l_run[mi];
#pragma unroll
        for (int x = 1; x < 16; x <<= 1)
#pragma unroll
            for (int r = 0; r < 4; ++r) lt[r] += __shfl_xor(lt[r], x, 64);
#pragma unroll
        for (int r = 0; r < 4; ++r) lt[r] = 1.f / lt[r];
#pragma unroll
        for (int di = 0; di < 4; ++di)
#pragma unroll
            for (int r = 0; r < 4; ++r) {
                const size_t idx = (size_t)(b * 1024 + tb + mi * 16 + kq * 4 + r) * 1024
                                 + h * 64 + di * 16 + lm;
                O[idx] = __float2bfloat16(acc_o[mi][di][r] * lt[r]);
            }
    }
}

// ---------------------------------------------------------------------------
// LayerNorm over D=1024 (fp32 in, bf16 out), one block per row, 4 elems/thr.
// ---------------------------------------------------------------------------
__global__ __launch_bounds__(256) void ln_kernel(
    const float* __restrict__ xin, const float* __restrict__ g,
    const float* __restrict__ bta, bf16* __restrict__ out)
{
    const int row = blockIdx.x;
    const int t = threadIdx.x;
    const size_t base = (size_t)row * 1024 + t * 4;

    const float4 f = *(const float4*)(xin + base);
    const float v[4] = {f.x, f.y, f.z, f.w};
    float s1 = v[0] + v[1] + v[2] + v[3];
    float s2 = v[0]*v[0] + v[1]*v[1] + v[2]*v[2] + v[3]*v[3];
#pragma unroll
    for (int off = 32; off > 0; off >>= 1) {
        s1 += __shfl_xor(s1, off, 64);
        s2 += __shfl_xor(s2, off, 64);
    }
    __shared__ float r1[4], r2[4];
    if ((t & 63) == 0) { r1[t >> 6] = s1; r2[t >> 6] = s2; }
    __syncthreads();
    s1 = r1[0] + r1[1] + r1[2] + r1[3];
    s2 = r2[0] + r2[1] + r2[2] + r2[3];
    const float mean = s1 * (1.f / 1024.f);
    const float var  = s2 * (1.f / 1024.f) - mean * mean;
    const float rstd = rsqrtf(var + 1e-5f);
#pragma unroll
    for (int j = 0; j < 4; ++j) {
        const int c = t * 4 + j;
        out[base + j] = __float2bfloat16((v[j] - mean) * rstd * g[c] + bta[c]);
    }
}

// ---------------------------------------------------------------------------
extern "C" void kernel_launch(void* const* d_in, const int* in_sizes, int n_in,
                              void* d_out, int out_size, void* d_ws, size_t ws_size,
                              hipStream_t stream)
{
    const float* x       = (const float*)d_in[0];
    const float* memory  = (const float*)d_in[1];
    const float* sbias   = (const float*)d_in[2];
    const float* sa_bq = (const float*)d_in[7];
    const float* sa_bk = (const float*)d_in[9];
    const float* sa_bv = (const float*)d_in[11];
    const float* sa_bo = (const float*)d_in[13];
    const float* ca_bq = (const float*)d_in[16];
    const float* ca_bk = (const float*)d_in[18];
    const float* ca_bv = (const float*)d_in[20];
    const float* ca_bo = (const float*)d_in[22];
    const float* ca_scale = (const float*)d_in[23];
    const float* ln1_g = (const float*)d_in[24]; const float* ln1_b = (const float*)d_in[25];
    const float* ln2_g = (const float*)d_in[26]; const float* ln2_b = (const float*)d_in[27];
    const float* ln3_g = (const float*)d_in[28]; const float* ln3_b = (const float*)d_in[29];
    const float* b1 = (const float*)d_in[31];
    const float* b2 = (const float*)d_in[33];

    char* ws = (char*)d_ws;
    const size_t MB = (size_t)1 << 20;
    float* x1    = (float*)(ws + 0 * MB);
    float* x2    = (float*)(ws + 16 * MB);
    bf16* lnbuf  = (bf16*)(ws + 32 * MB);
    bf16* Qb     = (bf16*)(ws + 40 * MB);
    bf16* Kb     = (bf16*)(ws + 48 * MB);
    bf16* Vtb    = (bf16*)(ws + 56 * MB);
    bf16* Ob     = (bf16*)(ws + 64 * MB);
    bf16* ffnmid = (bf16*)(ws + 40 * MB);
    bf16* wx     = (bf16*)(ws + 72 * MB);
    bf16* wmem   = (bf16*)(ws + 80 * MB);
    bf16* bw     = (bf16*)(ws + 88 * MB);
    bf16* b_sa_wq = bw + 0 * 1048576, *b_sa_wk = bw + 1 * 1048576;
    bf16* b_sa_wo = bw + 3 * 1048576;
    bf16* b_ca_wq = bw + 4 * 1048576, *b_ca_wk = bw + 5 * 1048576;
    bf16* b_ca_wo = bw + 7 * 1048576;
    bf16* b_w1   = (bf16*)(ws + 104 * MB);
    bf16* b_w2   = (bf16*)(ws + 112 * MB);
    bf16* part   = (bf16*)(ws + 72 * MB);

    const int M = 4096;
    dim3 blk256(256), blk128(128), blk512(512);
    const dim3 gQ(512);
    const dim3 gKV(512);
    const dim3 gFA(512);
    const dim3 g256(256);   // FFN1: 16x16 tiles; FFN2: 4 chunks x 64 tiles

    CvtSrcs cs;
    for (int c = 0; c < 4; ++c) {
        cs.p[c]      = x + (size_t)c * 1048576;
        cs.p[4 + c]  = memory + (size_t)c * 1048576;
        cs.p[16 + c] = (const float*)d_in[30] + (size_t)c * 1048576;  // w1
        cs.p[20 + c] = (const float*)d_in[32] + (size_t)c * 1048576;  // w2
    }
    cs.p[8]  = (const float*)d_in[6];
    cs.p[9]  = (const float*)d_in[8];
    cs.p[10] = (const float*)d_in[10];
    cs.p[11] = (const float*)d_in[12];
    cs.p[12] = (const float*)d_in[15];
    cs.p[13] = (const float*)d_in[17];
    cs.p[14] = (const float*)d_in[19];
    cs.p[15] = (const float*)d_in[21];
    cvt_all<<<24 * 1048576 / 2048, blk256, 0, stream>>>(cs, wx);

    // ---- self-attention ----
    ln_kernel<<<4096, blk256, 0, stream>>>(x, ln1_g, ln1_b, lnbuf);
    gemm_bt<EPI_QSCALE, 64><<<gQ, blk128, 0, stream>>>(
        lnbuf, b_sa_wq, sa_bq, nullptr, nullptr, Qb, M, 1024, 1024, 1024);
    gemm_bt<EPI_KV, 128><<<gKV, blk256, 0, stream>>>(
        wx, b_sa_wk, sa_bk, sa_bv, nullptr, Kb, M, 2048, 1024, 1024);
    flash_attn<true, false><<<gFA, blk256, 0, stream>>>(Qb, Kb, Vtb, Ob, nullptr, nullptr);
    gemm_bt<EPI_RES_F32_F32OUT, 64><<<gQ, blk128, 0, stream>>>(
        Ob, b_sa_wo, sa_bo, nullptr, x, x1, M, 1024, 1024, 1024);

    // ---- cross-attention ----
    ln_kernel<<<4096, blk256, 0, stream>>>(x1, ln2_g, ln2_b, lnbuf);
    gemm_bt<EPI_QSCALE, 64><<<gQ, blk128, 0, stream>>>(
        lnbuf, b_ca_wq, ca_bq, nullptr, nullptr, Qb, M, 1024, 1024, 1024);
    gemm_bt<EPI_KV, 128><<<gKV, blk256, 0, stream>>>(
        wmem, b_ca_wk, ca_bk, ca_bv, nullptr, Kb, M, 2048, 1024, 1024);
    flash_attn<false, true><<<gFA, blk256, 0, stream>>>(Qb, Kb, Vtb, Ob, sbias, ca_scale);
    gemm_bt<EPI_RES_F32_F32OUT, 64><<<gQ, blk128, 0, stream>>>(
        Ob, b_ca_wo, ca_bo, nullptr, x1, x2, M, 1024, 1024, 1024);

    // ---- FFN ----
    ln_kernel<<<4096, blk256, 0, stream>>>(x2, ln3_g, ln3_b, lnbuf);
    gemm256<EPI_RELU><<<g256, blk512, 0, stream>>>(
        lnbuf, b_w1, b1, ffnmid, 4096, 1024, 1024);
    gemm256<EPI_PART><<<g256, blk512, 0, stream>>>(
        ffnmid, b_w2, nullptr, part, 1024, 1024, 4096);
    ffn2_reduce<<<2048, blk256, 0, stream>>>(part, x2, b2, (float*)d_out);
}

// Round 5
// 496.718 us; speedup vs baseline: 1.0105x; 1.0105x over previous
//
#include <hip/hip_runtime.h>
#include <hip/hip_bf16.h>
#include <cmath>
#include <stdint.h>

typedef __hip_bfloat16 bf16;
typedef __attribute__((ext_vector_type(8))) __bf16 bf16x8;
typedef __attribute__((ext_vector_type(8))) unsigned short u16x8;
typedef __attribute__((ext_vector_type(4))) float f32x4;

// Async global->LDS DMA, 16B per lane. LDS dest must be wave-uniform base;
// HW adds lane*16.
__device__ __forceinline__ void gld16(const void* g, const void* l)
{
    __builtin_amdgcn_global_load_lds(
        (const __attribute__((address_space(1))) unsigned int*)(unsigned long long)g,
        (__attribute__((address_space(3))) unsigned int*)(unsigned int)(unsigned long long)l,
        16, 0, 0);
}

// ---------------------------------------------------------------------------
// Fused fp32 -> bf16 conversion of all 12 tensors in one launch.
// ---------------------------------------------------------------------------
struct CvtSrcs { const float* p[24]; };

__global__ __launch_bounds__(256) void cvt_all(CvtSrcs s, bf16* __restrict__ dst)
{
    const int i = (blockIdx.x * 256 + threadIdx.x) * 8;
    const int seg = i >> 20;
    const float* sp = s.p[seg] + (i & 1048575);
    const float4 a = *(const float4*)(sp);
    const float4 b = *(const float4*)(sp + 4);
    const float v[8] = {a.x, a.y, a.z, a.w, b.x, b.y, b.z, b.w};
    bf16 tmp[8];
#pragma unroll
    for (int j = 0; j < 8; ++j) tmp[j] = __float2bfloat16(v[j]);
    *(uint4*)(dst + i) = *(const uint4*)tmp;
}

enum {
    EPI_QSCALE = 0,          // out_bf16 = (C + bias) * 0.125
    EPI_KV = 1,              // N=2048 fused: K plain / Vt transposed
    EPI_RELU = 2,            // out_bf16 = relu(C + bias)
    EPI_RES_F32_F32OUT = 3,  // out_f32  = res_f32 + C + bias
    EPI_PART = 4             // split-K=4 partial: out_bf16 = C (no bias)
};

// ---------------------------------------------------------------------------
// gemm256: C[4096,N] = A[4096,K] @ W[N,K]^T (+bias). 256x256 tile, BK=64,
// 512 thr = 8 waves (2M x 4N), per-wave 128x64 out. LDS 128KB: 2 slots x
// (A 256x64 + B 256x64), each as 2 halves of 128 rows.
// K-loop (R4, verified): counted-vmcnt 4-phase pipeline; tile tt+1 staged in
// quarters over tile tt's phases; vmcnt(2) waits at P0/P1; raw s_barrier
// only at P0/P1; never drains vmcnt to 0 in the main loop.
// Epilogue (R5): LDS-bounce vectorized store. The old epilogue issued 128
// scalar 2B global stores/thread (65536/block ~ 16 kcy issue, ~16% of
// kernel) and produced 32B write sectors (WRITE_SIZE 2x ideal, measured
// 66MB vs 32MB). New: wave-private 16KB LDS strip (dead after K-loop),
// 128 ds_write_b16 (chunk-XOR swizzle, <=2-way) + 16 ds_read_b128 +
// 16 global_store_dwordx4 -> 8x fewer vmem stores, full-line writes.
// ---------------------------------------------------------------------------
template <int EPI>
__global__ __launch_bounds__(512, 2) void gemm256(
    const bf16* __restrict__ A, const bf16* __restrict__ W,
    const float* __restrict__ bias, void* __restrict__ out,
    int N, int Kiter, int Kstride)
{
    __shared__ __align__(16) unsigned short sA[2][2][128 * 64];  // [slot][half]
    __shared__ __align__(16) unsigned short sB[2][2][128 * 64];

    const int t  = threadIdx.x;          // 0..511
    const int l  = t & 63;
    const int w  = t >> 6;               // 0..7
    const int wv = w * 64;
    const int wr = w >> 2;               // 0..1 : M-half of block
    const int wc = w & 3;                // 0..3 : N-quarter of block
    const int lm = l & 15;
    const int kq = l >> 4;
    const int rx = lm & 7;               // read-side swizzle row bits

    int bx = blockIdx.x;
    if (EPI == EPI_PART) {
        const int chunk = bx >> 6;       // 4 chunks x 64 blocks
        bx &= 63;
        A += (size_t)chunk * 1024;       // K-offset within rows
        W += (size_t)chunk * 1024;
        out = (void*)((bf16*)out + (size_t)chunk * 4096 * 1024);
    }
    // XCD-aware: xcd owns 2 contiguous bm-bands; bm fastest within xcd.
    const int xcd = bx & 7;
    const int ib  = bx >> 3;
    const int bm  = xcd * 2 + (ib & 1);
    const int bn  = ib >> 1;

    // Staging source: thread t covers 16B = (row t>>3, phys slot t&7);
    // logical kslot = (t&7) ^ ((t>>3)&7)  (inverse-swizzled source).
    const bf16* gA = A + (size_t)(bm * 256 + (t >> 3)) * Kstride
                       + ((t & 7) ^ ((t >> 3) & 7)) * 8;
    const bf16* gB = W + (size_t)(bn * 256 + (t >> 3)) * Kstride
                       + ((t & 7) ^ ((t >> 3) & 7)) * 8;

    // stage one 64-row quarter j (0..3) of tile kt into slot
#define SQA(slot, kt, j)                                        \
    gld16(gA + (size_t)((j) * 64) * Kstride + (kt) * 64,        \
          &sA[slot][(j) >> 1][(((j) & 1) * 512 + wv) * 8])
#define SQB(slot, kt, j)                                        \
    gld16(gB + (size_t)((j) * 64) * Kstride + (kt) * 64,        \
          &sB[slot][(j) >> 1][(((j) & 1) * 512 + wv) * 8])

    bf16x8 af[4][2], bg[2][2];

#define READ_AF(s_, mh)                                                     \
    do {                                                                    \
        _Pragma("unroll")                                                   \
        for (int mi = 0; mi < 4; ++mi)                                      \
            _Pragma("unroll")                                               \
            for (int kk = 0; kk < 2; ++kk) {                                \
                const int lr = (mh) * 64 + mi * 16 + lm;                    \
                const int sl = ((kk << 2) | kq) ^ rx;                       \
                af[mi][kk] = __builtin_bit_cast(bf16x8,                     \
                    *(const u16x8*)(&sA[s_][wr][lr * 64 + sl * 8]));        \
            }                                                               \
    } while (0)
#define READ_BG(s_, nh)                                                     \
    do {                                                                    \
        _Pragma("unroll")                                                   \
        for (int ni = 0; ni < 2; ++ni)                                      \
            _Pragma("unroll")                                               \
            for (int kk = 0; kk < 2; ++kk) {                                \
                const int lr = (wc & 1) * 64 + (nh) * 32 + ni * 16 + lm;    \
                const int sl = ((kk << 2) | kq) ^ rx;                       \
                bg[ni][kk] = __builtin_bit_cast(bf16x8,                     \
                    *(const u16x8*)(&sB[s_][wc >> 1][lr * 64 + sl * 8]));   \
            }                                                               \
    } while (0)
#define MFMA_QUAD(mh, nh)                                                   \
    do {                                                                    \
        __builtin_amdgcn_s_setprio(1);                                      \
        _Pragma("unroll")                                                   \
        for (int mi = 0; mi < 4; ++mi)                                      \
            _Pragma("unroll")                                               \
            for (int ni = 0; ni < 2; ++ni)                                  \
                _Pragma("unroll")                                           \
                for (int kk = 0; kk < 2; ++kk)                              \
                    acc[(mh) * 4 + mi][(nh) * 2 + ni] =                     \
                        __builtin_amdgcn_mfma_f32_16x16x32_bf16(            \
                            af[mi][kk], bg[ni][kk],                         \
                            acc[(mh) * 4 + mi][(nh) * 2 + ni], 0, 0, 0);    \
        __builtin_amdgcn_s_setprio(0);                                      \
    } while (0)
#define BARRIER() do { __builtin_amdgcn_s_barrier();                        \
                       __builtin_amdgcn_sched_barrier(0); } while (0)
#define WAITV2() asm volatile("s_waitcnt vmcnt(2)" ::: "memory")
#define WAITV0() asm volatile("s_waitcnt vmcnt(0)" ::: "memory")

    f32x4 acc[8][4] = {};
    const int NT = Kiter >> 6;

    // prologue: tile 0 -> slot 0; issue order b0 b1 b2 b3 a0 a2 a1 a3
    SQB(0, 0, 0); SQB(0, 0, 1); SQB(0, 0, 2); SQB(0, 0, 3);
    SQA(0, 0, 0); SQA(0, 0, 2); SQA(0, 0, 1); SQA(0, 0, 3);

    for (int tt = 0; tt < NT - 1; ++tt) {
        const int s = tt & 1, d = s ^ 1, kn = tt + 1;
        // P0 (mh0,nh0): certify b0..b3,a0,a2 of tile tt
        WAITV2(); BARRIER();
        SQB(d, kn, 0); SQB(d, kn, 1);
        READ_AF(s, 0); READ_BG(s, 0);
        MFMA_QUAD(0, 0);
        // P1 (mh1,nh0): certify a1,a3 of tile tt
        WAITV2(); BARRIER();
        SQB(d, kn, 2); SQB(d, kn, 3);
        READ_AF(s, 1);
        MFMA_QUAD(1, 0);
        // P2 (mh1,nh1): af alive; bg nh1 certified since P0
        SQA(d, kn, 0); SQA(d, kn, 2);
        READ_BG(s, 1);
        MFMA_QUAD(1, 1);
        // P3 (mh0,nh1): re-read af mh0; bg alive
        SQA(d, kn, 1); SQA(d, kn, 3);
        READ_AF(s, 0);
        MFMA_QUAD(0, 1);
    }
    {   // final tile: no staging; P1 drains to 0 (vmcnt(2) would under-wait)
        const int s = (NT - 1) & 1;
        WAITV2(); BARRIER();
        READ_AF(s, 0); READ_BG(s, 0);
        MFMA_QUAD(0, 0);
        WAITV0(); BARRIER();
        READ_AF(s, 1);
        MFMA_QUAD(1, 0);
        READ_BG(s, 1);
        MFMA_QUAD(1, 1);
        READ_AF(s, 0);
        MFMA_QUAD(0, 1);
    }
#undef SQA
#undef SQB
#undef READ_AF
#undef READ_BG
#undef MFMA_QUAD
#undef BARRIER
#undef WAITV2
#undef WAITV0

    // ---- Epilogue (R5): LDS-bounce vectorized store ----
    // Wave-private 16KB scratch strip: waves 0-3 in sA, 4-7 in sB (each
    // array is 64KB). Layout: [128 rows][8 chunks of 16B], phys chunk =
    // logical chunk ^ (row&7) to break the 128B-row bank alias.
    __syncthreads();   // all waves done with K-loop LDS reads
    unsigned short* scr = (w < 4) ? &sA[0][0][0] + w * 8192
                                  : &sB[0][0][0] + (w - 4) * 8192;

#pragma unroll
    for (int NI = 0; NI < 4; ++NI) {
        const int col = bn * 256 + wc * 64 + NI * 16 + lm;
        const float bv = (EPI == EPI_PART) ? 0.f : bias[col];
        const int c  = NI * 2 + (lm >> 3);   // logical 16B chunk (0..7)
        const int ci = lm & 7;               // bf16 within chunk
#pragma unroll
        for (int MI = 0; MI < 8; ++MI) {
#pragma unroll
            for (int r = 0; r < 4; ++r) {
                float v = acc[MI][NI][r] + bv;
                if (EPI == EPI_RELU) v = fmaxf(v, 0.f);
                const int row = MI * 16 + kq * 4 + r;   // 0..127
                scr[row * 64 + ((c ^ (row & 7)) * 8) + ci] =
                    __builtin_bit_cast(unsigned short, (__bf16)v);
            }
        }
    }
    // read back row-contiguous, store 16B/lane (full 128B lines per row)
#pragma unroll
    for (int it = 0; it < 16; ++it) {
        const int row = it * 8 + (l >> 3);   // 0..127
        const int lc  = l & 7;               // logical chunk
        const u16x8 vv = *(const u16x8*)&scr[row * 64 + ((lc ^ (row & 7)) * 8)];
        const int Crow = bm * 256 + wr * 128 + row;
        const int Ccol = bn * 256 + wc * 64 + lc * 8;
        *(u16x8*)((bf16*)out + (size_t)Crow * N + Ccol) = vv;
    }
}

// ---------------------------------------------------------------------------
// GEMM (128-class): C[M,N] = A[M,K] @ W[N,K]^T (+ bias). BM x 128 tile,
// BK=32, async global_load_lds dbuf, 1 barrier/iter. Used for QKV/out-proj.
// ---------------------------------------------------------------------------
template <int EPI, int BM>
__global__ __launch_bounds__(BM * 2, 2) void gemm_bt(
    const bf16* __restrict__ A, const bf16* __restrict__ W,
    const float* __restrict__ bias, const float* __restrict__ bias2,
    const float* __restrict__ res, void* __restrict__ out,
    int M, int N, int Kiter, int Kstride)
{
    constexpr int T    = BM * 2;
    constexpr int ISSA = (BM * 4) / T;
    constexpr int ISSB = 512 / T;
    constexpr int ROWS = T / 4;
    constexpr int MBK  = 4096 / BM;
    constexpr int MBX  = MBK / 8;
    constexpr int MBS  = (BM == 64) ? 3 : 2;

    __shared__ __align__(16) unsigned short sA[2][BM * 32];
    __shared__ __align__(16) unsigned short sB[2][128 * 32];

    const int t  = threadIdx.x;
    const int l  = t & 63;
    const int w  = t >> 6;
    const int wv = w * 64;
    const int wm = (w >> 1) * 64;
    const int wn = (w & 1) * 64;
    const int lm = l & 15;
    const int kq = l >> 4;

    int bx = blockIdx.x;
    const int xcd = bx & 7;
    const int ib  = bx >> 3;
    const int bm  = xcd * MBX + (ib & (MBX - 1));
    const int bn  = ib >> MBS;

    const bf16* gA = A + (size_t)(bm * BM + (t >> 2)) * Kstride + (t & 3) * 8;
    const bf16* gB = W + (size_t)(bn * 128 + (t >> 2)) * Kstride + (t & 3) * 8;

    int aoffs[4], boffs[4];
#pragma unroll
    for (int i = 0; i < 4; ++i) {
        aoffs[i] = (wm + i * 16 + lm) * 32 + kq * 8;
        boffs[i] = (wn + i * 16 + lm) * 32 + kq * 8;
    }

#define STAGE(buf, kk)                                                       \
    do {                                                                     \
        _Pragma("unroll")                                                    \
        for (int j = 0; j < ISSA; ++j)                                       \
            gld16(gA + (size_t)j * ROWS * Kstride + (kk),                    \
                  &sA[buf][(j * T + wv) * 8]);                               \
        _Pragma("unroll")                                                    \
        for (int j = 0; j < ISSB; ++j)                                       \
            gld16(gB + (size_t)j * ROWS * Kstride + (kk),                    \
                  &sB[buf][(j * T + wv) * 8]);                               \
    } while (0)

    STAGE(0, 0);
    __syncthreads();

    f32x4 acc[4][4] = {};

    for (int k0 = 0; k0 < Kiter; k0 += 32) {
        const int cur = (k0 >> 5) & 1;

        if (k0 + 32 < Kiter) STAGE(cur ^ 1, k0 + 32);

        bf16x8 af[4], bg[4];
#pragma unroll
        for (int i = 0; i < 4; ++i)
            af[i] = __builtin_bit_cast(bf16x8, *(const u16x8*)(&sA[cur][aoffs[i]]));
#pragma unroll
        for (int i = 0; i < 4; ++i)
            bg[i] = __builtin_bit_cast(bf16x8, *(const u16x8*)(&sB[cur][boffs[i]]));
#pragma unroll
        for (int mi = 0; mi < 4; ++mi)
#pragma unroll
            for (int ni = 0; ni < 4; ++ni)
                acc[mi][ni] = __builtin_amdgcn_mfma_f32_16x16x32_bf16(
                    af[mi], bg[ni], acc[mi][ni], 0, 0, 0);

        __syncthreads();
    }
#undef STAGE

#pragma unroll
    for (int ni = 0; ni < 4; ++ni) {
        const int col = bn * 128 + wn + ni * 16 + lm;
        float bv = 0.f;
        if (EPI == EPI_KV) bv = (col < 1024) ? bias[col] : bias2[col - 1024];
        else bv = bias[col];
#pragma unroll
        for (int mi = 0; mi < 4; ++mi) {
#pragma unroll
            for (int r = 0; r < 4; ++r) {
                const int row = bm * BM + wm + mi * 16 + kq * 4 + r;
                float v = acc[mi][ni][r] + bv;
                if (EPI == EPI_QSCALE) v *= 0.125f;
                if (EPI == EPI_KV) {
                    if (col < 1024) {
                        ((bf16*)out)[(size_t)row * 1024 + col] = __float2bfloat16(v);
                    } else {
                        const int ch = col - 1024;  // h*64 + d
                        const size_t idx = (size_t)4 * 1048576 +
                            ((size_t)((row >> 10) * 16 + (ch >> 6)) * 64 + (ch & 63)) * 1024
                            + (row & 1023);
                        ((bf16*)out)[idx] = __float2bfloat16(v);
                    }
                } else if (EPI == EPI_RES_F32_F32OUT) {
                    const size_t idx = (size_t)row * N + col;
                    ((float*)out)[idx] = v + res[idx];
                } else {
                    ((bf16*)out)[(size_t)row * N + col] = __float2bfloat16(v);
                }
            }
        }
    }
}

// ---------------------------------------------------------------------------
// FFN2 split-K reduce: out_f32 = x2 + b2 + sum_{c<4} (float)P[c].
// ---------------------------------------------------------------------------
__global__ __launch_bounds__(256) void ffn2_reduce(
    const bf16* __restrict__ P, const float* __restrict__ x2,
    const float* __restrict__ b2, float* __restrict__ out)
{
    const int i = (blockIdx.x * 256 + threadIdx.x) * 8;
    float v[8];
    {
        const float4 a = *(const float4*)(x2 + i);
        const float4 b = *(const float4*)(x2 + i + 4);
        v[0]=a.x; v[1]=a.y; v[2]=a.z; v[3]=a.w; v[4]=b.x; v[5]=b.y; v[6]=b.z; v[7]=b.w;
    }
    const int cb = i & 1023;
#pragma unroll
    for (int j = 0; j < 8; ++j) v[j] += b2[cb + j];
#pragma unroll
    for (int c = 0; c < 4; ++c) {
        const u16x8 u = *(const u16x8*)(P + (size_t)c * 4194304 + i);
        const bf16x8 pb = __builtin_bit_cast(bf16x8, u);
#pragma unroll
        for (int j = 0; j < 8; ++j) v[j] += (float)pb[j];
    }
    float4 o0 = {v[0], v[1], v[2], v[3]}, o1 = {v[4], v[5], v[6], v[7]};
    *(float4*)(out + i) = o0;
    *(float4*)(out + i + 4) = o1;
}

// ---------------------------------------------------------------------------
// Flash attention (MFMA). One block = (b,h) x 128 q-rows; 4 waves x 32 q-rows.
// Q,K,O: [B,T,H*64] bf16 (0.125 pre-folded into Q). Vt: [B,H,64(d),S] bf16.
// K/V staged via async global_load_lds; double-buffered LDS, 1 barrier/tile.
// ---------------------------------------------------------------------------
template <bool CAUSAL, bool SBIAS>
__global__ __launch_bounds__(256, 2) void flash_attn(
    const bf16* __restrict__ Q, const bf16* __restrict__ K,
    const bf16* __restrict__ Vt, bf16* __restrict__ O,
    const float* __restrict__ sbias, const float* __restrict__ scale_ptr)
{
    __shared__ __align__(16) unsigned short sK[2][64 * 64];
    __shared__ __align__(16) unsigned short sV[2][64 * 64];
    __shared__ __align__(16) unsigned short sP[4 * 32 * 72];

    const int t  = threadIdx.x;
    const int l  = t & 63;
    const int w  = t >> 6;
    const int wv = w * 64;
    const int lm = l & 15;
    const int kq = l >> 4;

    const int qb = blockIdx.x & 7;
    const int bh = blockIdx.x >> 3;
    const int h  = bh & 15;
    const int b  = bh >> 4;

    const int tb = qb * 128 + w * 32;
    const size_t qrow0 = (size_t)(b * 1024 + tb) * 1024 + h * 64;

    bf16x8 qf[2][2];
#pragma unroll
    for (int mi = 0; mi < 2; ++mi)
#pragma unroll
        for (int kk = 0; kk < 2; ++kk)
            qf[mi][kk] = __builtin_bit_cast(bf16x8,
                *(const u16x8*)(Q + qrow0 + (size_t)(mi * 16 + lm) * 1024 + kk * 32 + kq * 8));

    float cs = 0.f; const float* sb = nullptr;
    if (SBIAS) { cs = scale_ptr[0]; sb = sbias + b * 1024; }

    const bf16* gK = K  + (size_t)(b * 1024 + (t >> 2)) * 1024 + h * 64 + (t & 3) * 8;
    const bf16* gV = Vt + (size_t)((b * 16 + h) * 64 + (t >> 2)) * 1024 + (t & 3) * 8;
    __bf16* sPw = (__bf16*)sP + w * 32 * 72;

#define STAGE_KV(buf, s0r)                                              \
    do {                                                                \
        gld16(gK + (size_t)(s0r) * 1024,      &sK[buf][wv * 8]);        \
        gld16(gK + (size_t)(s0r) * 1024 + 32, &sK[buf][wv * 8 + 2048]); \
        gld16(gV + (s0r),                     &sV[buf][wv * 8]);        \
        gld16(gV + (s0r) + 32,                &sV[buf][wv * 8 + 2048]); \
    } while (0)

    const int niter = CAUSAL ? (2 * qb + 2) : 16;

    STAGE_KV(0, 0);
    __syncthreads();

    f32x4 acc_o[2][4] = {};
    f32x4 l_run[2] = {};

    for (int it = 0; it < niter; ++it) {
        const int s0 = it * 64;
        const int cur = it & 1;

        if (it + 1 < niter) STAGE_KV(cur ^ 1, s0 + 64);

        f32x4 accs[2][4] = {};
#pragma unroll
        for (int ni = 0; ni < 4; ++ni)
#pragma unroll
            for (int kk = 0; kk < 2; ++kk) {
                const bf16x8 kf = __builtin_bit_cast(bf16x8,
                    *(const u16x8*)(&sK[cur][kk * 2048 + (ni * 16 + lm) * 32 + kq * 8]));
#pragma unroll
                for (int mi = 0; mi < 2; ++mi)
                    accs[mi][ni] = __builtin_amdgcn_mfma_f32_16x16x32_bf16(
                        qf[mi][kk], kf, accs[mi][ni], 0, 0, 0);
            }

        if (SBIAS) {
#pragma unroll
            for (int ni = 0; ni < 4; ++ni) {
                const float sv = cs * sb[s0 + ni * 16 + lm];
#pragma unroll
                for (int mi = 0; mi < 2; ++mi)
#pragma unroll
                    for (int r = 0; r < 4; ++r) accs[mi][ni][r] += sv;
            }
        }
        if (CAUSAL && (s0 + 63 > tb)) {
#pragma unroll
            for (int ni = 0; ni < 4; ++ni) {
                const int s = s0 + ni * 16 + lm;
#pragma unroll
                for (int mi = 0; mi < 2; ++mi)
#pragma unroll
                    for (int r = 0; r < 4; ++r)
                        if (s > tb + mi * 16 + kq * 4 + r) accs[mi][ni][r] = -1e30f;
            }
        }

#pragma unroll
        for (int mi = 0; mi < 2; ++mi)
#pragma unroll
            for (int ni = 0; ni < 4; ++ni)
#pragma unroll
                for (int r = 0; r < 4; ++r) {
                    const float e = __expf(accs[mi][ni][r]);
                    l_run[mi][r] += e;
                    sPw[(mi * 16 + kq * 4 + r) * 72 + ni * 16 + lm] = (__bf16)e;
                }

#pragma unroll
        for (int kk = 0; kk < 2; ++kk) {
            bf16x8 pf[2];
#pragma unroll
            for (int mi = 0; mi < 2; ++mi)
                pf[mi] = __builtin_bit_cast(bf16x8,
                    *(const u16x8*)(sPw + (mi * 16 + lm) * 72 + kk * 32 + kq * 8));
#pragma unroll
            for (int di = 0; di < 4; ++di) {
                const bf16x8 vf = __builtin_bit_cast(bf16x8,
                    *(const u16x8*)(&sV[cur][kk * 2048 + (di * 16 + lm) * 32 + kq * 8]));
#pragma unroll
                for (int mi = 0; mi < 2; ++mi)
                    acc_o[mi][di] = __builtin_amdgcn_mfma_f32_16x16x32_bf16(
                        pf[mi], vf, acc_o[mi][di], 0, 0, 0);
            }
        }

        __syncthreads();
    }
#undef STAGE_KV

#pragma unroll
    for (int mi = 0; mi < 2; ++mi) {
        f32x4 lt = l_run[mi];
#pragma unroll
        for (int x = 1; x < 16; x <<= 1)
#pragma unroll
            for (int r = 0; r < 4; ++r) lt[r] += __shfl_xor(lt[r], x, 64);
#pragma unroll
        for (int r = 0; r < 4; ++r) lt[r] = 1.f / lt[r];
#pragma unroll
        for (int di = 0; di < 4; ++di)
#pragma unroll
            for (int r = 0; r < 4; ++r) {
                const size_t idx = (size_t)(b * 1024 + tb + mi * 16 + kq * 4 + r) * 1024
                                 + h * 64 + di * 16 + lm;
                O[idx] = __float2bfloat16(acc_o[mi][di][r] * lt[r]);
            }
    }
}

// ---------------------------------------------------------------------------
// LayerNorm over D=1024 (fp32 in, bf16 out), one block per row, 4 elems/thr.
// ---------------------------------------------------------------------------
__global__ __launch_bounds__(256) void ln_kernel(
    const float* __restrict__ xin, const float* __restrict__ g,
    const float* __restrict__ bta, bf16* __restrict__ out)
{
    const int row = blockIdx.x;
    const int t = threadIdx.x;
    const size_t base = (size_t)row * 1024 + t * 4;

    const float4 f = *(const float4*)(xin + base);
    const float v[4] = {f.x, f.y, f.z, f.w};
    float s1 = v[0] + v[1] + v[2] + v[3];
    float s2 = v[0]*v[0] + v[1]*v[1] + v[2]*v[2] + v[3]*v[3];
#pragma unroll
    for (int off = 32; off > 0; off >>= 1) {
        s1 += __shfl_xor(s1, off, 64);
        s2 += __shfl_xor(s2, off, 64);
    }
    __shared__ float r1[4], r2[4];
    if ((t & 63) == 0) { r1[t >> 6] = s1; r2[t >> 6] = s2; }
    __syncthreads();
    s1 = r1[0] + r1[1] + r1[2] + r1[3];
    s2 = r2[0] + r2[1] + r2[2] + r2[3];
    const float mean = s1 * (1.f / 1024.f);
    const float var  = s2 * (1.f / 1024.f) - mean * mean;
    const float rstd = rsqrtf(var + 1e-5f);
#pragma unroll
    for (int j = 0; j < 4; ++j) {
        const int c = t * 4 + j;
        out[base + j] = __float2bfloat16((v[j] - mean) * rstd * g[c] + bta[c]);
    }
}

// ---------------------------------------------------------------------------
extern "C" void kernel_launch(void* const* d_in, const int* in_sizes, int n_in,
                              void* d_out, int out_size, void* d_ws, size_t ws_size,
                              hipStream_t stream)
{
    const float* x       = (const float*)d_in[0];
    const float* memory  = (const float*)d_in[1];
    const float* sbias   = (const float*)d_in[2];
    const float* sa_bq = (const float*)d_in[7];
    const float* sa_bk = (const float*)d_in[9];
    const float* sa_bv = (const float*)d_in[11];
    const float* sa_bo = (const float*)d_in[13];
    const float* ca_bq = (const float*)d_in[16];
    const float* ca_bk = (const float*)d_in[18];
    const float* ca_bv = (const float*)d_in[20];
    const float* ca_bo = (const float*)d_in[22];
    const float* ca_scale = (const float*)d_in[23];
    const float* ln1_g = (const float*)d_in[24]; const float* ln1_b = (const float*)d_in[25];
    const float* ln2_g = (const float*)d_in[26]; const float* ln2_b = (const float*)d_in[27];
    const float* ln3_g = (const float*)d_in[28]; const float* ln3_b = (const float*)d_in[29];
    const float* b1 = (const float*)d_in[31];
    const float* b2 = (const float*)d_in[33];

    char* ws = (char*)d_ws;
    const size_t MB = (size_t)1 << 20;
    float* x1    = (float*)(ws + 0 * MB);
    float* x2    = (float*)(ws + 16 * MB);
    bf16* lnbuf  = (bf16*)(ws + 32 * MB);
    bf16* Qb     = (bf16*)(ws + 40 * MB);
    bf16* Kb     = (bf16*)(ws + 48 * MB);
    bf16* Vtb    = (bf16*)(ws + 56 * MB);
    bf16* Ob     = (bf16*)(ws + 64 * MB);
    bf16* ffnmid = (bf16*)(ws + 40 * MB);
    bf16* wx     = (bf16*)(ws + 72 * MB);
    bf16* wmem   = (bf16*)(ws + 80 * MB);
    bf16* bw     = (bf16*)(ws + 88 * MB);
    bf16* b_sa_wq = bw + 0 * 1048576, *b_sa_wk = bw + 1 * 1048576;
    bf16* b_sa_wo = bw + 3 * 1048576;
    bf16* b_ca_wq = bw + 4 * 1048576, *b_ca_wk = bw + 5 * 1048576;
    bf16* b_ca_wo = bw + 7 * 1048576;
    bf16* b_w1   = (bf16*)(ws + 104 * MB);
    bf16* b_w2   = (bf16*)(ws + 112 * MB);
    bf16* part   = (bf16*)(ws + 72 * MB);

    const int M = 4096;
    dim3 blk256(256), blk128(128), blk512(512);
    const dim3 gQ(512);
    const dim3 gKV(512);
    const dim3 gFA(512);
    const dim3 g256(256);   // FFN1: 16x16 tiles; FFN2: 4 chunks x 64 tiles

    CvtSrcs cs;
    for (int c = 0; c < 4; ++c) {
        cs.p[c]      = x + (size_t)c * 1048576;
        cs.p[4 + c]  = memory + (size_t)c * 1048576;
        cs.p[16 + c] = (const float*)d_in[30] + (size_t)c * 1048576;  // w1
        cs.p[20 + c] = (const float*)d_in[32] + (size_t)c * 1048576;  // w2
    }
    cs.p[8]  = (const float*)d_in[6];
    cs.p[9]  = (const float*)d_in[8];
    cs.p[10] = (const float*)d_in[10];
    cs.p[11] = (const float*)d_in[12];
    cs.p[12] = (const float*)d_in[15];
    cs.p[13] = (const float*)d_in[17];
    cs.p[14] = (const float*)d_in[19];
    cs.p[15] = (const float*)d_in[21];
    cvt_all<<<24 * 1048576 / 2048, blk256, 0, stream>>>(cs, wx);

    // ---- self-attention ----
    ln_kernel<<<4096, blk256, 0, stream>>>(x, ln1_g, ln1_b, lnbuf);
    gemm_bt<EPI_QSCALE, 64><<<gQ, blk128, 0, stream>>>(
        lnbuf, b_sa_wq, sa_bq, nullptr, nullptr, Qb, M, 1024, 1024, 1024);
    gemm_bt<EPI_KV, 128><<<gKV, blk256, 0, stream>>>(
        wx, b_sa_wk, sa_bk, sa_bv, nullptr, Kb, M, 2048, 1024, 1024);
    flash_attn<true, false><<<gFA, blk256, 0, stream>>>(Qb, Kb, Vtb, Ob, nullptr, nullptr);
    gemm_bt<EPI_RES_F32_F32OUT, 64><<<gQ, blk128, 0, stream>>>(
        Ob, b_sa_wo, sa_bo, nullptr, x, x1, M, 1024, 1024, 1024);

    // ---- cross-attention ----
    ln_kernel<<<4096, blk256, 0, stream>>>(x1, ln2_g, ln2_b, lnbuf);
    gemm_bt<EPI_QSCALE, 64><<<gQ, blk128, 0, stream>>>(
        lnbuf, b_ca_wq, ca_bq, nullptr, nullptr, Qb, M, 1024, 1024, 1024);
    gemm_bt<EPI_KV, 128><<<gKV, blk256, 0, stream>>>(
        wmem, b_ca_wk, ca_bk, ca_bv, nullptr, Kb, M, 2048, 1024, 1024);
    flash_attn<false, true><<<gFA, blk256, 0, stream>>>(Qb, Kb, Vtb, Ob, sbias, ca_scale);
    gemm_bt<EPI_RES_F32_F32OUT, 64><<<gQ, blk128, 0, stream>>>(
        Ob, b_ca_wo, ca_bo, nullptr, x1, x2, M, 1024, 1024, 1024);

    // ---- FFN ----
    ln_kernel<<<4096, blk256, 0, stream>>>(x2, ln3_g, ln3_b, lnbuf);
    gemm256<EPI_RELU><<<g256, blk512, 0, stream>>>(
        lnbuf, b_w1, b1, ffnmid, 4096, 1024, 1024);
    gemm256<EPI_PART><<<g256, blk512, 0, stream>>>(
        ffnmid, b_w2, nullptr, part, 1024, 1024, 4096);
    ffn2_reduce<<<2048, blk256, 0, stream>>>(part, x2, b2, (float*)d_out);
}

// Round 6
// 483.042 us; speedup vs baseline: 1.0391x; 1.0283x over previous
//
#include <hip/hip_runtime.h>
#include <hip/hip_bf16.h>
#include <cmath>
#include <stdint.h>

typedef __hip_bfloat16 bf16;
typedef __attribute__((ext_vector_type(8))) __bf16 bf16x8;
typedef __attribute__((ext_vector_type(8))) unsigned short u16x8;
typedef __attribute__((ext_vector_type(4))) float f32x4;

// Async global->LDS DMA, 16B per lane. LDS dest must be wave-uniform base;
// HW adds lane*16.
__device__ __forceinline__ void gld16(const void* g, const void* l)
{
    __builtin_amdgcn_global_load_lds(
        (const __attribute__((address_space(1))) unsigned int*)(unsigned long long)g,
        (__attribute__((address_space(3))) unsigned int*)(unsigned int)(unsigned long long)l,
        16, 0, 0);
}

// ---------------------------------------------------------------------------
// Fused fp32 -> bf16 conversion of all 12 tensors in one launch.
// ---------------------------------------------------------------------------
struct CvtSrcs { const float* p[24]; };

__global__ __launch_bounds__(256) void cvt_all(CvtSrcs s, bf16* __restrict__ dst)
{
    const int i = (blockIdx.x * 256 + threadIdx.x) * 8;
    const int seg = i >> 20;
    const float* sp = s.p[seg] + (i & 1048575);
    const float4 a = *(const float4*)(sp);
    const float4 b = *(const float4*)(sp + 4);
    const float v[8] = {a.x, a.y, a.z, a.w, b.x, b.y, b.z, b.w};
    bf16 tmp[8];
#pragma unroll
    for (int j = 0; j < 8; ++j) tmp[j] = __float2bfloat16(v[j]);
    *(uint4*)(dst + i) = *(const uint4*)tmp;
}

enum {
    EPI_QSCALE = 0,          // out_bf16 = (C + bias) * 0.125
    EPI_KV = 1,              // N=2048 fused: K plain / Vt transposed
    EPI_RELU = 2,            // out_bf16 = relu(C + bias)
    EPI_RES_F32_F32OUT = 3,  // out_f32  = res_f32 + C + bias
    EPI_PART = 4             // split-K=4 partial: out_bf16 = C (no bias)
};

// ---------------------------------------------------------------------------
// gemm256: C[4096,N] = A[4096,K] @ W[N,K]^T (+bias). 256x256 tile, BK=64,
// 512 thr = 8 waves (2M x 4N), per-wave 128x64 out. LDS 128KB: 2 slots x
// (A 256x64 + B 256x64), each as 2 halves of 128 rows.
// K-loop (R4, verified): counted-vmcnt 4-phase pipeline; tile tt+1 staged in
// quarters over tile tt's phases; vmcnt(2) waits at P0/P1; raw s_barrier
// only at P0/P1; never drains vmcnt to 0 in the main loop.
// Epilogue (R5, verified): LDS-bounce vectorized store (16B/lane lines).
// ---------------------------------------------------------------------------
template <int EPI>
__global__ __launch_bounds__(512, 2) void gemm256(
    const bf16* __restrict__ A, const bf16* __restrict__ W,
    const float* __restrict__ bias, void* __restrict__ out,
    int N, int Kiter, int Kstride)
{
    __shared__ __align__(16) unsigned short sA[2][2][128 * 64];  // [slot][half]
    __shared__ __align__(16) unsigned short sB[2][2][128 * 64];

    const int t  = threadIdx.x;          // 0..511
    const int l  = t & 63;
    const int w  = t >> 6;               // 0..7
    const int wv = w * 64;
    const int wr = w >> 2;               // 0..1 : M-half of block
    const int wc = w & 3;                // 0..3 : N-quarter of block
    const int lm = l & 15;
    const int kq = l >> 4;
    const int rx = lm & 7;               // read-side swizzle row bits

    int bx = blockIdx.x;
    if (EPI == EPI_PART) {
        const int chunk = bx >> 6;       // 4 chunks x 64 blocks
        bx &= 63;
        A += (size_t)chunk * 1024;       // K-offset within rows
        W += (size_t)chunk * 1024;
        out = (void*)((bf16*)out + (size_t)chunk * 4096 * 1024);
    }
    // XCD-aware: xcd owns 2 contiguous bm-bands; bm fastest within xcd.
    const int xcd = bx & 7;
    const int ib  = bx >> 3;
    const int bm  = xcd * 2 + (ib & 1);
    const int bn  = ib >> 1;

    // Staging source: thread t covers 16B = (row t>>3, phys slot t&7);
    // logical kslot = (t&7) ^ ((t>>3)&7)  (inverse-swizzled source).
    const bf16* gA = A + (size_t)(bm * 256 + (t >> 3)) * Kstride
                       + ((t & 7) ^ ((t >> 3) & 7)) * 8;
    const bf16* gB = W + (size_t)(bn * 256 + (t >> 3)) * Kstride
                       + ((t & 7) ^ ((t >> 3) & 7)) * 8;

    // stage one 64-row quarter j (0..3) of tile kt into slot
#define SQA(slot, kt, j)                                        \
    gld16(gA + (size_t)((j) * 64) * Kstride + (kt) * 64,        \
          &sA[slot][(j) >> 1][(((j) & 1) * 512 + wv) * 8])
#define SQB(slot, kt, j)                                        \
    gld16(gB + (size_t)((j) * 64) * Kstride + (kt) * 64,        \
          &sB[slot][(j) >> 1][(((j) & 1) * 512 + wv) * 8])

    bf16x8 af[4][2], bg[2][2];

#define READ_AF(s_, mh)                                                     \
    do {                                                                    \
        _Pragma("unroll")                                                   \
        for (int mi = 0; mi < 4; ++mi)                                      \
            _Pragma("unroll")                                               \
            for (int kk = 0; kk < 2; ++kk) {                                \
                const int lr = (mh) * 64 + mi * 16 + lm;                    \
                const int sl = ((kk << 2) | kq) ^ rx;                       \
                af[mi][kk] = __builtin_bit_cast(bf16x8,                     \
                    *(const u16x8*)(&sA[s_][wr][lr * 64 + sl * 8]));        \
            }                                                               \
    } while (0)
#define READ_BG(s_, nh)                                                     \
    do {                                                                    \
        _Pragma("unroll")                                                   \
        for (int ni = 0; ni < 2; ++ni)                                      \
            _Pragma("unroll")                                               \
            for (int kk = 0; kk < 2; ++kk) {                                \
                const int lr = (wc & 1) * 64 + (nh) * 32 + ni * 16 + lm;    \
                const int sl = ((kk << 2) | kq) ^ rx;                       \
                bg[ni][kk] = __builtin_bit_cast(bf16x8,                     \
                    *(const u16x8*)(&sB[s_][wc >> 1][lr * 64 + sl * 8]));   \
            }                                                               \
    } while (0)
#define MFMA_QUAD(mh, nh)                                                   \
    do {                                                                    \
        __builtin_amdgcn_s_setprio(1);                                      \
        _Pragma("unroll")                                                   \
        for (int mi = 0; mi < 4; ++mi)                                      \
            _Pragma("unroll")                                               \
            for (int ni = 0; ni < 2; ++ni)                                  \
                _Pragma("unroll")                                           \
                for (int kk = 0; kk < 2; ++kk)                              \
                    acc[(mh) * 4 + mi][(nh) * 2 + ni] =                     \
                        __builtin_amdgcn_mfma_f32_16x16x32_bf16(            \
                            af[mi][kk], bg[ni][kk],                         \
                            acc[(mh) * 4 + mi][(nh) * 2 + ni], 0, 0, 0);    \
        __builtin_amdgcn_s_setprio(0);                                      \
    } while (0)
#define BARRIER() do { __builtin_amdgcn_s_barrier();                        \
                       __builtin_amdgcn_sched_barrier(0); } while (0)
#define WAITV2() asm volatile("s_waitcnt vmcnt(2)" ::: "memory")
#define WAITV0() asm volatile("s_waitcnt vmcnt(0)" ::: "memory")

    f32x4 acc[8][4] = {};
    const int NT = Kiter >> 6;

    // prologue: tile 0 -> slot 0; issue order b0 b1 b2 b3 a0 a2 a1 a3
    SQB(0, 0, 0); SQB(0, 0, 1); SQB(0, 0, 2); SQB(0, 0, 3);
    SQA(0, 0, 0); SQA(0, 0, 2); SQA(0, 0, 1); SQA(0, 0, 3);

    for (int tt = 0; tt < NT - 1; ++tt) {
        const int s = tt & 1, d = s ^ 1, kn = tt + 1;
        // P0 (mh0,nh0): certify b0..b3,a0,a2 of tile tt
        WAITV2(); BARRIER();
        SQB(d, kn, 0); SQB(d, kn, 1);
        READ_AF(s, 0); READ_BG(s, 0);
        MFMA_QUAD(0, 0);
        // P1 (mh1,nh0): certify a1,a3 of tile tt
        WAITV2(); BARRIER();
        SQB(d, kn, 2); SQB(d, kn, 3);
        READ_AF(s, 1);
        MFMA_QUAD(1, 0);
        // P2 (mh1,nh1): af alive; bg nh1 certified since P0
        SQA(d, kn, 0); SQA(d, kn, 2);
        READ_BG(s, 1);
        MFMA_QUAD(1, 1);
        // P3 (mh0,nh1): re-read af mh0; bg alive
        SQA(d, kn, 1); SQA(d, kn, 3);
        READ_AF(s, 0);
        MFMA_QUAD(0, 1);
    }
    {   // final tile: no staging; P1 drains to 0 (vmcnt(2) would under-wait)
        const int s = (NT - 1) & 1;
        WAITV2(); BARRIER();
        READ_AF(s, 0); READ_BG(s, 0);
        MFMA_QUAD(0, 0);
        WAITV0(); BARRIER();
        READ_AF(s, 1);
        MFMA_QUAD(1, 0);
        READ_BG(s, 1);
        MFMA_QUAD(1, 1);
        READ_AF(s, 0);
        MFMA_QUAD(0, 1);
    }
#undef SQA
#undef SQB
#undef READ_AF
#undef READ_BG
#undef MFMA_QUAD
#undef BARRIER
#undef WAITV2
#undef WAITV0

    // ---- Epilogue (R5): LDS-bounce vectorized store ----
    __syncthreads();   // all waves done with K-loop LDS reads
    unsigned short* scr = (w < 4) ? &sA[0][0][0] + w * 8192
                                  : &sB[0][0][0] + (w - 4) * 8192;

#pragma unroll
    for (int NI = 0; NI < 4; ++NI) {
        const int col = bn * 256 + wc * 64 + NI * 16 + lm;
        const float bv = (EPI == EPI_PART) ? 0.f : bias[col];
        const int c  = NI * 2 + (lm >> 3);   // logical 16B chunk (0..7)
        const int ci = lm & 7;               // bf16 within chunk
#pragma unroll
        for (int MI = 0; MI < 8; ++MI) {
#pragma unroll
            for (int r = 0; r < 4; ++r) {
                float v = acc[MI][NI][r] + bv;
                if (EPI == EPI_RELU) v = fmaxf(v, 0.f);
                const int row = MI * 16 + kq * 4 + r;   // 0..127
                scr[row * 64 + ((c ^ (row & 7)) * 8) + ci] =
                    __builtin_bit_cast(unsigned short, (__bf16)v);
            }
        }
    }
    // read back row-contiguous, store 16B/lane (full 128B lines per row)
#pragma unroll
    for (int it = 0; it < 16; ++it) {
        const int row = it * 8 + (l >> 3);   // 0..127
        const int lc  = l & 7;               // logical chunk
        const u16x8 vv = *(const u16x8*)&scr[row * 64 + ((lc ^ (row & 7)) * 8)];
        const int Crow = bm * 256 + wr * 128 + row;
        const int Ccol = bn * 256 + wc * 64 + lc * 8;
        *(u16x8*)((bf16*)out + (size_t)Crow * N + Ccol) = vv;
    }
}

// ---------------------------------------------------------------------------
// GEMM (128-class): C[M,N] = A[M,K] @ W[N,K]^T (+ bias). BM x 128 tile,
// BK=32, async global_load_lds dbuf, 1 barrier/iter. Used for QKV/out-proj.
// ---------------------------------------------------------------------------
template <int EPI, int BM>
__global__ __launch_bounds__(BM * 2, 2) void gemm_bt(
    const bf16* __restrict__ A, const bf16* __restrict__ W,
    const float* __restrict__ bias, const float* __restrict__ bias2,
    const float* __restrict__ res, void* __restrict__ out,
    int M, int N, int Kiter, int Kstride)
{
    constexpr int T    = BM * 2;
    constexpr int ISSA = (BM * 4) / T;
    constexpr int ISSB = 512 / T;
    constexpr int ROWS = T / 4;
    constexpr int MBK  = 4096 / BM;
    constexpr int MBX  = MBK / 8;
    constexpr int MBS  = (BM == 64) ? 3 : 2;

    __shared__ __align__(16) unsigned short sA[2][BM * 32];
    __shared__ __align__(16) unsigned short sB[2][128 * 32];

    const int t  = threadIdx.x;
    const int l  = t & 63;
    const int w  = t >> 6;
    const int wv = w * 64;
    const int wm = (w >> 1) * 64;
    const int wn = (w & 1) * 64;
    const int lm = l & 15;
    const int kq = l >> 4;

    int bx = blockIdx.x;
    const int xcd = bx & 7;
    const int ib  = bx >> 3;
    const int bm  = xcd * MBX + (ib & (MBX - 1));
    const int bn  = ib >> MBS;

    const bf16* gA = A + (size_t)(bm * BM + (t >> 2)) * Kstride + (t & 3) * 8;
    const bf16* gB = W + (size_t)(bn * 128 + (t >> 2)) * Kstride + (t & 3) * 8;

    int aoffs[4], boffs[4];
#pragma unroll
    for (int i = 0; i < 4; ++i) {
        aoffs[i] = (wm + i * 16 + lm) * 32 + kq * 8;
        boffs[i] = (wn + i * 16 + lm) * 32 + kq * 8;
    }

#define STAGE(buf, kk)                                                       \
    do {                                                                     \
        _Pragma("unroll")                                                    \
        for (int j = 0; j < ISSA; ++j)                                       \
            gld16(gA + (size_t)j * ROWS * Kstride + (kk),                    \
                  &sA[buf][(j * T + wv) * 8]);                               \
        _Pragma("unroll")                                                    \
        for (int j = 0; j < ISSB; ++j)                                       \
            gld16(gB + (size_t)j * ROWS * Kstride + (kk),                    \
                  &sB[buf][(j * T + wv) * 8]);                               \
    } while (0)

    STAGE(0, 0);
    __syncthreads();

    f32x4 acc[4][4] = {};

    for (int k0 = 0; k0 < Kiter; k0 += 32) {
        const int cur = (k0 >> 5) & 1;

        if (k0 + 32 < Kiter) STAGE(cur ^ 1, k0 + 32);

        bf16x8 af[4], bg[4];
#pragma unroll
        for (int i = 0; i < 4; ++i)
            af[i] = __builtin_bit_cast(bf16x8, *(const u16x8*)(&sA[cur][aoffs[i]]));
#pragma unroll
        for (int i = 0; i < 4; ++i)
            bg[i] = __builtin_bit_cast(bf16x8, *(const u16x8*)(&sB[cur][boffs[i]]));
#pragma unroll
        for (int mi = 0; mi < 4; ++mi)
#pragma unroll
            for (int ni = 0; ni < 4; ++ni)
                acc[mi][ni] = __builtin_amdgcn_mfma_f32_16x16x32_bf16(
                    af[mi], bg[ni], acc[mi][ni], 0, 0, 0);

        __syncthreads();
    }
#undef STAGE

#pragma unroll
    for (int ni = 0; ni < 4; ++ni) {
        const int col = bn * 128 + wn + ni * 16 + lm;
        float bv = 0.f;
        if (EPI == EPI_KV) bv = (col < 1024) ? bias[col] : bias2[col - 1024];
        else bv = bias[col];
#pragma unroll
        for (int mi = 0; mi < 4; ++mi) {
#pragma unroll
            for (int r = 0; r < 4; ++r) {
                const int row = bm * BM + wm + mi * 16 + kq * 4 + r;
                float v = acc[mi][ni][r] + bv;
                if (EPI == EPI_QSCALE) v *= 0.125f;
                if (EPI == EPI_KV) {
                    if (col < 1024) {
                        ((bf16*)out)[(size_t)row * 1024 + col] = __float2bfloat16(v);
                    } else {
                        const int ch = col - 1024;  // h*64 + d
                        const size_t idx = (size_t)4 * 1048576 +
                            ((size_t)((row >> 10) * 16 + (ch >> 6)) * 64 + (ch & 63)) * 1024
                            + (row & 1023);
                        ((bf16*)out)[idx] = __float2bfloat16(v);
                    }
                } else if (EPI == EPI_RES_F32_F32OUT) {
                    const size_t idx = (size_t)row * N + col;
                    ((float*)out)[idx] = v + res[idx];
                } else {
                    ((bf16*)out)[(size_t)row * N + col] = __float2bfloat16(v);
                }
            }
        }
    }
}

// ---------------------------------------------------------------------------
// FFN2 split-K reduce: out_f32 = x2 + b2 + sum_{c<4} (float)P[c].
// ---------------------------------------------------------------------------
__global__ __launch_bounds__(256) void ffn2_reduce(
    const bf16* __restrict__ P, const float* __restrict__ x2,
    const float* __restrict__ b2, float* __restrict__ out)
{
    const int i = (blockIdx.x * 256 + threadIdx.x) * 8;
    float v[8];
    {
        const float4 a = *(const float4*)(x2 + i);
        const float4 b = *(const float4*)(x2 + i + 4);
        v[0]=a.x; v[1]=a.y; v[2]=a.z; v[3]=a.w; v[4]=b.x; v[5]=b.y; v[6]=b.z; v[7]=b.w;
    }
    const int cb = i & 1023;
#pragma unroll
    for (int j = 0; j < 8; ++j) v[j] += b2[cb + j];
#pragma unroll
    for (int c = 0; c < 4; ++c) {
        const u16x8 u = *(const u16x8*)(P + (size_t)c * 4194304 + i);
        const bf16x8 pb = __builtin_bit_cast(bf16x8, u);
#pragma unroll
        for (int j = 0; j < 8; ++j) v[j] += (float)pb[j];
    }
    float4 o0 = {v[0], v[1], v[2], v[3]}, o1 = {v[4], v[5], v[6], v[7]};
    *(float4*)(out + i) = o0;
    *(float4*)(out + i + 4) = o1;
}

// ---------------------------------------------------------------------------
// Flash attention (MFMA). One block = (b,h) x 128 q-rows; 4 waves x 32 q-rows.
// Q,K,O: [B,T,H*64] bf16 (0.125 pre-folded into Q). Vt: [B,H,64(d),S] bf16.
// R6a: XCD-local block remap — bh = bid&63, qb = bid>>6, so the 8 q-blocks
// sharing one (b,h)'s K/V (256KB) land on the SAME XCD (bid%8 == bh%8);
// was qb=bid&7 which spread them over 8 XCDs -> 70MB FETCH (3x ideal).
// R6b: sK/sV as single [64][64] tiles (128B rows) with the gemm256-proven
// XOR swizzle (phys 16B-slot = logical ^ (row&7); linear gld16 dest +
// inverse-swizzled global source + swizzled read). Old 64B-row layout had
// 8-way bank conflicts on every K/V fragment read (2.6M measured).
// ---------------------------------------------------------------------------
template <bool CAUSAL, bool SBIAS>
__global__ __launch_bounds__(256, 2) void flash_attn(
    const bf16* __restrict__ Q, const bf16* __restrict__ K,
    const bf16* __restrict__ Vt, bf16* __restrict__ O,
    const float* __restrict__ sbias, const float* __restrict__ scale_ptr)
{
    __shared__ __align__(16) unsigned short sK[2][64 * 64];
    __shared__ __align__(16) unsigned short sV[2][64 * 64];
    __shared__ __align__(16) unsigned short sP[4 * 32 * 72];

    const int t  = threadIdx.x;
    const int l  = t & 63;
    const int w  = t >> 6;
    const int wv = w * 64;
    const int lm = l & 15;
    const int kq = l >> 4;

    const int bh = blockIdx.x & 63;      // same-XCD for all 8 q-blocks of bh
    const int qb = blockIdx.x >> 6;
    const int h  = bh & 15;
    const int b  = bh >> 4;

    const int tb = qb * 128 + w * 32;
    const size_t qrow0 = (size_t)(b * 1024 + tb) * 1024 + h * 64;

    bf16x8 qf[2][2];
#pragma unroll
    for (int mi = 0; mi < 2; ++mi)
#pragma unroll
        for (int kk = 0; kk < 2; ++kk)
            qf[mi][kk] = __builtin_bit_cast(bf16x8,
                *(const u16x8*)(Q + qrow0 + (size_t)(mi * 16 + lm) * 1024 + kk * 32 + kq * 8));

    float cs = 0.f; const float* sb = nullptr;
    if (SBIAS) { cs = scale_ptr[0]; sb = sbias + b * 1024; }

    // Staging source (swizzled): thread t covers 16B at (row t>>3, phys slot
    // t&7) of a 32-row sweep; logical slot = (t&7)^((t>>3)&7).
    const bf16* gK = K  + (size_t)(b * 1024 + (t >> 3)) * 1024 + h * 64
                   + ((t & 7) ^ ((t >> 3) & 7)) * 8;
    const bf16* gV = Vt + (size_t)((b * 16 + h) * 64 + (t >> 3)) * 1024
                   + ((t & 7) ^ ((t >> 3) & 7)) * 8;
    __bf16* sPw = (__bf16*)sP + w * 32 * 72;

    // K tile: rows = s (64), cols = d (64). V tile: rows = d (64), cols = s.
#define STAGE_KV(buf, s0r)                                                   \
    do {                                                                     \
        gld16(gK + (size_t)(s0r) * 1024,        &sK[buf][wv * 8]);           \
        gld16(gK + (size_t)((s0r) + 32) * 1024, &sK[buf][2048 + wv * 8]);    \
        gld16(gV + (s0r),                       &sV[buf][wv * 8]);           \
        gld16(gV + (s0r) + 32 * 1024,           &sV[buf][2048 + wv * 8]);    \
    } while (0)

    const int niter = CAUSAL ? (2 * qb + 2) : 16;

    STAGE_KV(0, 0);
    __syncthreads();

    f32x4 acc_o[2][4] = {};
    f32x4 l_run[2] = {};

    for (int it = 0; it < niter; ++it) {
        const int s0 = it * 64;
        const int cur = it & 1;

        if (it + 1 < niter) STAGE_KV(cur ^ 1, s0 + 64);

        f32x4 accs[2][4] = {};
#pragma unroll
        for (int ni = 0; ni < 4; ++ni)
#pragma unroll
            for (int kk = 0; kk < 2; ++kk) {
                const bf16x8 kf = __builtin_bit_cast(bf16x8,
                    *(const u16x8*)(&sK[cur][(ni * 16 + lm) * 64
                        + ((((kk << 2) | kq)) ^ (lm & 7)) * 8]));
#pragma unroll
                for (int mi = 0; mi < 2; ++mi)
                    accs[mi][ni] = __builtin_amdgcn_mfma_f32_16x16x32_bf16(
                        qf[mi][kk], kf, accs[mi][ni], 0, 0, 0);
            }

        if (SBIAS) {
#pragma unroll
            for (int ni = 0; ni < 4; ++ni) {
                const float sv = cs * sb[s0 + ni * 16 + lm];
#pragma unroll
                for (int mi = 0; mi < 2; ++mi)
#pragma unroll
                    for (int r = 0; r < 4; ++r) accs[mi][ni][r] += sv;
            }
        }
        if (CAUSAL && (s0 + 63 > tb)) {
#pragma unroll
            for (int ni = 0; ni < 4; ++ni) {
                const int s = s0 + ni * 16 + lm;
#pragma unroll
                for (int mi = 0; mi < 2; ++mi)
#pragma unroll
                    for (int r = 0; r < 4; ++r)
                        if (s > tb + mi * 16 + kq * 4 + r) accs[mi][ni][r] = -1e30f;
            }
        }

#pragma unroll
        for (int mi = 0; mi < 2; ++mi)
#pragma unroll
            for (int ni = 0; ni < 4; ++ni)
#pragma unroll
                for (int r = 0; r < 4; ++r) {
                    const float e = __expf(accs[mi][ni][r]);
                    l_run[mi][r] += e;
                    sPw[(mi * 16 + kq * 4 + r) * 72 + ni * 16 + lm] = (__bf16)e;
                }

#pragma unroll
        for (int kk = 0; kk < 2; ++kk) {
            bf16x8 pf[2];
#pragma unroll
            for (int mi = 0; mi < 2; ++mi)
                pf[mi] = __builtin_bit_cast(bf16x8,
                    *(const u16x8*)(sPw + (mi * 16 + lm) * 72 + kk * 32 + kq * 8));
#pragma unroll
            for (int di = 0; di < 4; ++di) {
                const bf16x8 vf = __builtin_bit_cast(bf16x8,
                    *(const u16x8*)(&sV[cur][(di * 16 + lm) * 64
                        + ((((kk << 2) | kq)) ^ (lm & 7)) * 8]));
#pragma unroll
                for (int mi = 0; mi < 2; ++mi)
                    acc_o[mi][di] = __builtin_amdgcn_mfma_f32_16x16x32_bf16(
                        pf[mi], vf, acc_o[mi][di], 0, 0, 0);
            }
        }

        __syncthreads();
    }
#undef STAGE_KV

#pragma unroll
    for (int mi = 0; mi < 2; ++mi) {
        f32x4 lt = l_run[mi];
#pragma unroll
        for (int x = 1; x < 16; x <<= 1)
#pragma unroll
            for (int r = 0; r < 4; ++r) lt[r] += __shfl_xor(lt[r], x, 64);
#pragma unroll
        for (int r = 0; r < 4; ++r) lt[r] = 1.f / lt[r];
#pragma unroll
        for (int di = 0; di < 4; ++di)
#pragma unroll
            for (int r = 0; r < 4; ++r) {
                const size_t idx = (size_t)(b * 1024 + tb + mi * 16 + kq * 4 + r) * 1024
                                 + h * 64 + di * 16 + lm;
                O[idx] = __float2bfloat16(acc_o[mi][di][r] * lt[r]);
            }
    }
}

// ---------------------------------------------------------------------------
// LayerNorm over D=1024 (fp32 in, bf16 out), one block per row, 4 elems/thr.
// ---------------------------------------------------------------------------
__global__ __launch_bounds__(256) void ln_kernel(
    const float* __restrict__ xin, const float* __restrict__ g,
    const float* __restrict__ bta, bf16* __restrict__ out)
{
    const int row = blockIdx.x;
    const int t = threadIdx.x;
    const size_t base = (size_t)row * 1024 + t * 4;

    const float4 f = *(const float4*)(xin + base);
    const float v[4] = {f.x, f.y, f.z, f.w};
    float s1 = v[0] + v[1] + v[2] + v[3];
    float s2 = v[0]*v[0] + v[1]*v[1] + v[2]*v[2] + v[3]*v[3];
#pragma unroll
    for (int off = 32; off > 0; off >>= 1) {
        s1 += __shfl_xor(s1, off, 64);
        s2 += __shfl_xor(s2, off, 64);
    }
    __shared__ float r1[4], r2[4];
    if ((t & 63) == 0) { r1[t >> 6] = s1; r2[t >> 6] = s2; }
    __syncthreads();
    s1 = r1[0] + r1[1] + r1[2] + r1[3];
    s2 = r2[0] + r2[1] + r2[2] + r2[3];
    const float mean = s1 * (1.f / 1024.f);
    const float var  = s2 * (1.f / 1024.f) - mean * mean;
    const float rstd = rsqrtf(var + 1e-5f);
#pragma unroll
    for (int j = 0; j < 4; ++j) {
        const int c = t * 4 + j;
        out[base + j] = __float2bfloat16((v[j] - mean) * rstd * g[c] + bta[c]);
    }
}

// ---------------------------------------------------------------------------
extern "C" void kernel_launch(void* const* d_in, const int* in_sizes, int n_in,
                              void* d_out, int out_size, void* d_ws, size_t ws_size,
                              hipStream_t stream)
{
    const float* x       = (const float*)d_in[0];
    const float* memory  = (const float*)d_in[1];
    const float* sbias   = (const float*)d_in[2];
    const float* sa_bq = (const float*)d_in[7];
    const float* sa_bk = (const float*)d_in[9];
    const float* sa_bv = (const float*)d_in[11];
    const float* sa_bo = (const float*)d_in[13];
    const float* ca_bq = (const float*)d_in[16];
    const float* ca_bk = (const float*)d_in[18];
    const float* ca_bv = (const float*)d_in[20];
    const float* ca_bo = (const float*)d_in[22];
    const float* ca_scale = (const float*)d_in[23];
    const float* ln1_g = (const float*)d_in[24]; const float* ln1_b = (const float*)d_in[25];
    const float* ln2_g = (const float*)d_in[26]; const float* ln2_b = (const float*)d_in[27];
    const float* ln3_g = (const float*)d_in[28]; const float* ln3_b = (const float*)d_in[29];
    const float* b1 = (const float*)d_in[31];
    const float* b2 = (const float*)d_in[33];

    char* ws = (char*)d_ws;
    const size_t MB = (size_t)1 << 20;
    float* x1    = (float*)(ws + 0 * MB);
    float* x2    = (float*)(ws + 16 * MB);
    bf16* lnbuf  = (bf16*)(ws + 32 * MB);
    bf16* Qb     = (bf16*)(ws + 40 * MB);
    bf16* Kb     = (bf16*)(ws + 48 * MB);
    bf16* Vtb    = (bf16*)(ws + 56 * MB);
    bf16* Ob     = (bf16*)(ws + 64 * MB);
    bf16* ffnmid = (bf16*)(ws + 40 * MB);
    bf16* wx     = (bf16*)(ws + 72 * MB);
    bf16* wmem   = (bf16*)(ws + 80 * MB);
    bf16* bw     = (bf16*)(ws + 88 * MB);
    bf16* b_sa_wq = bw + 0 * 1048576, *b_sa_wk = bw + 1 * 1048576;
    bf16* b_sa_wo = bw + 3 * 1048576;
    bf16* b_ca_wq = bw + 4 * 1048576, *b_ca_wk = bw + 5 * 1048576;
    bf16* b_ca_wo = bw + 7 * 1048576;
    bf16* b_w1   = (bf16*)(ws + 104 * MB);
    bf16* b_w2   = (bf16*)(ws + 112 * MB);
    bf16* part   = (bf16*)(ws + 72 * MB);

    const int M = 4096;
    dim3 blk256(256), blk128(128), blk512(512);
    const dim3 gQ(512);
    const dim3 gKV(512);
    const dim3 gFA(512);
    const dim3 g256(256);   // FFN1: 16x16 tiles; FFN2: 4 chunks x 64 tiles

    CvtSrcs cs;
    for (int c = 0; c < 4; ++c) {
        cs.p[c]      = x + (size_t)c * 1048576;
        cs.p[4 + c]  = memory + (size_t)c * 1048576;
        cs.p[16 + c] = (const float*)d_in[30] + (size_t)c * 1048576;  // w1
        cs.p[20 + c] = (const float*)d_in[32] + (size_t)c * 1048576;  // w2
    }
    cs.p[8]  = (const float*)d_in[6];
    cs.p[9]  = (const float*)d_in[8];
    cs.p[10] = (const float*)d_in[10];
    cs.p[11] = (const float*)d_in[12];
    cs.p[12] = (const float*)d_in[15];
    cs.p[13] = (const float*)d_in[17];
    cs.p[14] = (const float*)d_in[19];
    cs.p[15] = (const float*)d_in[21];
    cvt_all<<<24 * 1048576 / 2048, blk256, 0, stream>>>(cs, wx);

    // ---- self-attention ----
    ln_kernel<<<4096, blk256, 0, stream>>>(x, ln1_g, ln1_b, lnbuf);
    gemm_bt<EPI_QSCALE, 64><<<gQ, blk128, 0, stream>>>(
        lnbuf, b_sa_wq, sa_bq, nullptr, nullptr, Qb, M, 1024, 1024, 1024);
    gemm_bt<EPI_KV, 128><<<gKV, blk256, 0, stream>>>(
        wx, b_sa_wk, sa_bk, sa_bv, nullptr, Kb, M, 2048, 1024, 1024);
    flash_attn<true, false><<<gFA, blk256, 0, stream>>>(Qb, Kb, Vtb, Ob, nullptr, nullptr);
    gemm_bt<EPI_RES_F32_F32OUT, 64><<<gQ, blk128, 0, stream>>>(
        Ob, b_sa_wo, sa_bo, nullptr, x, x1, M, 1024, 1024, 1024);

    // ---- cross-attention ----
    ln_kernel<<<4096, blk256, 0, stream>>>(x1, ln2_g, ln2_b, lnbuf);
    gemm_bt<EPI_QSCALE, 64><<<gQ, blk128, 0, stream>>>(
        lnbuf, b_ca_wq, ca_bq, nullptr, nullptr, Qb, M, 1024, 1024, 1024);
    gemm_bt<EPI_KV, 128><<<gKV, blk256, 0, stream>>>(
        wmem, b_ca_wk, ca_bk, ca_bv, nullptr, Kb, M, 2048, 1024, 1024);
    flash_attn<false, true><<<gFA, blk256, 0, stream>>>(Qb, Kb, Vtb, Ob, sbias, ca_scale);
    gemm_bt<EPI_RES_F32_F32OUT, 64><<<gQ, blk128, 0, stream>>>(
        Ob, b_ca_wo, ca_bo, nullptr, x1, x2, M, 1024, 1024, 1024);

    // ---- FFN ----
    ln_kernel<<<4096, blk256, 0, stream>>>(x2, ln3_g, ln3_b, lnbuf);
    gemm256<EPI_RELU><<<g256, blk512, 0, stream>>>(
        lnbuf, b_w1, b1, ffnmid, 4096, 1024, 1024);
    gemm256<EPI_PART><<<g256, blk512, 0, stream>>>(
        ffnmid, b_w2, nullptr, part, 1024, 1024, 4096);
    ffn2_reduce<<<2048, blk256, 0, stream>>>(part, x2, b2, (float*)d_out);
}

// Round 7
// 478.087 us; speedup vs baseline: 1.0498x; 1.0104x over previous
//
#include <hip/hip_runtime.h>
#include <hip/hip_bf16.h>
#include <cmath>
#include <stdint.h>

typedef __hip_bfloat16 bf16;
typedef __attribute__((ext_vector_type(8))) __bf16 bf16x8;
typedef __attribute__((ext_vector_type(8))) unsigned short u16x8;
typedef __attribute__((ext_vector_type(4))) float f32x4;

// Async global->LDS DMA, 16B per lane. LDS dest must be wave-uniform base;
// HW adds lane*16.
__device__ __forceinline__ void gld16(const void* g, const void* l)
{
    __builtin_amdgcn_global_load_lds(
        (const __attribute__((address_space(1))) unsigned int*)(unsigned long long)g,
        (__attribute__((address_space(3))) unsigned int*)(unsigned int)(unsigned long long)l,
        16, 0, 0);
}

// ---------------------------------------------------------------------------
// Fused fp32 -> bf16 conversion of all 12 tensors in one launch.
// ---------------------------------------------------------------------------
struct CvtSrcs { const float* p[24]; };

__global__ __launch_bounds__(256) void cvt_all(CvtSrcs s, bf16* __restrict__ dst)
{
    const int i = (blockIdx.x * 256 + threadIdx.x) * 8;
    const int seg = i >> 20;
    const float* sp = s.p[seg] + (i & 1048575);
    const float4 a = *(const float4*)(sp);
    const float4 b = *(const float4*)(sp + 4);
    const float v[8] = {a.x, a.y, a.z, a.w, b.x, b.y, b.z, b.w};
    bf16 tmp[8];
#pragma unroll
    for (int j = 0; j < 8; ++j) tmp[j] = __float2bfloat16(v[j]);
    *(uint4*)(dst + i) = *(const uint4*)tmp;
}

enum {
    EPI_QSCALE = 0,          // out_bf16 = (C + bias) * 0.125
    EPI_KV = 1,              // N=2048 fused: K plain / Vt transposed
    EPI_RELU = 2,            // out_bf16 = relu(C + bias)
    EPI_RES_F32_F32OUT = 3,  // out_f32  = res_f32 + C + bias
    EPI_PART = 4             // split-K=4 partial: out_bf16 = C (no bias)
};

// ---------------------------------------------------------------------------
// gemm256: C[4096,N] = A[4096,K] @ W[N,K]^T (+bias). 256x256 tile, BK=64,
// 512 thr = 8 waves (2M x 4N), per-wave 128x64 out. LDS 128KB: 2 slots x
// (A 256x64 + B 256x64), each as 2 halves of 128 rows.
// K-loop (R4, verified): counted-vmcnt 4-phase pipeline; tile tt+1 staged in
// quarters over tile tt's phases; vmcnt(2) waits at P0/P1; raw s_barrier
// only at P0/P1; never drains vmcnt to 0 in the main loop.
// Epilogue (R5, verified): LDS-bounce vectorized store (16B/lane lines).
// ---------------------------------------------------------------------------
template <int EPI>
__global__ __launch_bounds__(512, 2) void gemm256(
    const bf16* __restrict__ A, const bf16* __restrict__ W,
    const float* __restrict__ bias, void* __restrict__ out,
    int N, int Kiter, int Kstride)
{
    __shared__ __align__(16) unsigned short sA[2][2][128 * 64];  // [slot][half]
    __shared__ __align__(16) unsigned short sB[2][2][128 * 64];

    const int t  = threadIdx.x;          // 0..511
    const int l  = t & 63;
    const int w  = t >> 6;               // 0..7
    const int wv = w * 64;
    const int wr = w >> 2;               // 0..1 : M-half of block
    const int wc = w & 3;                // 0..3 : N-quarter of block
    const int lm = l & 15;
    const int kq = l >> 4;
    const int rx = lm & 7;               // read-side swizzle row bits

    int bx = blockIdx.x;
    if (EPI == EPI_PART) {
        const int chunk = bx >> 6;       // 4 chunks x 64 blocks
        bx &= 63;
        A += (size_t)chunk * 1024;       // K-offset within rows
        W += (size_t)chunk * 1024;
        out = (void*)((bf16*)out + (size_t)chunk * 4096 * 1024);
    }
    // XCD-aware: xcd owns 2 contiguous bm-bands; bm fastest within xcd.
    const int xcd = bx & 7;
    const int ib  = bx >> 3;
    const int bm  = xcd * 2 + (ib & 1);
    const int bn  = ib >> 1;

    // Staging source: thread t covers 16B = (row t>>3, phys slot t&7);
    // logical kslot = (t&7) ^ ((t>>3)&7)  (inverse-swizzled source).
    const bf16* gA = A + (size_t)(bm * 256 + (t >> 3)) * Kstride
                       + ((t & 7) ^ ((t >> 3) & 7)) * 8;
    const bf16* gB = W + (size_t)(bn * 256 + (t >> 3)) * Kstride
                       + ((t & 7) ^ ((t >> 3) & 7)) * 8;

    // stage one 64-row quarter j (0..3) of tile kt into slot
#define SQA(slot, kt, j)                                        \
    gld16(gA + (size_t)((j) * 64) * Kstride + (kt) * 64,        \
          &sA[slot][(j) >> 1][(((j) & 1) * 512 + wv) * 8])
#define SQB(slot, kt, j)                                        \
    gld16(gB + (size_t)((j) * 64) * Kstride + (kt) * 64,        \
          &sB[slot][(j) >> 1][(((j) & 1) * 512 + wv) * 8])

    bf16x8 af[4][2], bg[2][2];

#define READ_AF(s_, mh)                                                     \
    do {                                                                    \
        _Pragma("unroll")                                                   \
        for (int mi = 0; mi < 4; ++mi)                                      \
            _Pragma("unroll")                                               \
            for (int kk = 0; kk < 2; ++kk) {                                \
                const int lr = (mh) * 64 + mi * 16 + lm;                    \
                const int sl = ((kk << 2) | kq) ^ rx;                       \
                af[mi][kk] = __builtin_bit_cast(bf16x8,                     \
                    *(const u16x8*)(&sA[s_][wr][lr * 64 + sl * 8]));        \
            }                                                               \
    } while (0)
#define READ_BG(s_, nh)                                                     \
    do {                                                                    \
        _Pragma("unroll")                                                   \
        for (int ni = 0; ni < 2; ++ni)                                      \
            _Pragma("unroll")                                               \
            for (int kk = 0; kk < 2; ++kk) {                                \
                const int lr = (wc & 1) * 64 + (nh) * 32 + ni * 16 + lm;    \
                const int sl = ((kk << 2) | kq) ^ rx;                       \
                bg[ni][kk] = __builtin_bit_cast(bf16x8,                     \
                    *(const u16x8*)(&sB[s_][wc >> 1][lr * 64 + sl * 8]));   \
            }                                                               \
    } while (0)
#define MFMA_QUAD(mh, nh)                                                   \
    do {                                                                    \
        __builtin_amdgcn_s_setprio(1);                                      \
        _Pragma("unroll")                                                   \
        for (int mi = 0; mi < 4; ++mi)                                      \
            _Pragma("unroll")                                               \
            for (int ni = 0; ni < 2; ++ni)                                  \
                _Pragma("unroll")                                           \
                for (int kk = 0; kk < 2; ++kk)                              \
                    acc[(mh) * 4 + mi][(nh) * 2 + ni] =                     \
                        __builtin_amdgcn_mfma_f32_16x16x32_bf16(            \
                            af[mi][kk], bg[ni][kk],                         \
                            acc[(mh) * 4 + mi][(nh) * 2 + ni], 0, 0, 0);    \
        __builtin_amdgcn_s_setprio(0);                                      \
    } while (0)
#define BARRIER() do { __builtin_amdgcn_s_barrier();                        \
                       __builtin_amdgcn_sched_barrier(0); } while (0)
#define WAITV4() asm volatile("s_waitcnt vmcnt(4)" ::: "memory")
#define WAITV2() asm volatile("s_waitcnt vmcnt(2)" ::: "memory")
#define WAITV0() asm volatile("s_waitcnt vmcnt(0)" ::: "memory")

    f32x4 acc[8][4] = {};
    const int NT = Kiter >> 6;

    // prologue: tile 0 -> slot 0; issue order b0 b1 b2 b3 a0 a2 a1 a3
    SQB(0, 0, 0); SQB(0, 0, 1); SQB(0, 0, 2); SQB(0, 0, 3);
    SQA(0, 0, 0); SQA(0, 0, 2); SQA(0, 0, 1); SQA(0, 0, 3);

    for (int tt = 0; tt < NT - 1; ++tt) {
        const int s = tt & 1, d = s ^ 1, kn = tt + 1;
        // P0 (mh0,nh0): certify b0..b3,a0,a2 of tile tt
        WAITV2(); BARRIER();
        SQB(d, kn, 0); SQB(d, kn, 1);
        READ_AF(s, 0); READ_BG(s, 0);
        MFMA_QUAD(0, 0);
        // P1 (mh1,nh0): certify a1,a3 of tile tt
        WAITV2(); BARRIER();
        SQB(d, kn, 2); SQB(d, kn, 3);
        READ_AF(s, 1);
        MFMA_QUAD(1, 0);
        // P2 (mh1,nh1): af alive; bg nh1 certified since P0
        SQA(d, kn, 0); SQA(d, kn, 2);
        READ_BG(s, 1);
        MFMA_QUAD(1, 1);
        // P3 (mh0,nh1): re-read af mh0; bg alive
        SQA(d, kn, 1); SQA(d, kn, 3);
        READ_AF(s, 0);
        MFMA_QUAD(0, 1);
    }
    {   // final tile: no staging; P1 drains to 0 (vmcnt(2) would under-wait)
        const int s = (NT - 1) & 1;
        WAITV2(); BARRIER();
        READ_AF(s, 0); READ_BG(s, 0);
        MFMA_QUAD(0, 0);
        WAITV0(); BARRIER();
        READ_AF(s, 1);
        MFMA_QUAD(1, 0);
        READ_BG(s, 1);
        MFMA_QUAD(1, 1);
        READ_AF(s, 0);
        MFMA_QUAD(0, 1);
    }

    // ---- Epilogue (R5): LDS-bounce vectorized store ----
    __syncthreads();   // all waves done with K-loop LDS reads
    unsigned short* scr = (w < 4) ? &sA[0][0][0] + w * 8192
                                  : &sB[0][0][0] + (w - 4) * 8192;

#pragma unroll
    for (int NI = 0; NI < 4; ++NI) {
        const int col = bn * 256 + wc * 64 + NI * 16 + lm;
        const float bv = (EPI == EPI_PART) ? 0.f : bias[col];
        const int c  = NI * 2 + (lm >> 3);   // logical 16B chunk (0..7)
        const int ci = lm & 7;               // bf16 within chunk
#pragma unroll
        for (int MI = 0; MI < 8; ++MI) {
#pragma unroll
            for (int r = 0; r < 4; ++r) {
                float v = acc[MI][NI][r] + bv;
                if (EPI == EPI_RELU) v = fmaxf(v, 0.f);
                const int row = MI * 16 + kq * 4 + r;   // 0..127
                scr[row * 64 + ((c ^ (row & 7)) * 8) + ci] =
                    __builtin_bit_cast(unsigned short, (__bf16)v);
            }
        }
    }
    // read back row-contiguous, store 16B/lane (full 128B lines per row)
#pragma unroll
    for (int it = 0; it < 16; ++it) {
        const int row = it * 8 + (l >> 3);   // 0..127
        const int lc  = l & 7;               // logical chunk
        const u16x8 vv = *(const u16x8*)&scr[row * 64 + ((lc ^ (row & 7)) * 8)];
        const int Crow = bm * 256 + wr * 128 + row;
        const int Ccol = bn * 256 + wc * 64 + lc * 8;
        *(u16x8*)((bf16*)out + (size_t)Crow * N + Ccol) = vv;
    }
#undef SQA
#undef SQB
#undef READ_AF
#undef READ_BG
#undef MFMA_QUAD
}

// ---------------------------------------------------------------------------
// gemm_bt (R7): C[4096,N] = A[4096,K] @ W[N,K]^T (+bias). 128x128 tile,
// BK=64, 256 thr = 4 waves (2M x 2N), per-wave 64x64 out. LDS 64KB: 2 slots
// x (A 128x64 + B 128x64). Counted-vmcnt 4-phase pipeline (R4-derived, waits
// re-derived for this geometry):
//   batch order (tile k+1, staged 2/phase during tile k):
//     b0 b2 a0 a2 | b1 b3 a1 a3      (sweep = 32 rows)
//   P0 (mh0,nh0) needs {b0,b2,a0,a2} -> vmcnt(4) with 8 outstanding.
//   P1 (mh1,nh0) needs {a1,a3} (and P2's {b1,b3}) -> vmcnt(2) with 6.
//   P2/P3 wait-free; raw s_barrier + sched_barrier(0) only at P0/P1.
//   Final tile: vmcnt(4), then vmcnt(0).
// XOR swizzle identical to gemm256 (0 conflicts measured).
// Epilogues unchanged (QSCALE / KV / RES_F32).
// ---------------------------------------------------------------------------
template <int EPI>
__global__ __launch_bounds__(256, 2) void gemm_bt(
    const bf16* __restrict__ A, const bf16* __restrict__ W,
    const float* __restrict__ bias, const float* __restrict__ bias2,
    const float* __restrict__ res, void* __restrict__ out,
    int M, int N, int Kiter, int Kstride)
{
    __shared__ __align__(16) unsigned short sA[2][128 * 64];
    __shared__ __align__(16) unsigned short sB[2][128 * 64];

    const int t  = threadIdx.x;     // 0..255
    const int l  = t & 63;
    const int w  = t >> 6;          // 0..3
    const int wv = w * 64;
    const int wm = (w >> 1) * 64;
    const int wn = (w & 1) * 64;
    const int lm = l & 15;
    const int kq = l >> 4;
    const int rx = lm & 7;

    const int bx  = blockIdx.x;
    const int xcd = bx & 7;
    const int ib  = bx >> 3;
    const int bm  = xcd * 4 + (ib & 3);   // 32 bm tiles, 4 per XCD
    const int bn  = ib >> 2;

    // Staging source: thread t covers 16B at (row t>>3, phys slot t&7) of a
    // 32-row sweep; logical slot = (t&7)^((t>>3)&7) (inverse swizzle).
    const bf16* gA = A + (size_t)(bm * 128 + (t >> 3)) * Kstride
                       + ((t & 7) ^ ((t >> 3) & 7)) * 8;
    const bf16* gB = W + (size_t)(bn * 128 + (t >> 3)) * Kstride
                       + ((t & 7) ^ ((t >> 3) & 7)) * 8;

    // stage one 32-row sweep j (0..3) of K-tile kt into slot
#define SQA(slot, kt, j)                                        \
    gld16(gA + (size_t)((j) * 32) * Kstride + (kt) * 64,        \
          &sA[slot][((j) * 256 + wv) * 8])
#define SQB(slot, kt, j)                                        \
    gld16(gB + (size_t)((j) * 32) * Kstride + (kt) * 64,        \
          &sB[slot][((j) * 256 + wv) * 8])

    bf16x8 af[2][2], bg[2][2];

#define READ_AF(s_, mh)                                                     \
    do {                                                                    \
        _Pragma("unroll")                                                   \
        for (int mi = 0; mi < 2; ++mi)                                      \
            _Pragma("unroll")                                               \
            for (int kk = 0; kk < 2; ++kk) {                                \
                const int lr = wm + (mh) * 32 + mi * 16 + lm;               \
                const int sl = ((kk << 2) | kq) ^ rx;                       \
                af[mi][kk] = __builtin_bit_cast(bf16x8,                     \
                    *(const u16x8*)(&sA[s_][lr * 64 + sl * 8]));            \
            }                                                               \
    } while (0)
#define READ_BG(s_, nh)                                                     \
    do {                                                                    \
        _Pragma("unroll")                                                   \
        for (int ni = 0; ni < 2; ++ni)                                      \
            _Pragma("unroll")                                               \
            for (int kk = 0; kk < 2; ++kk) {                                \
                const int lr = wn + (nh) * 32 + ni * 16 + lm;               \
                const int sl = ((kk << 2) | kq) ^ rx;                       \
                bg[ni][kk] = __builtin_bit_cast(bf16x8,                     \
                    *(const u16x8*)(&sB[s_][lr * 64 + sl * 8]));            \
            }                                                               \
    } while (0)
#define MFMA_QUAD(mh, nh)                                                   \
    do {                                                                    \
        __builtin_amdgcn_s_setprio(1);                                      \
        _Pragma("unroll")                                                   \
        for (int mi = 0; mi < 2; ++mi)                                      \
            _Pragma("unroll")                                               \
            for (int ni = 0; ni < 2; ++ni)                                  \
                _Pragma("unroll")                                           \
                for (int kk = 0; kk < 2; ++kk)                              \
                    acc[(mh) * 2 + mi][(nh) * 2 + ni] =                     \
                        __builtin_amdgcn_mfma_f32_16x16x32_bf16(            \
                            af[mi][kk], bg[ni][kk],                         \
                            acc[(mh) * 2 + mi][(nh) * 2 + ni], 0, 0, 0);    \
        __builtin_amdgcn_s_setprio(0);                                      \
    } while (0)

    f32x4 acc[4][4] = {};
    const int NT = Kiter >> 6;

    // prologue: tile 0 -> slot 0; order b0 b2 a0 a2 b1 b3 a1 a3
    SQB(0, 0, 0); SQB(0, 0, 2); SQA(0, 0, 0); SQA(0, 0, 2);
    SQB(0, 0, 1); SQB(0, 0, 3); SQA(0, 0, 1); SQA(0, 0, 3);

    for (int tt = 0; tt < NT - 1; ++tt) {
        const int s = tt & 1, d = s ^ 1, kn = tt + 1;
        // P0 (mh0,nh0): certify b0,b2,a0,a2 of tile tt
        WAITV4(); BARRIER();
        SQB(d, kn, 0); SQB(d, kn, 2);
        READ_AF(s, 0); READ_BG(s, 0);
        MFMA_QUAD(0, 0);
        // P1 (mh1,nh0): certify b1,b3,a1,a3 of tile tt
        WAITV2(); BARRIER();
        SQA(d, kn, 0); SQA(d, kn, 2);
        READ_AF(s, 1);
        MFMA_QUAD(1, 0);
        // P2 (mh1,nh1): b1,b3 certified at P1
        SQB(d, kn, 1); SQB(d, kn, 3);
        READ_BG(s, 1);
        MFMA_QUAD(1, 1);
        // P3 (mh0,nh1)
        SQA(d, kn, 1); SQA(d, kn, 3);
        READ_AF(s, 0);
        MFMA_QUAD(0, 1);
    }
    {   // final tile: no staging
        const int s = (NT - 1) & 1;
        WAITV4(); BARRIER();
        READ_AF(s, 0); READ_BG(s, 0);
        MFMA_QUAD(0, 0);
        WAITV0(); BARRIER();
        READ_AF(s, 1);
        MFMA_QUAD(1, 0);
        READ_BG(s, 1);
        MFMA_QUAD(1, 1);
        READ_AF(s, 0);
        MFMA_QUAD(0, 1);
    }
#undef SQA
#undef SQB
#undef READ_AF
#undef READ_BG
#undef MFMA_QUAD
#undef BARRIER
#undef WAITV4
#undef WAITV2
#undef WAITV0

    // Epilogue. C/D: col = lane&15 (+16*ni), row = kq*4 + r (+16*mi).
#pragma unroll
    for (int ni = 0; ni < 4; ++ni) {
        const int col = bn * 128 + wn + ni * 16 + lm;
        float bv = 0.f;
        if (EPI == EPI_KV) bv = (col < 1024) ? bias[col] : bias2[col - 1024];
        else bv = bias[col];
#pragma unroll
        for (int mi = 0; mi < 4; ++mi) {
#pragma unroll
            for (int r = 0; r < 4; ++r) {
                const int row = bm * 128 + wm + mi * 16 + kq * 4 + r;
                float v = acc[mi][ni][r] + bv;
                if (EPI == EPI_QSCALE) v *= 0.125f;
                if (EPI == EPI_KV) {
                    if (col < 1024) {
                        ((bf16*)out)[(size_t)row * 1024 + col] = __float2bfloat16(v);
                    } else {
                        const int ch = col - 1024;  // h*64 + d
                        const size_t idx = (size_t)4 * 1048576 +
                            ((size_t)((row >> 10) * 16 + (ch >> 6)) * 64 + (ch & 63)) * 1024
                            + (row & 1023);
                        ((bf16*)out)[idx] = __float2bfloat16(v);
                    }
                } else if (EPI == EPI_RES_F32_F32OUT) {
                    const size_t idx = (size_t)row * N + col;
                    ((float*)out)[idx] = v + res[idx];
                } else {
                    ((bf16*)out)[(size_t)row * N + col] = __float2bfloat16(v);
                }
            }
        }
    }
}

// ---------------------------------------------------------------------------
// FFN2 split-K reduce: out_f32 = x2 + b2 + sum_{c<4} (float)P[c].
// ---------------------------------------------------------------------------
__global__ __launch_bounds__(256) void ffn2_reduce(
    const bf16* __restrict__ P, const float* __restrict__ x2,
    const float* __restrict__ b2, float* __restrict__ out)
{
    const int i = (blockIdx.x * 256 + threadIdx.x) * 8;
    float v[8];
    {
        const float4 a = *(const float4*)(x2 + i);
        const float4 b = *(const float4*)(x2 + i + 4);
        v[0]=a.x; v[1]=a.y; v[2]=a.z; v[3]=a.w; v[4]=b.x; v[5]=b.y; v[6]=b.z; v[7]=b.w;
    }
    const int cb = i & 1023;
#pragma unroll
    for (int j = 0; j < 8; ++j) v[j] += b2[cb + j];
#pragma unroll
    for (int c = 0; c < 4; ++c) {
        const u16x8 u = *(const u16x8*)(P + (size_t)c * 4194304 + i);
        const bf16x8 pb = __builtin_bit_cast(bf16x8, u);
#pragma unroll
        for (int j = 0; j < 8; ++j) v[j] += (float)pb[j];
    }
    float4 o0 = {v[0], v[1], v[2], v[3]}, o1 = {v[4], v[5], v[6], v[7]};
    *(float4*)(out + i) = o0;
    *(float4*)(out + i + 4) = o1;
}

// ---------------------------------------------------------------------------
// Flash attention (MFMA). One block = (b,h) x 128 q-rows; 4 waves x 32 q-rows.
// Q,K,O: [B,T,H*64] bf16 (0.125 pre-folded into Q). Vt: [B,H,64(d),S] bf16.
// R6a (verified): XCD-local block remap (bh = bid&63). R6b (verified):
// sK/sV 128B-row tiles + XOR swizzle, conflict-free.
// ---------------------------------------------------------------------------
template <bool CAUSAL, bool SBIAS>
__global__ __launch_bounds__(256, 2) void flash_attn(
    const bf16* __restrict__ Q, const bf16* __restrict__ K,
    const bf16* __restrict__ Vt, bf16* __restrict__ O,
    const float* __restrict__ sbias, const float* __restrict__ scale_ptr)
{
    __shared__ __align__(16) unsigned short sK[2][64 * 64];
    __shared__ __align__(16) unsigned short sV[2][64 * 64];
    __shared__ __align__(16) unsigned short sP[4 * 32 * 72];

    const int t  = threadIdx.x;
    const int l  = t & 63;
    const int w  = t >> 6;
    const int wv = w * 64;
    const int lm = l & 15;
    const int kq = l >> 4;

    const int bh = blockIdx.x & 63;      // same-XCD for all 8 q-blocks of bh
    const int qb = blockIdx.x >> 6;
    const int h  = bh & 15;
    const int b  = bh >> 4;

    const int tb = qb * 128 + w * 32;
    const size_t qrow0 = (size_t)(b * 1024 + tb) * 1024 + h * 64;

    bf16x8 qf[2][2];
#pragma unroll
    for (int mi = 0; mi < 2; ++mi)
#pragma unroll
        for (int kk = 0; kk < 2; ++kk)
            qf[mi][kk] = __builtin_bit_cast(bf16x8,
                *(const u16x8*)(Q + qrow0 + (size_t)(mi * 16 + lm) * 1024 + kk * 32 + kq * 8));

    float cs = 0.f; const float* sb = nullptr;
    if (SBIAS) { cs = scale_ptr[0]; sb = sbias + b * 1024; }

    // Staging source (swizzled): thread t covers 16B at (row t>>3, phys slot
    // t&7) of a 32-row sweep; logical slot = (t&7)^((t>>3)&7).
    const bf16* gK = K  + (size_t)(b * 1024 + (t >> 3)) * 1024 + h * 64
                   + ((t & 7) ^ ((t >> 3) & 7)) * 8;
    const bf16* gV = Vt + (size_t)((b * 16 + h) * 64 + (t >> 3)) * 1024
                   + ((t & 7) ^ ((t >> 3) & 7)) * 8;
    __bf16* sPw = (__bf16*)sP + w * 32 * 72;

    // K tile: rows = s (64), cols = d (64). V tile: rows = d (64), cols = s.
#define STAGE_KV(buf, s0r)                                                   \
    do {                                                                     \
        gld16(gK + (size_t)(s0r) * 1024,        &sK[buf][wv * 8]);           \
        gld16(gK + (size_t)((s0r) + 32) * 1024, &sK[buf][2048 + wv * 8]);    \
        gld16(gV + (s0r),                       &sV[buf][wv * 8]);           \
        gld16(gV + (s0r) + 32 * 1024,           &sV[buf][2048 + wv * 8]);    \
    } while (0)

    const int niter = CAUSAL ? (2 * qb + 2) : 16;

    STAGE_KV(0, 0);
    __syncthreads();

    f32x4 acc_o[2][4] = {};
    f32x4 l_run[2] = {};

    for (int it = 0; it < niter; ++it) {
        const int s0 = it * 64;
        const int cur = it & 1;

        if (it + 1 < niter) STAGE_KV(cur ^ 1, s0 + 64);

        f32x4 accs[2][4] = {};
#pragma unroll
        for (int ni = 0; ni < 4; ++ni)
#pragma unroll
            for (int kk = 0; kk < 2; ++kk) {
                const bf16x8 kf = __builtin_bit_cast(bf16x8,
                    *(const u16x8*)(&sK[cur][(ni * 16 + lm) * 64
                        + ((((kk << 2) | kq)) ^ (lm & 7)) * 8]));
#pragma unroll
                for (int mi = 0; mi < 2; ++mi)
                    accs[mi][ni] = __builtin_amdgcn_mfma_f32_16x16x32_bf16(
                        qf[mi][kk], kf, accs[mi][ni], 0, 0, 0);
            }

        if (SBIAS) {
#pragma unroll
            for (int ni = 0; ni < 4; ++ni) {
                const float sv = cs * sb[s0 + ni * 16 + lm];
#pragma unroll
                for (int mi = 0; mi < 2; ++mi)
#pragma unroll
                    for (int r = 0; r < 4; ++r) accs[mi][ni][r] += sv;
            }
        }
        if (CAUSAL && (s0 + 63 > tb)) {
#pragma unroll
            for (int ni = 0; ni < 4; ++ni) {
                const int s = s0 + ni * 16 + lm;
#pragma unroll
                for (int mi = 0; mi < 2; ++mi)
#pragma unroll
                    for (int r = 0; r < 4; ++r)
                        if (s > tb + mi * 16 + kq * 4 + r) accs[mi][ni][r] = -1e30f;
            }
        }

#pragma unroll
        for (int mi = 0; mi < 2; ++mi)
#pragma unroll
            for (int ni = 0; ni < 4; ++ni)
#pragma unroll
                for (int r = 0; r < 4; ++r) {
                    const float e = __expf(accs[mi][ni][r]);
                    l_run[mi][r] += e;
                    sPw[(mi * 16 + kq * 4 + r) * 72 + ni * 16 + lm] = (__bf16)e;
                }

#pragma unroll
        for (int kk = 0; kk < 2; ++kk) {
            bf16x8 pf[2];
#pragma unroll
            for (int mi = 0; mi < 2; ++mi)
                pf[mi] = __builtin_bit_cast(bf16x8,
                    *(const u16x8*)(sPw + (mi * 16 + lm) * 72 + kk * 32 + kq * 8));
#pragma unroll
            for (int di = 0; di < 4; ++di) {
                const bf16x8 vf = __builtin_bit_cast(bf16x8,
                    *(const u16x8*)(&sV[cur][(di * 16 + lm) * 64
                        + ((((kk << 2) | kq)) ^ (lm & 7)) * 8]));
#pragma unroll
                for (int mi = 0; mi < 2; ++mi)
                    acc_o[mi][di] = __builtin_amdgcn_mfma_f32_16x16x32_bf16(
                        pf[mi], vf, acc_o[mi][di], 0, 0, 0);
            }
        }

        __syncthreads();
    }
#undef STAGE_KV

#pragma unroll
    for (int mi = 0; mi < 2; ++mi) {
        f32x4 lt = l_run[mi];
#pragma unroll
        for (int x = 1; x < 16; x <<= 1)
#pragma unroll
            for (int r = 0; r < 4; ++r) lt[r] += __shfl_xor(lt[r], x, 64);
#pragma unroll
        for (int r = 0; r < 4; ++r) lt[r] = 1.f / lt[r];
#pragma unroll
        for (int di = 0; di < 4; ++di)
#pragma unroll
            for (int r = 0; r < 4; ++r) {
                const size_t idx = (size_t)(b * 1024 + tb + mi * 16 + kq * 4 + r) * 1024
                                 + h * 64 + di * 16 + lm;
                O[idx] = __float2bfloat16(acc_o[mi][di][r] * lt[r]);
            }
    }
}

// ---------------------------------------------------------------------------
// LayerNorm over D=1024 (fp32 in, bf16 out), one block per row, 4 elems/thr.
// ---------------------------------------------------------------------------
__global__ __launch_bounds__(256) void ln_kernel(
    const float* __restrict__ xin, const float* __restrict__ g,
    const float* __restrict__ bta, bf16* __restrict__ out)
{
    const int row = blockIdx.x;
    const int t = threadIdx.x;
    const size_t base = (size_t)row * 1024 + t * 4;

    const float4 f = *(const float4*)(xin + base);
    const float v[4] = {f.x, f.y, f.z, f.w};
    float s1 = v[0] + v[1] + v[2] + v[3];
    float s2 = v[0]*v[0] + v[1]*v[1] + v[2]*v[2] + v[3]*v[3];
#pragma unroll
    for (int off = 32; off > 0; off >>= 1) {
        s1 += __shfl_xor(s1, off, 64);
        s2 += __shfl_xor(s2, off, 64);
    }
    __shared__ float r1[4], r2[4];
    if ((t & 63) == 0) { r1[t >> 6] = s1; r2[t >> 6] = s2; }
    __syncthreads();
    s1 = r1[0] + r1[1] + r1[2] + r1[3];
    s2 = r2[0] + r2[1] + r2[2] + r2[3];
    const float mean = s1 * (1.f / 1024.f);
    const float var  = s2 * (1.f / 1024.f) - mean * mean;
    const float rstd = rsqrtf(var + 1e-5f);
#pragma unroll
    for (int j = 0; j < 4; ++j) {
        const int c = t * 4 + j;
        out[base + j] = __float2bfloat16((v[j] - mean) * rstd * g[c] + bta[c]);
    }
}

// ---------------------------------------------------------------------------
extern "C" void kernel_launch(void* const* d_in, const int* in_sizes, int n_in,
                              void* d_out, int out_size, void* d_ws, size_t ws_size,
                              hipStream_t stream)
{
    const float* x       = (const float*)d_in[0];
    const float* memory  = (const float*)d_in[1];
    const float* sbias   = (const float*)d_in[2];
    const float* sa_bq = (const float*)d_in[7];
    const float* sa_bk = (const float*)d_in[9];
    const float* sa_bv = (const float*)d_in[11];
    const float* sa_bo = (const float*)d_in[13];
    const float* ca_bq = (const float*)d_in[16];
    const float* ca_bk = (const float*)d_in[18];
    const float* ca_bv = (const float*)d_in[20];
    const float* ca_bo = (const float*)d_in[22];
    const float* ca_scale = (const float*)d_in[23];
    const float* ln1_g = (const float*)d_in[24]; const float* ln1_b = (const float*)d_in[25];
    const float* ln2_g = (const float*)d_in[26]; const float* ln2_b = (const float*)d_in[27];
    const float* ln3_g = (const float*)d_in[28]; const float* ln3_b = (const float*)d_in[29];
    const float* b1 = (const float*)d_in[31];
    const float* b2 = (const float*)d_in[33];

    char* ws = (char*)d_ws;
    const size_t MB = (size_t)1 << 20;
    float* x1    = (float*)(ws + 0 * MB);
    float* x2    = (float*)(ws + 16 * MB);
    bf16* lnbuf  = (bf16*)(ws + 32 * MB);
    bf16* Qb     = (bf16*)(ws + 40 * MB);
    bf16* Kb     = (bf16*)(ws + 48 * MB);
    bf16* Vtb    = (bf16*)(ws + 56 * MB);
    bf16* Ob     = (bf16*)(ws + 64 * MB);
    bf16* ffnmid = (bf16*)(ws + 40 * MB);
    bf16* wx     = (bf16*)(ws + 72 * MB);
    bf16* wmem   = (bf16*)(ws + 80 * MB);
    bf16* bw     = (bf16*)(ws + 88 * MB);
    bf16* b_sa_wq = bw + 0 * 1048576, *b_sa_wk = bw + 1 * 1048576;
    bf16* b_sa_wo = bw + 3 * 1048576;
    bf16* b_ca_wq = bw + 4 * 1048576, *b_ca_wk = bw + 5 * 1048576;
    bf16* b_ca_wo = bw + 7 * 1048576;
    bf16* b_w1   = (bf16*)(ws + 104 * MB);
    bf16* b_w2   = (bf16*)(ws + 112 * MB);
    bf16* part   = (bf16*)(ws + 72 * MB);

    const int M = 4096;
    dim3 blk256(256), blk512(512);
    const dim3 gQ(256);    // (4096/128)*(1024/128): 128^2 tiles
    const dim3 gKV(512);   // (4096/128)*(2048/128)
    const dim3 gFA(512);   // 64 (b,h) x 8 q-blocks
    const dim3 g256(256);  // FFN1: 16x16 tiles; FFN2: 4 chunks x 64 tiles

    CvtSrcs cs;
    for (int c = 0; c < 4; ++c) {
        cs.p[c]      = x + (size_t)c * 1048576;
        cs.p[4 + c]  = memory + (size_t)c * 1048576;
        cs.p[16 + c] = (const float*)d_in[30] + (size_t)c * 1048576;  // w1
        cs.p[20 + c] = (const float*)d_in[32] + (size_t)c * 1048576;  // w2
    }
    cs.p[8]  = (const float*)d_in[6];
    cs.p[9]  = (const float*)d_in[8];
    cs.p[10] = (const float*)d_in[10];
    cs.p[11] = (const float*)d_in[12];
    cs.p[12] = (const float*)d_in[15];
    cs.p[13] = (const float*)d_in[17];
    cs.p[14] = (const float*)d_in[19];
    cs.p[15] = (const float*)d_in[21];
    cvt_all<<<24 * 1048576 / 2048, blk256, 0, stream>>>(cs, wx);

    // ---- self-attention ----
    ln_kernel<<<4096, blk256, 0, stream>>>(x, ln1_g, ln1_b, lnbuf);
    gemm_bt<EPI_QSCALE><<<gQ, blk256, 0, stream>>>(
        lnbuf, b_sa_wq, sa_bq, nullptr, nullptr, Qb, M, 1024, 1024, 1024);
    gemm_bt<EPI_KV><<<gKV, blk256, 0, stream>>>(
        wx, b_sa_wk, sa_bk, sa_bv, nullptr, Kb, M, 2048, 1024, 1024);
    flash_attn<true, false><<<gFA, blk256, 0, stream>>>(Qb, Kb, Vtb, Ob, nullptr, nullptr);
    gemm_bt<EPI_RES_F32_F32OUT><<<gQ, blk256, 0, stream>>>(
        Ob, b_sa_wo, sa_bo, nullptr, x, x1, M, 1024, 1024, 1024);

    // ---- cross-attention ----
    ln_kernel<<<4096, blk256, 0, stream>>>(x1, ln2_g, ln2_b, lnbuf);
    gemm_bt<EPI_QSCALE><<<gQ, blk256, 0, stream>>>(
        lnbuf, b_ca_wq, ca_bq, nullptr, nullptr, Qb, M, 1024, 1024, 1024);
    gemm_bt<EPI_KV><<<gKV, blk256, 0, stream>>>(
        wmem, b_ca_wk, ca_bk, ca_bv, nullptr, Kb, M, 2048, 1024, 1024);
    flash_attn<false, true><<<gFA, blk256, 0, stream>>>(Qb, Kb, Vtb, Ob, sbias, ca_scale);
    gemm_bt<EPI_RES_F32_F32OUT><<<gQ, blk256, 0, stream>>>(
        Ob, b_ca_wo, ca_bo, nullptr, x1, x2, M, 1024, 1024, 1024);

    // ---- FFN ----
    ln_kernel<<<4096, blk256, 0, stream>>>(x2, ln3_g, ln3_b, lnbuf);
    gemm256<EPI_RELU><<<g256, blk512, 0, stream>>>(
        lnbuf, b_w1, b1, ffnmid, 4096, 1024, 1024);
    gemm256<EPI_PART><<<g256, blk512, 0, stream>>>(
        ffnmid, b_w2, nullptr, part, 1024, 1024, 4096);
    ffn2_reduce<<<2048, blk256, 0, stream>>>(part, x2, b2, (float*)d_out);
}

// Round 8
// 457.550 us; speedup vs baseline: 1.0969x; 1.0449x over previous
//
#include <hip/hip_runtime.h>
#include <hip/hip_bf16.h>
#include <cmath>
#include <stdint.h>

typedef __hip_bfloat16 bf16;
typedef __attribute__((ext_vector_type(8))) __bf16 bf16x8;
typedef __attribute__((ext_vector_type(8))) unsigned short u16x8;
typedef __attribute__((ext_vector_type(4))) float f32x4;

// Async global->LDS DMA, 16B per lane. LDS dest must be wave-uniform base;
// HW adds lane*16.
__device__ __forceinline__ void gld16(const void* g, const void* l)
{
    __builtin_amdgcn_global_load_lds(
        (const __attribute__((address_space(1))) unsigned int*)(unsigned long long)g,
        (__attribute__((address_space(3))) unsigned int*)(unsigned int)(unsigned long long)l,
        16, 0, 0);
}

// ---------------------------------------------------------------------------
// Fused fp32 -> bf16 conversion of all 12 tensors in one launch.
// R8: LN1 fused for segments 0-3 (the x tensor). One block = 2048 elems =
// exactly 2 rows of D=1024; waves {0,1} own row 0, {2,3} row 1. Per-wave
// 64-lane shfl reduce + 2-wave LDS combine -> mean/rstd; writes normalized
// bf16 to lnout alongside the raw bf16 to dst. Deletes the ln1 launch
// (24MB traffic + dispatch).
// ---------------------------------------------------------------------------
struct CvtSrcs { const float* p[24]; };

__global__ __launch_bounds__(256) void cvt_all(
    CvtSrcs s, bf16* __restrict__ dst,
    const float* __restrict__ lg, const float* __restrict__ lb,
    bf16* __restrict__ lnout)
{
    const int t = threadIdx.x;
    const int i = (blockIdx.x * 256 + t) * 8;
    const int seg = i >> 20;
    const float* sp = s.p[seg] + (i & 1048575);
    const float4 a = *(const float4*)(sp);
    const float4 b = *(const float4*)(sp + 4);
    const float v[8] = {a.x, a.y, a.z, a.w, b.x, b.y, b.z, b.w};
    bf16 tmp[8];
#pragma unroll
    for (int j = 0; j < 8; ++j) tmp[j] = __float2bfloat16(v[j]);
    *(uint4*)(dst + i) = *(const uint4*)tmp;

    if (seg < 4) {   // x tensor: fused LayerNorm (seg uniform per block)
        float s1 = 0.f, s2 = 0.f;
#pragma unroll
        for (int j = 0; j < 8; ++j) { s1 += v[j]; s2 += v[j] * v[j]; }
#pragma unroll
        for (int off = 32; off > 0; off >>= 1) {
            s1 += __shfl_xor(s1, off, 64);
            s2 += __shfl_xor(s2, off, 64);
        }
        __shared__ float r1[4], r2[4];
        const int w = t >> 6;
        if ((t & 63) == 0) { r1[w] = s1; r2[w] = s2; }
        __syncthreads();
        const int rw = (w >> 1) * 2;        // first wave of this row
        s1 = r1[rw] + r1[rw + 1];
        s2 = r2[rw] + r2[rw + 1];
        const float mean = s1 * (1.f / 1024.f);
        const float var  = s2 * (1.f / 1024.f) - mean * mean;
        const float rstd = rsqrtf(var + 1e-5f);
        bf16 lt[8];
        const int c0 = i & 1023;
#pragma unroll
        for (int j = 0; j < 8; ++j)
            lt[j] = __float2bfloat16((v[j] - mean) * rstd * lg[c0 + j] + lb[c0 + j]);
        *(uint4*)(lnout + i) = *(const uint4*)lt;
    }
}

enum {
    EPI_QSCALE = 0,          // out_bf16 = (C + bias) * 0.125
    EPI_KV = 1,              // N=2048 fused: K plain / Vt transposed
    EPI_RELU = 2,            // out_bf16 = relu(C + bias)
    EPI_RES_F32_F32OUT = 3,  // out_f32  = res_f32 + C + bias
    EPI_PART = 4             // (unused since R8)
};

// ---------------------------------------------------------------------------
// gemm256: C[4096,N] = A[4096,K] @ W[N,K]^T (+bias). 256x256 tile, BK=64,
// 512 thr = 8 waves (2M x 4N), per-wave 128x64 out. LDS 128KB: 2 slots x
// (A 256x64 + B 256x64), each as 2 halves of 128 rows.
// K-loop (R4, verified): counted-vmcnt 4-phase pipeline; tile tt+1 staged in
// quarters over tile tt's phases; vmcnt(2) waits at P0/P1; raw s_barrier
// only at P0/P1; never drains vmcnt to 0 in the main loop.
// Epilogue (R5, verified): LDS-bounce vectorized store (16B/lane lines).
// ---------------------------------------------------------------------------
template <int EPI>
__global__ __launch_bounds__(512, 2) void gemm256(
    const bf16* __restrict__ A, const bf16* __restrict__ W,
    const float* __restrict__ bias, void* __restrict__ out,
    int N, int Kiter, int Kstride)
{
    __shared__ __align__(16) unsigned short sA[2][2][128 * 64];  // [slot][half]
    __shared__ __align__(16) unsigned short sB[2][2][128 * 64];

    const int t  = threadIdx.x;          // 0..511
    const int l  = t & 63;
    const int w  = t >> 6;               // 0..7
    const int wv = w * 64;
    const int wr = w >> 2;               // 0..1 : M-half of block
    const int wc = w & 3;                // 0..3 : N-quarter of block
    const int lm = l & 15;
    const int kq = l >> 4;
    const int rx = lm & 7;               // read-side swizzle row bits

    int bx = blockIdx.x;
    // XCD-aware: xcd owns 2 contiguous bm-bands; bm fastest within xcd.
    const int xcd = bx & 7;
    const int ib  = bx >> 3;
    const int bm  = xcd * 2 + (ib & 1);
    const int bn  = ib >> 1;

    // Staging source: thread t covers 16B = (row t>>3, phys slot t&7);
    // logical kslot = (t&7) ^ ((t>>3)&7)  (inverse-swizzled source).
    const bf16* gA = A + (size_t)(bm * 256 + (t >> 3)) * Kstride
                       + ((t & 7) ^ ((t >> 3) & 7)) * 8;
    const bf16* gB = W + (size_t)(bn * 256 + (t >> 3)) * Kstride
                       + ((t & 7) ^ ((t >> 3) & 7)) * 8;

    // stage one 64-row quarter j (0..3) of tile kt into slot
#define SQA(slot, kt, j)                                        \
    gld16(gA + (size_t)((j) * 64) * Kstride + (kt) * 64,        \
          &sA[slot][(j) >> 1][(((j) & 1) * 512 + wv) * 8])
#define SQB(slot, kt, j)                                        \
    gld16(gB + (size_t)((j) * 64) * Kstride + (kt) * 64,        \
          &sB[slot][(j) >> 1][(((j) & 1) * 512 + wv) * 8])

    bf16x8 af[4][2], bg[2][2];

#define READ_AF(s_, mh)                                                     \
    do {                                                                    \
        _Pragma("unroll")                                                   \
        for (int mi = 0; mi < 4; ++mi)                                      \
            _Pragma("unroll")                                               \
            for (int kk = 0; kk < 2; ++kk) {                                \
                const int lr = (mh) * 64 + mi * 16 + lm;                    \
                const int sl = ((kk << 2) | kq) ^ rx;                       \
                af[mi][kk] = __builtin_bit_cast(bf16x8,                     \
                    *(const u16x8*)(&sA[s_][wr][lr * 64 + sl * 8]));        \
            }                                                               \
    } while (0)
#define READ_BG(s_, nh)                                                     \
    do {                                                                    \
        _Pragma("unroll")                                                   \
        for (int ni = 0; ni < 2; ++ni)                                      \
            _Pragma("unroll")                                               \
            for (int kk = 0; kk < 2; ++kk) {                                \
                const int lr = (wc & 1) * 64 + (nh) * 32 + ni * 16 + lm;    \
                const int sl = ((kk << 2) | kq) ^ rx;                       \
                bg[ni][kk] = __builtin_bit_cast(bf16x8,                     \
                    *(const u16x8*)(&sB[s_][wc >> 1][lr * 64 + sl * 8]));   \
            }                                                               \
    } while (0)
#define MFMA_QUAD(mh, nh)                                                   \
    do {                                                                    \
        __builtin_amdgcn_s_setprio(1);                                      \
        _Pragma("unroll")                                                   \
        for (int mi = 0; mi < 4; ++mi)                                      \
            _Pragma("unroll")                                               \
            for (int ni = 0; ni < 2; ++ni)                                  \
                _Pragma("unroll")                                           \
                for (int kk = 0; kk < 2; ++kk)                              \
                    acc[(mh) * 4 + mi][(nh) * 2 + ni] =                     \
                        __builtin_amdgcn_mfma_f32_16x16x32_bf16(            \
                            af[mi][kk], bg[ni][kk],                         \
                            acc[(mh) * 4 + mi][(nh) * 2 + ni], 0, 0, 0);    \
        __builtin_amdgcn_s_setprio(0);                                      \
    } while (0)
#define BARRIER() do { __builtin_amdgcn_s_barrier();                        \
                       __builtin_amdgcn_sched_barrier(0); } while (0)
#define WAITV4() asm volatile("s_waitcnt vmcnt(4)" ::: "memory")
#define WAITV2() asm volatile("s_waitcnt vmcnt(2)" ::: "memory")
#define WAITV0() asm volatile("s_waitcnt vmcnt(0)" ::: "memory")

    f32x4 acc[8][4] = {};
    const int NT = Kiter >> 6;

    // prologue: tile 0 -> slot 0; issue order b0 b1 b2 b3 a0 a2 a1 a3
    SQB(0, 0, 0); SQB(0, 0, 1); SQB(0, 0, 2); SQB(0, 0, 3);
    SQA(0, 0, 0); SQA(0, 0, 2); SQA(0, 0, 1); SQA(0, 0, 3);

    for (int tt = 0; tt < NT - 1; ++tt) {
        const int s = tt & 1, d = s ^ 1, kn = tt + 1;
        // P0 (mh0,nh0): certify b0..b3,a0,a2 of tile tt
        WAITV2(); BARRIER();
        SQB(d, kn, 0); SQB(d, kn, 1);
        READ_AF(s, 0); READ_BG(s, 0);
        MFMA_QUAD(0, 0);
        // P1 (mh1,nh0): certify a1,a3 of tile tt
        WAITV2(); BARRIER();
        SQB(d, kn, 2); SQB(d, kn, 3);
        READ_AF(s, 1);
        MFMA_QUAD(1, 0);
        // P2 (mh1,nh1): af alive; bg nh1 certified since P0
        SQA(d, kn, 0); SQA(d, kn, 2);
        READ_BG(s, 1);
        MFMA_QUAD(1, 1);
        // P3 (mh0,nh1): re-read af mh0; bg alive
        SQA(d, kn, 1); SQA(d, kn, 3);
        READ_AF(s, 0);
        MFMA_QUAD(0, 1);
    }
    {   // final tile: no staging; P1 drains to 0 (vmcnt(2) would under-wait)
        const int s = (NT - 1) & 1;
        WAITV2(); BARRIER();
        READ_AF(s, 0); READ_BG(s, 0);
        MFMA_QUAD(0, 0);
        WAITV0(); BARRIER();
        READ_AF(s, 1);
        MFMA_QUAD(1, 0);
        READ_BG(s, 1);
        MFMA_QUAD(1, 1);
        READ_AF(s, 0);
        MFMA_QUAD(0, 1);
    }

    // ---- Epilogue (R5): LDS-bounce vectorized store ----
    __syncthreads();   // all waves done with K-loop LDS reads
    unsigned short* scr = (w < 4) ? &sA[0][0][0] + w * 8192
                                  : &sB[0][0][0] + (w - 4) * 8192;

#pragma unroll
    for (int NI = 0; NI < 4; ++NI) {
        const int col = bn * 256 + wc * 64 + NI * 16 + lm;
        const float bv = bias[col];
        const int c  = NI * 2 + (lm >> 3);   // logical 16B chunk (0..7)
        const int ci = lm & 7;               // bf16 within chunk
#pragma unroll
        for (int MI = 0; MI < 8; ++MI) {
#pragma unroll
            for (int r = 0; r < 4; ++r) {
                float v = acc[MI][NI][r] + bv;
                if (EPI == EPI_RELU) v = fmaxf(v, 0.f);
                const int row = MI * 16 + kq * 4 + r;   // 0..127
                scr[row * 64 + ((c ^ (row & 7)) * 8) + ci] =
                    __builtin_bit_cast(unsigned short, (__bf16)v);
            }
        }
    }
    // read back row-contiguous, store 16B/lane (full 128B lines per row)
#pragma unroll
    for (int it = 0; it < 16; ++it) {
        const int row = it * 8 + (l >> 3);   // 0..127
        const int lc  = l & 7;               // logical chunk
        const u16x8 vv = *(const u16x8*)&scr[row * 64 + ((lc ^ (row & 7)) * 8)];
        const int Crow = bm * 256 + wr * 128 + row;
        const int Ccol = bn * 256 + wc * 64 + lc * 8;
        *(u16x8*)((bf16*)out + (size_t)Crow * N + Ccol) = vv;
    }
#undef SQA
#undef SQB
#undef READ_AF
#undef READ_BG
#undef MFMA_QUAD
}

// ---------------------------------------------------------------------------
// gemm_bt (R7, verified): C[4096,N] = A[4096,K] @ W[N,K]^T (+bias). 128x128
// tile, BK=64, 256 thr = 4 waves (2M x 2N). Counted-vmcnt 4-phase pipeline;
// XOR swizzle as gemm256. R8: also serves FFN2 directly (K=4096, fused
// residual fp32 out) — replaces split-K partials + ffn2_reduce.
// ---------------------------------------------------------------------------
template <int EPI>
__global__ __launch_bounds__(256, 2) void gemm_bt(
    const bf16* __restrict__ A, const bf16* __restrict__ W,
    const float* __restrict__ bias, const float* __restrict__ bias2,
    const float* __restrict__ res, void* __restrict__ out,
    int M, int N, int Kiter, int Kstride)
{
    __shared__ __align__(16) unsigned short sA[2][128 * 64];
    __shared__ __align__(16) unsigned short sB[2][128 * 64];

    const int t  = threadIdx.x;     // 0..255
    const int l  = t & 63;
    const int w  = t >> 6;          // 0..3
    const int wv = w * 64;
    const int wm = (w >> 1) * 64;
    const int wn = (w & 1) * 64;
    const int lm = l & 15;
    const int kq = l >> 4;
    const int rx = lm & 7;

    const int bx  = blockIdx.x;
    const int xcd = bx & 7;
    const int ib  = bx >> 3;
    const int bm  = xcd * 4 + (ib & 3);   // 32 bm tiles, 4 per XCD
    const int bn  = ib >> 2;

    // Staging source: thread t covers 16B at (row t>>3, phys slot t&7) of a
    // 32-row sweep; logical slot = (t&7)^((t>>3)&7) (inverse swizzle).
    const bf16* gA = A + (size_t)(bm * 128 + (t >> 3)) * Kstride
                       + ((t & 7) ^ ((t >> 3) & 7)) * 8;
    const bf16* gB = W + (size_t)(bn * 128 + (t >> 3)) * Kstride
                       + ((t & 7) ^ ((t >> 3) & 7)) * 8;

    // stage one 32-row sweep j (0..3) of K-tile kt into slot
#define SQA(slot, kt, j)                                        \
    gld16(gA + (size_t)((j) * 32) * Kstride + (kt) * 64,        \
          &sA[slot][((j) * 256 + wv) * 8])
#define SQB(slot, kt, j)                                        \
    gld16(gB + (size_t)((j) * 32) * Kstride + (kt) * 64,        \
          &sB[slot][((j) * 256 + wv) * 8])

    bf16x8 af[2][2], bg[2][2];

#define READ_AF(s_, mh)                                                     \
    do {                                                                    \
        _Pragma("unroll")                                                   \
        for (int mi = 0; mi < 2; ++mi)                                      \
            _Pragma("unroll")                                               \
            for (int kk = 0; kk < 2; ++kk) {                                \
                const int lr = wm + (mh) * 32 + mi * 16 + lm;               \
                const int sl = ((kk << 2) | kq) ^ rx;                       \
                af[mi][kk] = __builtin_bit_cast(bf16x8,                     \
                    *(const u16x8*)(&sA[s_][lr * 64 + sl * 8]));            \
            }                                                               \
    } while (0)
#define READ_BG(s_, nh)                                                     \
    do {                                                                    \
        _Pragma("unroll")                                                   \
        for (int ni = 0; ni < 2; ++ni)                                      \
            _Pragma("unroll")                                               \
            for (int kk = 0; kk < 2; ++kk) {                                \
                const int lr = wn + (nh) * 32 + ni * 16 + lm;               \
                const int sl = ((kk << 2) | kq) ^ rx;                       \
                bg[ni][kk] = __builtin_bit_cast(bf16x8,                     \
                    *(const u16x8*)(&sB[s_][lr * 64 + sl * 8]));            \
            }                                                               \
    } while (0)
#define MFMA_QUAD(mh, nh)                                                   \
    do {                                                                    \
        __builtin_amdgcn_s_setprio(1);                                      \
        _Pragma("unroll")                                                   \
        for (int mi = 0; mi < 2; ++mi)                                      \
            _Pragma("unroll")                                               \
            for (int ni = 0; ni < 2; ++ni)                                  \
                _Pragma("unroll")                                           \
                for (int kk = 0; kk < 2; ++kk)                              \
                    acc[(mh) * 2 + mi][(nh) * 2 + ni] =                     \
                        __builtin_amdgcn_mfma_f32_16x16x32_bf16(            \
                            af[mi][kk], bg[ni][kk],                         \
                            acc[(mh) * 2 + mi][(nh) * 2 + ni], 0, 0, 0);    \
        __builtin_amdgcn_s_setprio(0);                                      \
    } while (0)

    f32x4 acc[4][4] = {};
    const int NT = Kiter >> 6;

    // prologue: tile 0 -> slot 0; order b0 b2 a0 a2 b1 b3 a1 a3
    SQB(0, 0, 0); SQB(0, 0, 2); SQA(0, 0, 0); SQA(0, 0, 2);
    SQB(0, 0, 1); SQB(0, 0, 3); SQA(0, 0, 1); SQA(0, 0, 3);

    for (int tt = 0; tt < NT - 1; ++tt) {
        const int s = tt & 1, d = s ^ 1, kn = tt + 1;
        // P0 (mh0,nh0): certify b0,b2,a0,a2 of tile tt
        WAITV4(); BARRIER();
        SQB(d, kn, 0); SQB(d, kn, 2);
        READ_AF(s, 0); READ_BG(s, 0);
        MFMA_QUAD(0, 0);
        // P1 (mh1,nh0): certify b1,b3,a1,a3 of tile tt
        WAITV2(); BARRIER();
        SQA(d, kn, 0); SQA(d, kn, 2);
        READ_AF(s, 1);
        MFMA_QUAD(1, 0);
        // P2 (mh1,nh1): b1,b3 certified at P1
        SQB(d, kn, 1); SQB(d, kn, 3);
        READ_BG(s, 1);
        MFMA_QUAD(1, 1);
        // P3 (mh0,nh1)
        SQA(d, kn, 1); SQA(d, kn, 3);
        READ_AF(s, 0);
        MFMA_QUAD(0, 1);
    }
    {   // final tile: no staging
        const int s = (NT - 1) & 1;
        WAITV4(); BARRIER();
        READ_AF(s, 0); READ_BG(s, 0);
        MFMA_QUAD(0, 0);
        WAITV0(); BARRIER();
        READ_AF(s, 1);
        MFMA_QUAD(1, 0);
        READ_BG(s, 1);
        MFMA_QUAD(1, 1);
        READ_AF(s, 0);
        MFMA_QUAD(0, 1);
    }
#undef SQA
#undef SQB
#undef READ_AF
#undef READ_BG
#undef MFMA_QUAD
#undef BARRIER
#undef WAITV4
#undef WAITV2
#undef WAITV0

    // Epilogue. C/D: col = lane&15 (+16*ni), row = kq*4 + r (+16*mi).
#pragma unroll
    for (int ni = 0; ni < 4; ++ni) {
        const int col = bn * 128 + wn + ni * 16 + lm;
        float bv = 0.f;
        if (EPI == EPI_KV) bv = (col < 1024) ? bias[col] : bias2[col - 1024];
        else bv = bias[col];
#pragma unroll
        for (int mi = 0; mi < 4; ++mi) {
#pragma unroll
            for (int r = 0; r < 4; ++r) {
                const int row = bm * 128 + wm + mi * 16 + kq * 4 + r;
                float v = acc[mi][ni][r] + bv;
                if (EPI == EPI_QSCALE) v *= 0.125f;
                if (EPI == EPI_KV) {
                    if (col < 1024) {
                        ((bf16*)out)[(size_t)row * 1024 + col] = __float2bfloat16(v);
                    } else {
                        const int ch = col - 1024;  // h*64 + d
                        const size_t idx = (size_t)4 * 1048576 +
                            ((size_t)((row >> 10) * 16 + (ch >> 6)) * 64 + (ch & 63)) * 1024
                            + (row & 1023);
                        ((bf16*)out)[idx] = __float2bfloat16(v);
                    }
                } else if (EPI == EPI_RES_F32_F32OUT) {
                    const size_t idx = (size_t)row * N + col;
                    ((float*)out)[idx] = v + res[idx];
                } else {
                    ((bf16*)out)[(size_t)row * N + col] = __float2bfloat16(v);
                }
            }
        }
    }
}

// ---------------------------------------------------------------------------
// Flash attention (MFMA). One block = (b,h) x 128 q-rows; 4 waves x 32 q-rows.
// Q,K,O: [B,T,H*64] bf16 (0.125 pre-folded into Q). Vt: [B,H,64(d),S] bf16.
// R6a (verified): XCD-local block remap (bh = bid&63). R6b (verified):
// sK/sV 128B-row tiles + XOR swizzle, conflict-free.
// ---------------------------------------------------------------------------
template <bool CAUSAL, bool SBIAS>
__global__ __launch_bounds__(256, 2) void flash_attn(
    const bf16* __restrict__ Q, const bf16* __restrict__ K,
    const bf16* __restrict__ Vt, bf16* __restrict__ O,
    const float* __restrict__ sbias, const float* __restrict__ scale_ptr)
{
    __shared__ __align__(16) unsigned short sK[2][64 * 64];
    __shared__ __align__(16) unsigned short sV[2][64 * 64];
    __shared__ __align__(16) unsigned short sP[4 * 32 * 72];

    const int t  = threadIdx.x;
    const int l  = t & 63;
    const int w  = t >> 6;
    const int wv = w * 64;
    const int lm = l & 15;
    const int kq = l >> 4;

    const int bh = blockIdx.x & 63;      // same-XCD for all 8 q-blocks of bh
    const int qb = blockIdx.x >> 6;
    const int h  = bh & 15;
    const int b  = bh >> 4;

    const int tb = qb * 128 + w * 32;
    const size_t qrow0 = (size_t)(b * 1024 + tb) * 1024 + h * 64;

    bf16x8 qf[2][2];
#pragma unroll
    for (int mi = 0; mi < 2; ++mi)
#pragma unroll
        for (int kk = 0; kk < 2; ++kk)
            qf[mi][kk] = __builtin_bit_cast(bf16x8,
                *(const u16x8*)(Q + qrow0 + (size_t)(mi * 16 + lm) * 1024 + kk * 32 + kq * 8));

    float cs = 0.f; const float* sb = nullptr;
    if (SBIAS) { cs = scale_ptr[0]; sb = sbias + b * 1024; }

    // Staging source (swizzled): thread t covers 16B at (row t>>3, phys slot
    // t&7) of a 32-row sweep; logical slot = (t&7)^((t>>3)&7).
    const bf16* gK = K  + (size_t)(b * 1024 + (t >> 3)) * 1024 + h * 64
                   + ((t & 7) ^ ((t >> 3) & 7)) * 8;
    const bf16* gV = Vt + (size_t)((b * 16 + h) * 64 + (t >> 3)) * 1024
                   + ((t & 7) ^ ((t >> 3) & 7)) * 8;
    __bf16* sPw = (__bf16*)sP + w * 32 * 72;

    // K tile: rows = s (64), cols = d (64). V tile: rows = d (64), cols = s.
#define STAGE_KV(buf, s0r)                                                   \
    do {                                                                     \
        gld16(gK + (size_t)(s0r) * 1024,        &sK[buf][wv * 8]);           \
        gld16(gK + (size_t)((s0r) + 32) * 1024, &sK[buf][2048 + wv * 8]);    \
        gld16(gV + (s0r),                       &sV[buf][wv * 8]);           \
        gld16(gV + (s0r) + 32 * 1024,           &sV[buf][2048 + wv * 8]);    \
    } while (0)

    const int niter = CAUSAL ? (2 * qb + 2) : 16;

    STAGE_KV(0, 0);
    __syncthreads();

    f32x4 acc_o[2][4] = {};
    f32x4 l_run[2] = {};

    for (int it = 0; it < niter; ++it) {
        const int s0 = it * 64;
        const int cur = it & 1;

        if (it + 1 < niter) STAGE_KV(cur ^ 1, s0 + 64);

        f32x4 accs[2][4] = {};
#pragma unroll
        for (int ni = 0; ni < 4; ++ni)
#pragma unroll
            for (int kk = 0; kk < 2; ++kk) {
                const bf16x8 kf = __builtin_bit_cast(bf16x8,
                    *(const u16x8*)(&sK[cur][(ni * 16 + lm) * 64
                        + ((((kk << 2) | kq)) ^ (lm & 7)) * 8]));
#pragma unroll
                for (int mi = 0; mi < 2; ++mi)
                    accs[mi][ni] = __builtin_amdgcn_mfma_f32_16x16x32_bf16(
                        qf[mi][kk], kf, accs[mi][ni], 0, 0, 0);
            }

        if (SBIAS) {
#pragma unroll
            for (int ni = 0; ni < 4; ++ni) {
                const float sv = cs * sb[s0 + ni * 16 + lm];
#pragma unroll
                for (int mi = 0; mi < 2; ++mi)
#pragma unroll
                    for (int r = 0; r < 4; ++r) accs[mi][ni][r] += sv;
            }
        }
        if (CAUSAL && (s0 + 63 > tb)) {
#pragma unroll
            for (int ni = 0; ni < 4; ++ni) {
                const int s = s0 + ni * 16 + lm;
#pragma unroll
                for (int mi = 0; mi < 2; ++mi)
#pragma unroll
                    for (int r = 0; r < 4; ++r)
                        if (s > tb + mi * 16 + kq * 4 + r) accs[mi][ni][r] = -1e30f;
            }
        }

#pragma unroll
        for (int mi = 0; mi < 2; ++mi)
#pragma unroll
            for (int ni = 0; ni < 4; ++ni)
#pragma unroll
                for (int r = 0; r < 4; ++r) {
                    const float e = __expf(accs[mi][ni][r]);
                    l_run[mi][r] += e;
                    sPw[(mi * 16 + kq * 4 + r) * 72 + ni * 16 + lm] = (__bf16)e;
                }

#pragma unroll
        for (int kk = 0; kk < 2; ++kk) {
            bf16x8 pf[2];
#pragma unroll
            for (int mi = 0; mi < 2; ++mi)
                pf[mi] = __builtin_bit_cast(bf16x8,
                    *(const u16x8*)(sPw + (mi * 16 + lm) * 72 + kk * 32 + kq * 8));
#pragma unroll
            for (int di = 0; di < 4; ++di) {
                const bf16x8 vf = __builtin_bit_cast(bf16x8,
                    *(const u16x8*)(&sV[cur][(di * 16 + lm) * 64
                        + ((((kk << 2) | kq)) ^ (lm & 7)) * 8]));
#pragma unroll
                for (int mi = 0; mi < 2; ++mi)
                    acc_o[mi][di] = __builtin_amdgcn_mfma_f32_16x16x32_bf16(
                        pf[mi], vf, acc_o[mi][di], 0, 0, 0);
            }
        }

        __syncthreads();
    }
#undef STAGE_KV

#pragma unroll
    for (int mi = 0; mi < 2; ++mi) {
        f32x4 lt = l_run[mi];
#pragma unroll
        for (int x = 1; x < 16; x <<= 1)
#pragma unroll
            for (int r = 0; r < 4; ++r) lt[r] += __shfl_xor(lt[r], x, 64);
#pragma unroll
        for (int r = 0; r < 4; ++r) lt[r] = 1.f / lt[r];
#pragma unroll
        for (int di = 0; di < 4; ++di)
#pragma unroll
            for (int r = 0; r < 4; ++r) {
                const size_t idx = (size_t)(b * 1024 + tb + mi * 16 + kq * 4 + r) * 1024
                                 + h * 64 + di * 16 + lm;
                O[idx] = __float2bfloat16(acc_o[mi][di][r] * lt[r]);
            }
    }
}

// ---------------------------------------------------------------------------
// LayerNorm over D=1024 (fp32 in, bf16 out), one block per row, 4 elems/thr.
// ---------------------------------------------------------------------------
__global__ __launch_bounds__(256) void ln_kernel(
    const float* __restrict__ xin, const float* __restrict__ g,
    const float* __restrict__ bta, bf16* __restrict__ out)
{
    const int row = blockIdx.x;
    const int t = threadIdx.x;
    const size_t base = (size_t)row * 1024 + t * 4;

    const float4 f = *(const float4*)(xin + base);
    const float v[4] = {f.x, f.y, f.z, f.w};
    float s1 = v[0] + v[1] + v[2] + v[3];
    float s2 = v[0]*v[0] + v[1]*v[1] + v[2]*v[2] + v[3]*v[3];
#pragma unroll
    for (int off = 32; off > 0; off >>= 1) {
        s1 += __shfl_xor(s1, off, 64);
        s2 += __shfl_xor(s2, off, 64);
    }
    __shared__ float r1[4], r2[4];
    if ((t & 63) == 0) { r1[t >> 6] = s1; r2[t >> 6] = s2; }
    __syncthreads();
    s1 = r1[0] + r1[1] + r1[2] + r1[3];
    s2 = r2[0] + r2[1] + r2[2] + r2[3];
    const float mean = s1 * (1.f / 1024.f);
    const float var  = s2 * (1.f / 1024.f) - mean * mean;
    const float rstd = rsqrtf(var + 1e-5f);
#pragma unroll
    for (int j = 0; j < 4; ++j) {
        const int c = t * 4 + j;
        out[base + j] = __float2bfloat16((v[j] - mean) * rstd * g[c] + bta[c]);
    }
}

// ---------------------------------------------------------------------------
extern "C" void kernel_launch(void* const* d_in, const int* in_sizes, int n_in,
                              void* d_out, int out_size, void* d_ws, size_t ws_size,
                              hipStream_t stream)
{
    const float* x       = (const float*)d_in[0];
    const float* memory  = (const float*)d_in[1];
    const float* sbias   = (const float*)d_in[2];
    const float* sa_bq = (const float*)d_in[7];
    const float* sa_bk = (const float*)d_in[9];
    const float* sa_bv = (const float*)d_in[11];
    const float* sa_bo = (const float*)d_in[13];
    const float* ca_bq = (const float*)d_in[16];
    const float* ca_bk = (const float*)d_in[18];
    const float* ca_bv = (const float*)d_in[20];
    const float* ca_bo = (const float*)d_in[22];
    const float* ca_scale = (const float*)d_in[23];
    const float* ln1_g = (const float*)d_in[24]; const float* ln1_b = (const float*)d_in[25];
    const float* ln2_g = (const float*)d_in[26]; const float* ln2_b = (const float*)d_in[27];
    const float* ln3_g = (const float*)d_in[28]; const float* ln3_b = (const float*)d_in[29];
    const float* b1 = (const float*)d_in[31];
    const float* b2 = (const float*)d_in[33];

    char* ws = (char*)d_ws;
    const size_t MB = (size_t)1 << 20;
    float* x1    = (float*)(ws + 0 * MB);
    float* x2    = (float*)(ws + 16 * MB);
    bf16* lnbuf  = (bf16*)(ws + 32 * MB);
    bf16* Qb     = (bf16*)(ws + 40 * MB);
    bf16* Kb     = (bf16*)(ws + 48 * MB);
    bf16* Vtb    = (bf16*)(ws + 56 * MB);
    bf16* Ob     = (bf16*)(ws + 64 * MB);
    bf16* ffnmid = (bf16*)(ws + 40 * MB);
    bf16* wx     = (bf16*)(ws + 72 * MB);
    bf16* wmem   = (bf16*)(ws + 80 * MB);
    bf16* bw     = (bf16*)(ws + 88 * MB);
    bf16* b_sa_wq = bw + 0 * 1048576, *b_sa_wk = bw + 1 * 1048576;
    bf16* b_sa_wo = bw + 3 * 1048576;
    bf16* b_ca_wq = bw + 4 * 1048576, *b_ca_wk = bw + 5 * 1048576;
    bf16* b_ca_wo = bw + 7 * 1048576;
    bf16* b_w1   = (bf16*)(ws + 104 * MB);
    bf16* b_w2   = (bf16*)(ws + 112 * MB);

    const int M = 4096;
    dim3 blk256(256), blk512(512);
    const dim3 gQ(256);    // (4096/128)*(1024/128): 128^2 tiles
    const dim3 gKV(512);   // (4096/128)*(2048/128)
    const dim3 gFA(512);   // 64 (b,h) x 8 q-blocks
    const dim3 g256(256);  // FFN1: 16x16 tiles (256^2)

    CvtSrcs cs;
    for (int c = 0; c < 4; ++c) {
        cs.p[c]      = x + (size_t)c * 1048576;
        cs.p[4 + c]  = memory + (size_t)c * 1048576;
        cs.p[16 + c] = (const float*)d_in[30] + (size_t)c * 1048576;  // w1
        cs.p[20 + c] = (const float*)d_in[32] + (size_t)c * 1048576;  // w2
    }
    cs.p[8]  = (const float*)d_in[6];
    cs.p[9]  = (const float*)d_in[8];
    cs.p[10] = (const float*)d_in[10];
    cs.p[11] = (const float*)d_in[12];
    cs.p[12] = (const float*)d_in[15];
    cs.p[13] = (const float*)d_in[17];
    cs.p[14] = (const float*)d_in[19];
    cs.p[15] = (const float*)d_in[21];
    // cvt + fused LN1 (segments 0-3 = x -> lnbuf)
    cvt_all<<<24 * 1048576 / 2048, blk256, 0, stream>>>(
        cs, wx, ln1_g, ln1_b, lnbuf);

    // ---- self-attention ----
    gemm_bt<EPI_QSCALE><<<gQ, blk256, 0, stream>>>(
        lnbuf, b_sa_wq, sa_bq, nullptr, nullptr, Qb, M, 1024, 1024, 1024);
    gemm_bt<EPI_KV><<<gKV, blk256, 0, stream>>>(
        wx, b_sa_wk, sa_bk, sa_bv, nullptr, Kb, M, 2048, 1024, 1024);
    flash_attn<true, false><<<gFA, blk256, 0, stream>>>(Qb, Kb, Vtb, Ob, nullptr, nullptr);
    gemm_bt<EPI_RES_F32_F32OUT><<<gQ, blk256, 0, stream>>>(
        Ob, b_sa_wo, sa_bo, nullptr, x, x1, M, 1024, 1024, 1024);

    // ---- cross-attention ----
    ln_kernel<<<4096, blk256, 0, stream>>>(x1, ln2_g, ln2_b, lnbuf);
    gemm_bt<EPI_QSCALE><<<gQ, blk256, 0, stream>>>(
        lnbuf, b_ca_wq, ca_bq, nullptr, nullptr, Qb, M, 1024, 1024, 1024);
    gemm_bt<EPI_KV><<<gKV, blk256, 0, stream>>>(
        wmem, b_ca_wk, ca_bk, ca_bv, nullptr, Kb, M, 2048, 1024, 1024);
    flash_attn<false, true><<<gFA, blk256, 0, stream>>>(Qb, Kb, Vtb, Ob, sbias, ca_scale);
    gemm_bt<EPI_RES_F32_F32OUT><<<gQ, blk256, 0, stream>>>(
        Ob, b_ca_wo, ca_bo, nullptr, x1, x2, M, 1024, 1024, 1024);

    // ---- FFN ----
    ln_kernel<<<4096, blk256, 0, stream>>>(x2, ln3_g, ln3_b, lnbuf);
    gemm256<EPI_RELU><<<g256, blk512, 0, stream>>>(
        lnbuf, b_w1, b1, ffnmid, 4096, 1024, 1024);
    // FFN2 direct (R8): K=4096, fused residual + bias, fp32 out. Replaces
    // split-K partials (32MB) + ffn2_reduce (64MB traffic + launch).
    gemm_bt<EPI_RES_F32_F32OUT><<<gQ, blk256, 0, stream>>>(
        ffnmid, b_w2, b2, nullptr, x2, d_out, M, 1024, 4096, 4096);
}

// Round 9
// 457.270 us; speedup vs baseline: 1.0976x; 1.0006x over previous
//
#include <hip/hip_runtime.h>
#include <hip/hip_bf16.h>
#include <cmath>
#include <stdint.h>

typedef __hip_bfloat16 bf16;
typedef __attribute__((ext_vector_type(8))) __bf16 bf16x8;
typedef __attribute__((ext_vector_type(8))) unsigned short u16x8;
typedef __attribute__((ext_vector_type(4))) float f32x4;

// Async global->LDS DMA, 16B per lane. LDS dest must be wave-uniform base;
// HW adds lane*16.
__device__ __forceinline__ void gld16(const void* g, const void* l)
{
    __builtin_amdgcn_global_load_lds(
        (const __attribute__((address_space(1))) unsigned int*)(unsigned long long)g,
        (__attribute__((address_space(3))) unsigned int*)(unsigned int)(unsigned long long)l,
        16, 0, 0);
}

// ---------------------------------------------------------------------------
// Fused fp32 -> bf16 conversion of all 12 tensors in one launch.
// R8 (verified): LN1 fused for segments 0-3 (the x tensor).
// ---------------------------------------------------------------------------
struct CvtSrcs { const float* p[24]; };

__global__ __launch_bounds__(256) void cvt_all(
    CvtSrcs s, bf16* __restrict__ dst,
    const float* __restrict__ lg, const float* __restrict__ lb,
    bf16* __restrict__ lnout)
{
    const int t = threadIdx.x;
    const int i = (blockIdx.x * 256 + t) * 8;
    const int seg = i >> 20;
    const float* sp = s.p[seg] + (i & 1048575);
    const float4 a = *(const float4*)(sp);
    const float4 b = *(const float4*)(sp + 4);
    const float v[8] = {a.x, a.y, a.z, a.w, b.x, b.y, b.z, b.w};
    bf16 tmp[8];
#pragma unroll
    for (int j = 0; j < 8; ++j) tmp[j] = __float2bfloat16(v[j]);
    *(uint4*)(dst + i) = *(const uint4*)tmp;

    if (seg < 4) {   // x tensor: fused LayerNorm (seg uniform per block)
        float s1 = 0.f, s2 = 0.f;
#pragma unroll
        for (int j = 0; j < 8; ++j) { s1 += v[j]; s2 += v[j] * v[j]; }
#pragma unroll
        for (int off = 32; off > 0; off >>= 1) {
            s1 += __shfl_xor(s1, off, 64);
            s2 += __shfl_xor(s2, off, 64);
        }
        __shared__ float r1[4], r2[4];
        const int w = t >> 6;
        if ((t & 63) == 0) { r1[w] = s1; r2[w] = s2; }
        __syncthreads();
        const int rw = (w >> 1) * 2;        // first wave of this row
        s1 = r1[rw] + r1[rw + 1];
        s2 = r2[rw] + r2[rw + 1];
        const float mean = s1 * (1.f / 1024.f);
        const float var  = s2 * (1.f / 1024.f) - mean * mean;
        const float rstd = rsqrtf(var + 1e-5f);
        bf16 lt[8];
        const int c0 = i & 1023;
#pragma unroll
        for (int j = 0; j < 8; ++j)
            lt[j] = __float2bfloat16((v[j] - mean) * rstd * lg[c0 + j] + lb[c0 + j]);
        *(uint4*)(lnout + i) = *(const uint4*)lt;
    }
}

enum {
    EPI_QSCALE = 0,          // out_bf16 = (C + bias) * 0.125
    EPI_KV = 1,              // N=2048 fused: K plain / Vt transposed
    EPI_RELU = 2,            // out_bf16 = relu(C + bias)
    EPI_RES_F32_F32OUT = 3,  // out_f32  = res_f32 + C + bias
    EPI_PART = 4             // (unused since R8)
};

// ---------------------------------------------------------------------------
// gemm256: C[4096,N] = A[4096,K] @ W[N,K]^T (+bias). 256x256 tile, BK=64,
// 512 thr = 8 waves (2M x 4N), per-wave 128x64 out. K-loop (R4, verified):
// counted-vmcnt 4-phase pipeline. Epilogue (R5, verified): LDS-bounce store.
// Used for FFN1 (grid 256 = full machine).
// ---------------------------------------------------------------------------
template <int EPI>
__global__ __launch_bounds__(512, 2) void gemm256(
    const bf16* __restrict__ A, const bf16* __restrict__ W,
    const float* __restrict__ bias, void* __restrict__ out,
    int N, int Kiter, int Kstride)
{
    __shared__ __align__(16) unsigned short sA[2][2][128 * 64];  // [slot][half]
    __shared__ __align__(16) unsigned short sB[2][2][128 * 64];

    const int t  = threadIdx.x;          // 0..511
    const int l  = t & 63;
    const int w  = t >> 6;               // 0..7
    const int wv = w * 64;
    const int wr = w >> 2;               // 0..1 : M-half of block
    const int wc = w & 3;                // 0..3 : N-quarter of block
    const int lm = l & 15;
    const int kq = l >> 4;
    const int rx = lm & 7;               // read-side swizzle row bits

    int bx = blockIdx.x;
    // XCD-aware: xcd owns 2 contiguous bm-bands; bm iterates fastest.
    const int xcd = bx & 7;
    const int ib  = bx >> 3;
    const int bm  = xcd * 2 + (ib & 1);
    const int bn  = ib >> 1;

    const bf16* gA = A + (size_t)(bm * 256 + (t >> 3)) * Kstride
                       + ((t & 7) ^ ((t >> 3) & 7)) * 8;
    const bf16* gB = W + (size_t)(bn * 256 + (t >> 3)) * Kstride
                       + ((t & 7) ^ ((t >> 3) & 7)) * 8;

#define SQA(slot, kt, j)                                        \
    gld16(gA + (size_t)((j) * 64) * Kstride + (kt) * 64,        \
          &sA[slot][(j) >> 1][(((j) & 1) * 512 + wv) * 8])
#define SQB(slot, kt, j)                                        \
    gld16(gB + (size_t)((j) * 64) * Kstride + (kt) * 64,        \
          &sB[slot][(j) >> 1][(((j) & 1) * 512 + wv) * 8])

    bf16x8 af[4][2], bg[2][2];

#define READ_AF(s_, mh)                                                     \
    do {                                                                    \
        _Pragma("unroll")                                                   \
        for (int mi = 0; mi < 4; ++mi)                                      \
            _Pragma("unroll")                                               \
            for (int kk = 0; kk < 2; ++kk) {                                \
                const int lr = (mh) * 64 + mi * 16 + lm;                    \
                const int sl = ((kk << 2) | kq) ^ rx;                       \
                af[mi][kk] = __builtin_bit_cast(bf16x8,                     \
                    *(const u16x8*)(&sA[s_][wr][lr * 64 + sl * 8]));        \
            }                                                               \
    } while (0)
#define READ_BG(s_, nh)                                                     \
    do {                                                                    \
        _Pragma("unroll")                                                   \
        for (int ni = 0; ni < 2; ++ni)                                      \
            _Pragma("unroll")                                               \
            for (int kk = 0; kk < 2; ++kk) {                                \
                const int lr = (wc & 1) * 64 + (nh) * 32 + ni * 16 + lm;    \
                const int sl = ((kk << 2) | kq) ^ rx;                       \
                bg[ni][kk] = __builtin_bit_cast(bf16x8,                     \
                    *(const u16x8*)(&sB[s_][wc >> 1][lr * 64 + sl * 8]));   \
            }                                                               \
    } while (0)
#define MFMA_QUAD(mh, nh)                                                   \
    do {                                                                    \
        __builtin_amdgcn_s_setprio(1);                                      \
        _Pragma("unroll")                                                   \
        for (int mi = 0; mi < 4; ++mi)                                      \
            _Pragma("unroll")                                               \
            for (int ni = 0; ni < 2; ++ni)                                  \
                _Pragma("unroll")                                           \
                for (int kk = 0; kk < 2; ++kk)                              \
                    acc[(mh) * 4 + mi][(nh) * 2 + ni] =                     \
                        __builtin_amdgcn_mfma_f32_16x16x32_bf16(            \
                            af[mi][kk], bg[ni][kk],                         \
                            acc[(mh) * 4 + mi][(nh) * 2 + ni], 0, 0, 0);    \
        __builtin_amdgcn_s_setprio(0);                                      \
    } while (0)
#define BARRIER() do { __builtin_amdgcn_s_barrier();                        \
                       __builtin_amdgcn_sched_barrier(0); } while (0)
#define WAITV2() asm volatile("s_waitcnt vmcnt(2)" ::: "memory")
#define WAITV0() asm volatile("s_waitcnt vmcnt(0)" ::: "memory")

    f32x4 acc[8][4] = {};
    const int NT = Kiter >> 6;

    // prologue: tile 0 -> slot 0; issue order b0 b1 b2 b3 a0 a2 a1 a3
    SQB(0, 0, 0); SQB(0, 0, 1); SQB(0, 0, 2); SQB(0, 0, 3);
    SQA(0, 0, 0); SQA(0, 0, 2); SQA(0, 0, 1); SQA(0, 0, 3);

    for (int tt = 0; tt < NT - 1; ++tt) {
        const int s = tt & 1, d = s ^ 1, kn = tt + 1;
        WAITV2(); BARRIER();
        SQB(d, kn, 0); SQB(d, kn, 1);
        READ_AF(s, 0); READ_BG(s, 0);
        MFMA_QUAD(0, 0);
        WAITV2(); BARRIER();
        SQB(d, kn, 2); SQB(d, kn, 3);
        READ_AF(s, 1);
        MFMA_QUAD(1, 0);
        SQA(d, kn, 0); SQA(d, kn, 2);
        READ_BG(s, 1);
        MFMA_QUAD(1, 1);
        SQA(d, kn, 1); SQA(d, kn, 3);
        READ_AF(s, 0);
        MFMA_QUAD(0, 1);
    }
    {   // final tile
        const int s = (NT - 1) & 1;
        WAITV2(); BARRIER();
        READ_AF(s, 0); READ_BG(s, 0);
        MFMA_QUAD(0, 0);
        WAITV0(); BARRIER();
        READ_AF(s, 1);
        MFMA_QUAD(1, 0);
        READ_BG(s, 1);
        MFMA_QUAD(1, 1);
        READ_AF(s, 0);
        MFMA_QUAD(0, 1);
    }

    // ---- Epilogue (R5): LDS-bounce vectorized store ----
    __syncthreads();
    unsigned short* scr = (w < 4) ? &sA[0][0][0] + w * 8192
                                  : &sB[0][0][0] + (w - 4) * 8192;

#pragma unroll
    for (int NI = 0; NI < 4; ++NI) {
        const int col = bn * 256 + wc * 64 + NI * 16 + lm;
        const float bv = bias[col];
        const int c  = NI * 2 + (lm >> 3);
        const int ci = lm & 7;
#pragma unroll
        for (int MI = 0; MI < 8; ++MI) {
#pragma unroll
            for (int r = 0; r < 4; ++r) {
                float v = acc[MI][NI][r] + bv;
                if (EPI == EPI_RELU) v = fmaxf(v, 0.f);
                const int row = MI * 16 + kq * 4 + r;
                scr[row * 64 + ((c ^ (row & 7)) * 8) + ci] =
                    __builtin_bit_cast(unsigned short, (__bf16)v);
            }
        }
    }
#pragma unroll
    for (int it = 0; it < 16; ++it) {
        const int row = it * 8 + (l >> 3);
        const int lc  = l & 7;
        const u16x8 vv = *(const u16x8*)&scr[row * 64 + ((lc ^ (row & 7)) * 8)];
        const int Crow = bm * 256 + wr * 128 + row;
        const int Ccol = bn * 256 + wc * 64 + lc * 8;
        *(u16x8*)((bf16*)out + (size_t)Crow * N + Ccol) = vv;
    }
#undef SQA
#undef SQB
#undef READ_AF
#undef READ_BG
#undef MFMA_QUAD
}

// ---------------------------------------------------------------------------
// gemm_bt (R9): C[4096,N] = A[4096,K] @ W[N,K]^T (+bias). 128x64 tile,
// BK=64, 256 thr = 4 waves (2M x 2N), wave-tile 64x32. LDS 48KB (2 slots x
// (A 128x64 + B 64x64)) -> __launch_bounds__(256,3): up to 3 blocks/CU.
// Grid doubles vs R8 (M/128 x N/64): 512 for N=1024, 1024 for KV ->
// 8-12 waves/CU (was 4; occupancy 9.5% was the R8 FFN2 limiter).
// Counted-vmcnt 4-phase schedule re-derived for 6 loads/tile, order
// b0 b1 a0 a2 a1 a3 (sweeps: A 32 rows x4, B 32 rows x2):
//   P0 (mh0,kk0): 6 outstanding, vmcnt(2) certifies {b0,b1,a0,a2}; barrier;
//     stage next b0,b1.  P0 reads af[0..1][0] (rows wr*64+{0,16}: a0|a2),
//     bg[*][0] (b0|b1).
//   P1 (mh1,kk0): 4 outstanding, vmcnt(2) certifies {a1,a3}; barrier;
//     stage next a0,a2.  Reads af[2..3][0] (rows wr*64+{32,48}: a1|a3).
//   P2 (mh1,kk1): wait-free; stage next a1,a3.  P3 (mh0,kk1): wait-free.
// WAR: slot d idle during tile tt except staged writes, all after P0/P1
// barriers; last reads of d were tile tt-1 (before P0 barrier).
// Final tile: vmcnt(2) then vmcnt(0). Never drains mid-loop.
// ---------------------------------------------------------------------------
template <int EPI>
__global__ __launch_bounds__(256, 3) void gemm_bt(
    const bf16* __restrict__ A, const bf16* __restrict__ W,
    const float* __restrict__ bias, const float* __restrict__ bias2,
    const float* __restrict__ res, void* __restrict__ out,
    int M, int N, int Kiter, int Kstride)
{
    __shared__ __align__(16) unsigned short sA[2][128 * 64];
    __shared__ __align__(16) unsigned short sB[2][64 * 64];

    const int t  = threadIdx.x;     // 0..255
    const int l  = t & 63;
    const int w  = t >> 6;          // 0..3
    const int wv = w * 64;
    const int wr = w >> 1;          // 0..1 : M-half (64 rows)
    const int wc = w & 1;           // 0..1 : N-half (32 cols)
    const int lm = l & 15;
    const int kq = l >> 4;
    const int rx = lm & 7;

    const int bx  = blockIdx.x;
    const int xcd = bx & 7;
    const int ib  = bx >> 3;
    const int bm  = xcd * 4 + (ib & 3);   // 32 bm tiles, 4 per XCD
    const int bn  = ib >> 2;

    // Staging source: thread t covers 16B at (row t>>3, phys slot t&7) of a
    // 32-row sweep; logical slot = (t&7)^((t>>3)&7) (inverse swizzle).
    const bf16* gA = A + (size_t)(bm * 128 + (t >> 3)) * Kstride
                       + ((t & 7) ^ ((t >> 3) & 7)) * 8;
    const bf16* gB = W + (size_t)(bn * 64 + (t >> 3)) * Kstride
                       + ((t & 7) ^ ((t >> 3) & 7)) * 8;

    // stage one 32-row sweep j of K-tile kt into slot
#define SQA(slot, kt, j)                                        \
    gld16(gA + (size_t)((j) * 32) * Kstride + (kt) * 64,        \
          &sA[slot][((j) * 256 + wv) * 8])
#define SQB(slot, kt, j)                                        \
    gld16(gB + (size_t)((j) * 32) * Kstride + (kt) * 64,        \
          &sB[slot][((j) * 256 + wv) * 8])

    bf16x8 af[4][2], bg[2][2];

#define READ_A(s_, mh, kk)                                                  \
    do {                                                                    \
        _Pragma("unroll")                                                   \
        for (int m2 = 0; m2 < 2; ++m2) {                                    \
            const int mi = (mh) * 2 + m2;                                   \
            const int lr = wr * 64 + mi * 16 + lm;                          \
            const int sl = (((kk) << 2) | kq) ^ rx;                         \
            af[mi][kk] = __builtin_bit_cast(bf16x8,                         \
                *(const u16x8*)(&sA[s_][lr * 64 + sl * 8]));                \
        }                                                                   \
    } while (0)
#define READ_B(s_, kk)                                                      \
    do {                                                                    \
        _Pragma("unroll")                                                   \
        for (int ni = 0; ni < 2; ++ni) {                                    \
            const int lr = wc * 32 + ni * 16 + lm;                          \
            const int sl = (((kk) << 2) | kq) ^ rx;                         \
            bg[ni][kk] = __builtin_bit_cast(bf16x8,                         \
                *(const u16x8*)(&sB[s_][lr * 64 + sl * 8]));                \
        }                                                                   \
    } while (0)
#define MFMA_PH(mh, kk)                                                     \
    do {                                                                    \
        __builtin_amdgcn_s_setprio(1);                                      \
        _Pragma("unroll")                                                   \
        for (int m2 = 0; m2 < 2; ++m2)                                      \
            _Pragma("unroll")                                               \
            for (int ni = 0; ni < 2; ++ni)                                  \
                acc[(mh) * 2 + m2][ni] =                                    \
                    __builtin_amdgcn_mfma_f32_16x16x32_bf16(                \
                        af[(mh) * 2 + m2][kk], bg[ni][kk],                  \
                        acc[(mh) * 2 + m2][ni], 0, 0, 0);                   \
        __builtin_amdgcn_s_setprio(0);                                      \
    } while (0)
#define BARRIER() do { __builtin_amdgcn_s_barrier();                        \
                       __builtin_amdgcn_sched_barrier(0); } while (0)
#define WAITV2() asm volatile("s_waitcnt vmcnt(2)" ::: "memory")
#define WAITV0() asm volatile("s_waitcnt vmcnt(0)" ::: "memory")

    f32x4 acc[4][2] = {};
    const int NT = Kiter >> 6;

    // prologue: tile 0 -> slot 0; order b0 b1 a0 a2 a1 a3
    SQB(0, 0, 0); SQB(0, 0, 1);
    SQA(0, 0, 0); SQA(0, 0, 2);
    SQA(0, 0, 1); SQA(0, 0, 3);

    for (int tt = 0; tt < NT - 1; ++tt) {
        const int s = tt & 1, d = s ^ 1, kn = tt + 1;
        // P0 (mh0,kk0): certify b0,b1,a0,a2 of tile tt (6 outstanding)
        WAITV2(); BARRIER();
        SQB(d, kn, 0); SQB(d, kn, 1);
        READ_A(s, 0, 0); READ_B(s, 0);
        MFMA_PH(0, 0);
        // P1 (mh1,kk0): certify a1,a3 (4 outstanding)
        WAITV2(); BARRIER();
        SQA(d, kn, 0); SQA(d, kn, 2);
        READ_A(s, 1, 0);
        MFMA_PH(1, 0);
        // P2 (mh1,kk1): wait-free
        SQA(d, kn, 1); SQA(d, kn, 3);
        READ_A(s, 1, 1); READ_B(s, 1);
        MFMA_PH(1, 1);
        // P3 (mh0,kk1): wait-free
        READ_A(s, 0, 1);
        MFMA_PH(0, 1);
    }
    {   // final tile: no staging
        const int s = (NT - 1) & 1;
        WAITV2(); BARRIER();
        READ_A(s, 0, 0); READ_B(s, 0);
        MFMA_PH(0, 0);
        WAITV0(); BARRIER();
        READ_A(s, 1, 0);
        MFMA_PH(1, 0);
        READ_A(s, 1, 1); READ_B(s, 1);
        MFMA_PH(1, 1);
        READ_A(s, 0, 1);
        MFMA_PH(0, 1);
    }
#undef SQA
#undef SQB
#undef READ_A
#undef READ_B
#undef MFMA_PH
#undef BARRIER
#undef WAITV2
#undef WAITV0

    // Epilogue. C/D: col = lane&15 (+16*ni), row = kq*4 + r (+16*mi).
#pragma unroll
    for (int ni = 0; ni < 2; ++ni) {
        const int col = bn * 64 + wc * 32 + ni * 16 + lm;
        float bv = 0.f;
        if (EPI == EPI_KV) bv = (col < 1024) ? bias[col] : bias2[col - 1024];
        else bv = bias[col];
#pragma unroll
        for (int mi = 0; mi < 4; ++mi) {
#pragma unroll
            for (int r = 0; r < 4; ++r) {
                const int row = bm * 128 + wr * 64 + mi * 16 + kq * 4 + r;
                float v = acc[mi][ni][r] + bv;
                if (EPI == EPI_QSCALE) v *= 0.125f;
                if (EPI == EPI_KV) {
                    if (col < 1024) {
                        ((bf16*)out)[(size_t)row * 1024 + col] = __float2bfloat16(v);
                    } else {
                        const int ch = col - 1024;  // h*64 + d
                        const size_t idx = (size_t)4 * 1048576 +
                            ((size_t)((row >> 10) * 16 + (ch >> 6)) * 64 + (ch & 63)) * 1024
                            + (row & 1023);
                        ((bf16*)out)[idx] = __float2bfloat16(v);
                    }
                } else if (EPI == EPI_RES_F32_F32OUT) {
                    const size_t idx = (size_t)row * N + col;
                    ((float*)out)[idx] = v + res[idx];
                } else {
                    ((bf16*)out)[(size_t)row * N + col] = __float2bfloat16(v);
                }
            }
        }
    }
}

// ---------------------------------------------------------------------------
// Flash attention (MFMA). R6a/R6b verified: XCD-local remap + swizzled
// conflict-free K/V tiles.
// ---------------------------------------------------------------------------
template <bool CAUSAL, bool SBIAS>
__global__ __launch_bounds__(256, 2) void flash_attn(
    const bf16* __restrict__ Q, const bf16* __restrict__ K,
    const bf16* __restrict__ Vt, bf16* __restrict__ O,
    const float* __restrict__ sbias, const float* __restrict__ scale_ptr)
{
    __shared__ __align__(16) unsigned short sK[2][64 * 64];
    __shared__ __align__(16) unsigned short sV[2][64 * 64];
    __shared__ __align__(16) unsigned short sP[4 * 32 * 72];

    const int t  = threadIdx.x;
    const int l  = t & 63;
    const int w  = t >> 6;
    const int wv = w * 64;
    const int lm = l & 15;
    const int kq = l >> 4;

    const int bh = blockIdx.x & 63;      // same-XCD for all 8 q-blocks of bh
    const int qb = blockIdx.x >> 6;
    const int h  = bh & 15;
    const int b  = bh >> 4;

    const int tb = qb * 128 + w * 32;
    const size_t qrow0 = (size_t)(b * 1024 + tb) * 1024 + h * 64;

    bf16x8 qf[2][2];
#pragma unroll
    for (int mi = 0; mi < 2; ++mi)
#pragma unroll
        for (int kk = 0; kk < 2; ++kk)
            qf[mi][kk] = __builtin_bit_cast(bf16x8,
                *(const u16x8*)(Q + qrow0 + (size_t)(mi * 16 + lm) * 1024 + kk * 32 + kq * 8));

    float cs = 0.f; const float* sb = nullptr;
    if (SBIAS) { cs = scale_ptr[0]; sb = sbias + b * 1024; }

    const bf16* gK = K  + (size_t)(b * 1024 + (t >> 3)) * 1024 + h * 64
                   + ((t & 7) ^ ((t >> 3) & 7)) * 8;
    const bf16* gV = Vt + (size_t)((b * 16 + h) * 64 + (t >> 3)) * 1024
                   + ((t & 7) ^ ((t >> 3) & 7)) * 8;
    __bf16* sPw = (__bf16*)sP + w * 32 * 72;

#define STAGE_KV(buf, s0r)                                                   \
    do {                                                                     \
        gld16(gK + (size_t)(s0r) * 1024,        &sK[buf][wv * 8]);           \
        gld16(gK + (size_t)((s0r) + 32) * 1024, &sK[buf][2048 + wv * 8]);    \
        gld16(gV + (s0r),                       &sV[buf][wv * 8]);           \
        gld16(gV + (s0r) + 32 * 1024,           &sV[buf][2048 + wv * 8]);    \
    } while (0)

    const int niter = CAUSAL ? (2 * qb + 2) : 16;

    STAGE_KV(0, 0);
    __syncthreads();

    f32x4 acc_o[2][4] = {};
    f32x4 l_run[2] = {};

    for (int it = 0; it < niter; ++it) {
        const int s0 = it * 64;
        const int cur = it & 1;

        if (it + 1 < niter) STAGE_KV(cur ^ 1, s0 + 64);

        f32x4 accs[2][4] = {};
#pragma unroll
        for (int ni = 0; ni < 4; ++ni)
#pragma unroll
            for (int kk = 0; kk < 2; ++kk) {
                const bf16x8 kf = __builtin_bit_cast(bf16x8,
                    *(const u16x8*)(&sK[cur][(ni * 16 + lm) * 64
                        + ((((kk << 2) | kq)) ^ (lm & 7)) * 8]));
#pragma unroll
                for (int mi = 0; mi < 2; ++mi)
                    accs[mi][ni] = __builtin_amdgcn_mfma_f32_16x16x32_bf16(
                        qf[mi][kk], kf, accs[mi][ni], 0, 0, 0);
            }

        if (SBIAS) {
#pragma unroll
            for (int ni = 0; ni < 4; ++ni) {
                const float sv = cs * sb[s0 + ni * 16 + lm];
#pragma unroll
                for (int mi = 0; mi < 2; ++mi)
#pragma unroll
                    for (int r = 0; r < 4; ++r) accs[mi][ni][r] += sv;
            }
        }
        if (CAUSAL && (s0 + 63 > tb)) {
#pragma unroll
            for (int ni = 0; ni < 4; ++ni) {
                const int s = s0 + ni * 16 + lm;
#pragma unroll
                for (int mi = 0; mi < 2; ++mi)
#pragma unroll
                    for (int r = 0; r < 4; ++r)
                        if (s > tb + mi * 16 + kq * 4 + r) accs[mi][ni][r] = -1e30f;
            }
        }

#pragma unroll
        for (int mi = 0; mi < 2; ++mi)
#pragma unroll
            for (int ni = 0; ni < 4; ++ni)
#pragma unroll
                for (int r = 0; r < 4; ++r) {
                    const float e = __expf(accs[mi][ni][r]);
                    l_run[mi][r] += e;
                    sPw[(mi * 16 + kq * 4 + r) * 72 + ni * 16 + lm] = (__bf16)e;
                }

#pragma unroll
        for (int kk = 0; kk < 2; ++kk) {
            bf16x8 pf[2];
#pragma unroll
            for (int mi = 0; mi < 2; ++mi)
                pf[mi] = __builtin_bit_cast(bf16x8,
                    *(const u16x8*)(sPw + (mi * 16 + lm) * 72 + kk * 32 + kq * 8));
#pragma unroll
            for (int di = 0; di < 4; ++di) {
                const bf16x8 vf = __builtin_bit_cast(bf16x8,
                    *(const u16x8*)(&sV[cur][(di * 16 + lm) * 64
                        + ((((kk << 2) | kq)) ^ (lm & 7)) * 8]));
#pragma unroll
                for (int mi = 0; mi < 2; ++mi)
                    acc_o[mi][di] = __builtin_amdgcn_mfma_f32_16x16x32_bf16(
                        pf[mi], vf, acc_o[mi][di], 0, 0, 0);
            }
        }

        __syncthreads();
    }
#undef STAGE_KV

#pragma unroll
    for (int mi = 0; mi < 2; ++mi) {
        f32x4 lt = l_run[mi];
#pragma unroll
        for (int x = 1; x < 16; x <<= 1)
#pragma unroll
            for (int r = 0; r < 4; ++r) lt[r] += __shfl_xor(lt[r], x, 64);
#pragma unroll
        for (int r = 0; r < 4; ++r) lt[r] = 1.f / lt[r];
#pragma unroll
        for (int di = 0; di < 4; ++di)
#pragma unroll
            for (int r = 0; r < 4; ++r) {
                const size_t idx = (size_t)(b * 1024 + tb + mi * 16 + kq * 4 + r) * 1024
                                 + h * 64 + di * 16 + lm;
                O[idx] = __float2bfloat16(acc_o[mi][di][r] * lt[r]);
            }
    }
}

// ---------------------------------------------------------------------------
// LayerNorm over D=1024 (fp32 in, bf16 out), one block per row, 4 elems/thr.
// ---------------------------------------------------------------------------
__global__ __launch_bounds__(256) void ln_kernel(
    const float* __restrict__ xin, const float* __restrict__ g,
    const float* __restrict__ bta, bf16* __restrict__ out)
{
    const int row = blockIdx.x;
    const int t = threadIdx.x;
    const size_t base = (size_t)row * 1024 + t * 4;

    const float4 f = *(const float4*)(xin + base);
    const float v[4] = {f.x, f.y, f.z, f.w};
    float s1 = v[0] + v[1] + v[2] + v[3];
    float s2 = v[0]*v[0] + v[1]*v[1] + v[2]*v[2] + v[3]*v[3];
#pragma unroll
    for (int off = 32; off > 0; off >>= 1) {
        s1 += __shfl_xor(s1, off, 64);
        s2 += __shfl_xor(s2, off, 64);
    }
    __shared__ float r1[4], r2[4];
    if ((t & 63) == 0) { r1[t >> 6] = s1; r2[t >> 6] = s2; }
    __syncthreads();
    s1 = r1[0] + r1[1] + r1[2] + r1[3];
    s2 = r2[0] + r2[1] + r2[2] + r2[3];
    const float mean = s1 * (1.f / 1024.f);
    const float var  = s2 * (1.f / 1024.f) - mean * mean;
    const float rstd = rsqrtf(var + 1e-5f);
#pragma unroll
    for (int j = 0; j < 4; ++j) {
        const int c = t * 4 + j;
        out[base + j] = __float2bfloat16((v[j] - mean) * rstd * g[c] + bta[c]);
    }
}

// ---------------------------------------------------------------------------
extern "C" void kernel_launch(void* const* d_in, const int* in_sizes, int n_in,
                              void* d_out, int out_size, void* d_ws, size_t ws_size,
                              hipStream_t stream)
{
    const float* x       = (const float*)d_in[0];
    const float* memory  = (const float*)d_in[1];
    const float* sbias   = (const float*)d_in[2];
    const float* sa_bq = (const float*)d_in[7];
    const float* sa_bk = (const float*)d_in[9];
    const float* sa_bv = (const float*)d_in[11];
    const float* sa_bo = (const float*)d_in[13];
    const float* ca_bq = (const float*)d_in[16];
    const float* ca_bk = (const float*)d_in[18];
    const float* ca_bv = (const float*)d_in[20];
    const float* ca_bo = (const float*)d_in[22];
    const float* ca_scale = (const float*)d_in[23];
    const float* ln1_g = (const float*)d_in[24]; const float* ln1_b = (const float*)d_in[25];
    const float* ln2_g = (const float*)d_in[26]; const float* ln2_b = (const float*)d_in[27];
    const float* ln3_g = (const float*)d_in[28]; const float* ln3_b = (const float*)d_in[29];
    const float* b1 = (const float*)d_in[31];
    const float* b2 = (const float*)d_in[33];

    char* ws = (char*)d_ws;
    const size_t MB = (size_t)1 << 20;
    float* x1    = (float*)(ws + 0 * MB);
    float* x2    = (float*)(ws + 16 * MB);
    bf16* lnbuf  = (bf16*)(ws + 32 * MB);
    bf16* Qb     = (bf16*)(ws + 40 * MB);
    bf16* Kb     = (bf16*)(ws + 48 * MB);
    bf16* Vtb    = (bf16*)(ws + 56 * MB);
    bf16* Ob     = (bf16*)(ws + 64 * MB);
    bf16* ffnmid = (bf16*)(ws + 40 * MB);
    bf16* wx     = (bf16*)(ws + 72 * MB);
    bf16* wmem   = (bf16*)(ws + 80 * MB);
    bf16* bw     = (bf16*)(ws + 88 * MB);
    bf16* b_sa_wq = bw + 0 * 1048576, *b_sa_wk = bw + 1 * 1048576;
    bf16* b_sa_wo = bw + 3 * 1048576;
    bf16* b_ca_wq = bw + 4 * 1048576, *b_ca_wk = bw + 5 * 1048576;
    bf16* b_ca_wo = bw + 7 * 1048576;
    bf16* b_w1   = (bf16*)(ws + 104 * MB);
    bf16* b_w2   = (bf16*)(ws + 112 * MB);

    const int M = 4096;
    dim3 blk256(256), blk512(512);
    const dim3 gQ(512);    // (4096/128)*(1024/64): 128x64 tiles
    const dim3 gKV(1024);  // (4096/128)*(2048/64)
    const dim3 gFA(512);   // 64 (b,h) x 8 q-blocks
    const dim3 g256(256);  // FFN1: 16x16 tiles (256^2)

    CvtSrcs cs;
    for (int c = 0; c < 4; ++c) {
        cs.p[c]      = x + (size_t)c * 1048576;
        cs.p[4 + c]  = memory + (size_t)c * 1048576;
        cs.p[16 + c] = (const float*)d_in[30] + (size_t)c * 1048576;  // w1
        cs.p[20 + c] = (const float*)d_in[32] + (size_t)c * 1048576;  // w2
    }
    cs.p[8]  = (const float*)d_in[6];
    cs.p[9]  = (const float*)d_in[8];
    cs.p[10] = (const float*)d_in[10];
    cs.p[11] = (const float*)d_in[12];
    cs.p[12] = (const float*)d_in[15];
    cs.p[13] = (const float*)d_in[17];
    cs.p[14] = (const float*)d_in[19];
    cs.p[15] = (const float*)d_in[21];
    // cvt + fused LN1 (segments 0-3 = x -> lnbuf)
    cvt_all<<<24 * 1048576 / 2048, blk256, 0, stream>>>(
        cs, wx, ln1_g, ln1_b, lnbuf);

    // ---- self-attention ----
    gemm_bt<EPI_QSCALE><<<gQ, blk256, 0, stream>>>(
        lnbuf, b_sa_wq, sa_bq, nullptr, nullptr, Qb, M, 1024, 1024, 1024);
    gemm_bt<EPI_KV><<<gKV, blk256, 0, stream>>>(
        wx, b_sa_wk, sa_bk, sa_bv, nullptr, Kb, M, 2048, 1024, 1024);
    flash_attn<true, false><<<gFA, blk256, 0, stream>>>(Qb, Kb, Vtb, Ob, nullptr, nullptr);
    gemm_bt<EPI_RES_F32_F32OUT><<<gQ, blk256, 0, stream>>>(
        Ob, b_sa_wo, sa_bo, nullptr, x, x1, M, 1024, 1024, 1024);

    // ---- cross-attention ----
    ln_kernel<<<4096, blk256, 0, stream>>>(x1, ln2_g, ln2_b, lnbuf);
    gemm_bt<EPI_QSCALE><<<gQ, blk256, 0, stream>>>(
        lnbuf, b_ca_wq, ca_bq, nullptr, nullptr, Qb, M, 1024, 1024, 1024);
    gemm_bt<EPI_KV><<<gKV, blk256, 0, stream>>>(
        wmem, b_ca_wk, ca_bk, ca_bv, nullptr, Kb, M, 2048, 1024, 1024);
    flash_attn<false, true><<<gFA, blk256, 0, stream>>>(Qb, Kb, Vtb, Ob, sbias, ca_scale);
    gemm_bt<EPI_RES_F32_F32OUT><<<gQ, blk256, 0, stream>>>(
        Ob, b_ca_wo, ca_bo, nullptr, x1, x2, M, 1024, 1024, 1024);

    // ---- FFN ----
    ln_kernel<<<4096, blk256, 0, stream>>>(x2, ln3_g, ln3_b, lnbuf);
    gemm256<EPI_RELU><<<g256, blk512, 0, stream>>>(
        lnbuf, b_w1, b1, ffnmid, 4096, 1024, 1024);
    // FFN2 direct (R8): K=4096, fused residual + bias, fp32 out.
    gemm_bt<EPI_RES_F32_F32OUT><<<gQ, blk256, 0, stream>>>(
        ffnmid, b_w2, b2, nullptr, x2, d_out, M, 1024, 4096, 4096);
}